// Round 11
// baseline (3234.511 us; speedup 1.0000x reference)
//
#include <hip/hip_runtime.h>
#include <hip/hip_bf16.h>
#include <cstdint>
#include <cstddef>

#define BN_EPS 1e-3f
typedef unsigned short ushort_t;
typedef unsigned int uint_t;
typedef __attribute__((ext_vector_type(8))) short short8v;   // 8 bf16 (4 VGPRs)
typedef __attribute__((ext_vector_type(4))) float f32x4;     // MFMA C/D

// ---------- numeric helpers ----------

__device__ __forceinline__ float fast_tanh(float x) {
    float xc = fminf(fmaxf(x, -12.0f), 12.0f);
    float e = __expf(2.0f * xc);
    return (e - 1.0f) / (e + 1.0f);
}

__device__ __forceinline__ float bf2f(uint_t u) {
    return __uint_as_float(u << 16);
}
__device__ __forceinline__ ushort_t f2bf(float f) {
    union { __hip_bfloat16 h; ushort_t u; } cv;
    cv.h = __float2bfloat16(f);   // RNE
    return cv.u;
}

// split 8 f32 -> 8 bf16 hi + 8 bf16 lo (lo = bf16(x - hi)), packed 16B each
__device__ __forceinline__ void split8(const float* f, uint4& h, uint4& lo) {
    uint_t hh[8], ll[8];
    #pragma unroll
    for (int j = 0; j < 8; ++j) {
        float x = f[j];
        ushort_t xh = f2bf(x);
        float xr = x - bf2f(xh);
        hh[j] = xh;
        ll[j] = f2bf(xr);
    }
    h  = make_uint4(hh[0] | (hh[1] << 16), hh[2] | (hh[3] << 16),
                    hh[4] | (hh[5] << 16), hh[6] | (hh[7] << 16));
    lo = make_uint4(ll[0] | (ll[1] << 16), ll[2] | (ll[3] << 16),
                    ll[4] | (ll[5] << 16), ll[6] | (ll[7] << 16));
}

// ---------- counting sort of atoms by membership (ascending) ----------

__global__ void k_zero_bins(int* __restrict__ binCnt, int* __restrict__ binFill) {
    int t = blockIdx.x * 256 + threadIdx.x;
    if (t < 40000) { binCnt[t] = 0; binFill[t] = 0; }
}

__global__ void k_hist(const int* __restrict__ memb, int* __restrict__ binCnt) {
    int t = blockIdx.x * 256 + threadIdx.x;
    if (t < 1000000) atomicAdd(&binCnt[memb[t]], 1);
}

__global__ __launch_bounds__(1024)
void k_scan(const int* __restrict__ binCnt, int* __restrict__ binBase) {
    __shared__ int part[1024];
    const int t = threadIdx.x;
    const int base = t * 40;
    int local[40];
    int s = 0;
    #pragma unroll
    for (int j = 0; j < 40; ++j) {
        int idx = base + j;
        int c = (idx < 40000) ? binCnt[idx] : 0;
        local[j] = s;
        s += c;
    }
    part[t] = s;
    __syncthreads();
    for (int off = 1; off < 1024; off <<= 1) {
        int v = (t >= off) ? part[t - off] : 0;
        __syncthreads();
        part[t] += v;
        __syncthreads();
    }
    int add = (t > 0) ? part[t - 1] : 0;
    #pragma unroll
    for (int j = 0; j < 40; ++j) {
        int idx = base + j;
        if (idx < 40000) binBase[idx] = add + local[j];
    }
}

__global__ void k_scatter(const int* __restrict__ memb, const int* __restrict__ binBase,
                          int* __restrict__ binFill, int* __restrict__ perm) {
    int t = blockIdx.x * 256 + threadIdx.x;
    if (t < 1000000) {
        int m = memb[t];
        int pos = binBase[m] + atomicAdd(&binFill[m], 1);
        perm[pos] = t;
    }
}

// ---------- subtile metadata: 125000 subtiles of 8 sorted rows ----------

__global__ void k_meta(const int* __restrict__ memb, const int* __restrict__ perm,
                       int* __restrict__ firstSeg, int* __restrict__ segCnt) {
    int t = blockIdx.x * 256 + threadIdx.x;
    if (t < 125000) {
        int f = memb[perm[8 * t]];
        int l = memb[perm[8 * t + 7]];
        firstSeg[t] = f;
        segCnt[t] = l - f + 1;
    }
}

__global__ __launch_bounds__(1024)
void k_scan2(const int* __restrict__ segCnt, int* __restrict__ cumSeg) {
    __shared__ int part[1024];
    const int t = threadIdx.x;
    const int base = t * 123;
    int s = 0;
    for (int j = 0; j < 123; ++j) {
        int idx = base + j;
        if (idx < 125000) s += segCnt[idx];
    }
    part[t] = s;
    __syncthreads();
    for (int off = 1; off < 1024; off <<= 1) {
        int v = (t >= off) ? part[t - off] : 0;
        __syncthreads();
        part[t] += v;
        __syncthreads();
    }
    int run = (t > 0) ? part[t - 1] : 0;
    for (int j = 0; j < 123; ++j) {
        int idx = base + j;
        if (idx < 125000) { cumSeg[idx] = run; run += segCnt[idx]; }
    }
}

// ---------- W fragment prep: dense [128][256] ----------
// fid = (tn*4 + ks)*64 + lane; lane j holds W[ks*32 + (lane>>4)*8 + j][tn*16 + (lane&15)]

__global__ void k_prepW(const float* __restrict__ W,
                        ushort_t* __restrict__ Bh, ushort_t* __restrict__ Bl) {
    int idx = blockIdx.x * 256 + threadIdx.x;
    if (idx >= 4096) return;
    int l = idx & 63, g = idx >> 6;       // g = tn*4 + ks
    int tn = g >> 2, ks = g & 3;
    int n = tn * 16 + (l & 15);
    int k0 = ks * 32 + (l >> 4) * 8;
    float f[8];
    #pragma unroll
    for (int j = 0; j < 8; ++j) f[j] = W[(size_t)(k0 + j) * 256 + n];
    uint4 h, lo; split8(f, h, lo);
    *(uint4*)(Bh + (size_t)idx * 8) = h;
    *(uint4*)(Bl + (size_t)idx * 8) = lo;
}

// ---------- W fragment prep: gc2's 9 matrices [128][128] (5 self + 4 rel) ----------

__global__ void k_prepW2(const float* __restrict__ Ws5, const float* __restrict__ Wr4,
                         ushort_t* __restrict__ Fh, ushort_t* __restrict__ Fl) {
    int idx = blockIdx.x * 256 + threadIdx.x;   // [0, 9*2048)
    if (idx >= 18432) return;
    int mat = idx >> 11;
    int fid = idx & 2047;
    int l = fid & 63, g = fid >> 6;
    int tn = g >> 2, ks = g & 3;
    int n = tn * 16 + (l & 15);
    int k0 = ks * 32 + (l >> 4) * 8;
    const float* W = (mat < 5) ? (Ws5 + (size_t)mat * 16384)
                               : (Wr4 + (size_t)(mat - 5) * 16384);
    float f[8];
    #pragma unroll
    for (int j = 0; j < 8; ++j) f[j] = W[(size_t)(k0 + j) * 128 + n];
    uint4 h, lo; split8(f, h, lo);
    *(uint4*)(Fh + (size_t)idx * 8) = h;
    *(uint4*)(Fl + (size_t)idx * 8) = lo;
}

// ---------- W fragment prep: gc1's 9 matrices [75][128], K padded to 96 ----------
// per matrix: 1536 frags (tn 0..7, ks 0..2, lane 0..63); k >= 75 -> 0.

__global__ void k_prepW1(const float* __restrict__ Ws5, const float* __restrict__ Wr4,
                         ushort_t* __restrict__ Fh, ushort_t* __restrict__ Fl) {
    int idx = blockIdx.x * 256 + threadIdx.x;   // [0, 9*1536)
    if (idx >= 13824) return;
    int mat = idx / 1536;
    int fid = idx - mat * 1536;
    int l = fid & 63, g = fid >> 6;             // g = tn*3 + ks
    int tn = g / 3, ks = g - tn * 3;
    int n = tn * 16 + (l & 15);
    int k0 = ks * 32 + (l >> 4) * 8;
    const float* W = (mat < 5) ? (Ws5 + (size_t)mat * 9600)
                               : (Wr4 + (size_t)(mat - 5) * 9600);
    float f[8];
    #pragma unroll
    for (int j = 0; j < 8; ++j)
        f[j] = (k0 + j < 75) ? W[(size_t)(k0 + j) * 128 + n] : 0.0f;
    uint4 h, lo; split8(f, h, lo);
    *(uint4*)(Fh + (size_t)idx * 8) = h;
    *(uint4*)(Fl + (size_t)idx * 8) = lo;
}

// ---------- gc1 via MFMA split-bf16 (tanh + bn1 fused), K=75 padded to 96 ----------
// v2 staging: thread owns (row, 8-k chunk), b128 LDS writes.

template<int DEG>
__global__ __launch_bounds__(256)
void k_gc1m(const float* __restrict__ X, const int* __restrict__ adj,
            const ushort_t* __restrict__ Wsh, const ushort_t* __restrict__ Wsl,
            const ushort_t* __restrict__ Wrh, const ushort_t* __restrict__ Wrl,
            const float* __restrict__ bias,
            const float* __restrict__ bg, const float* __restrict__ bb,
            const float* __restrict__ bm, const float* __restrict__ bv,
            float* __restrict__ Out, int start, int count)
{
    __shared__ __align__(16) ushort_t Sh[64 * 128];
    __shared__ __align__(16) ushort_t Sl[64 * 128];
    __shared__ __align__(16) ushort_t Nh[(DEG > 0) ? 64 * 128 : 8];
    __shared__ __align__(16) ushort_t Nl[(DEG > 0) ? 64 * 128 : 8];

    const int tid = threadIdx.x;
    const int tileBase = blockIdx.x * 64;

    // stage 12 chunks x 8 k per row (covers k=0..95; zeros pad k>=75)
    for (int idx = tid; idx < 64 * 12; idx += 256) {
        int a = idx / 12;
        int c = idx - a * 12;
        int k0 = c * 8;
        int ga = tileBase + a;
        float fs[8] = {0, 0, 0, 0, 0, 0, 0, 0};
        float fn[8] = {0, 0, 0, 0, 0, 0, 0, 0};
        if (ga < count) {
            const float* row = X + (size_t)(start + ga) * 75;
            #pragma unroll
            for (int j = 0; j < 8; ++j) {
                int k = k0 + j;
                if (k < 75) fs[j] = row[k];
            }
            if constexpr (DEG > 0) {
                #pragma unroll
                for (int jj = 0; jj < DEG; ++jj) {
                    int nb = adj[(size_t)ga * DEG + jj];
                    const float* nr = X + (size_t)nb * 75;
                    #pragma unroll
                    for (int j = 0; j < 8; ++j) {
                        int k = k0 + j;
                        if (k < 75) fn[j] += nr[k];
                    }
                }
            }
        }
        int cs = c ^ (a & 15);
        uint4 h, lo;
        split8(fs, h, lo);
        *(uint4*)(Sh + a * 128 + cs * 8) = h;
        *(uint4*)(Sl + a * 128 + cs * 8) = lo;
        if constexpr (DEG > 0) {
            split8(fn, h, lo);
            *(uint4*)(Nh + a * 128 + cs * 8) = h;
            *(uint4*)(Nl + a * 128 + cs * 8) = lo;
        }
    }
    __syncthreads();

    const int w = tid >> 6, l = tid & 63;
    const int lm = l & 15, lq = l >> 4;

    f32x4 acc[4][2];
    #pragma unroll
    for (int rt = 0; rt < 4; ++rt)
        #pragma unroll
        for (int ti = 0; ti < 2; ++ti)
            acc[rt][ti] = (f32x4){0.f, 0.f, 0.f, 0.f};

    for (int ks = 0; ks < 3; ++ks) {
        short8v ash[4], asl[4], anh[4], anl[4];
        #pragma unroll
        for (int rt = 0; rt < 4; ++rt) {
            int a = rt * 16 + lm;
            int cs = (ks * 4 + lq) ^ lm;
            ash[rt] = *(const short8v*)(Sh + a * 128 + cs * 8);
            asl[rt] = *(const short8v*)(Sl + a * 128 + cs * 8);
            if constexpr (DEG > 0) {
                anh[rt] = *(const short8v*)(Nh + a * 128 + cs * 8);
                anl[rt] = *(const short8v*)(Nl + a * 128 + cs * 8);
            }
        }
        #pragma unroll
        for (int ti = 0; ti < 2; ++ti) {
            int fid = ((w + ti * 4) * 3 + ks) * 64 + l;
            short8v bh = *(const short8v*)(Wsh + (size_t)fid * 8);
            short8v bl = *(const short8v*)(Wsl + (size_t)fid * 8);
            #pragma unroll
            for (int rt = 0; rt < 4; ++rt) {
                acc[rt][ti] = __builtin_amdgcn_mfma_f32_16x16x32_bf16(ash[rt], bh, acc[rt][ti], 0, 0, 0);
                acc[rt][ti] = __builtin_amdgcn_mfma_f32_16x16x32_bf16(asl[rt], bh, acc[rt][ti], 0, 0, 0);
                acc[rt][ti] = __builtin_amdgcn_mfma_f32_16x16x32_bf16(ash[rt], bl, acc[rt][ti], 0, 0, 0);
            }
            if constexpr (DEG > 0) {
                short8v rh = *(const short8v*)(Wrh + (size_t)fid * 8);
                short8v rl = *(const short8v*)(Wrl + (size_t)fid * 8);
                #pragma unroll
                for (int rt = 0; rt < 4; ++rt) {
                    acc[rt][ti] = __builtin_amdgcn_mfma_f32_16x16x32_bf16(anh[rt], rh, acc[rt][ti], 0, 0, 0);
                    acc[rt][ti] = __builtin_amdgcn_mfma_f32_16x16x32_bf16(anl[rt], rh, acc[rt][ti], 0, 0, 0);
                    acc[rt][ti] = __builtin_amdgcn_mfma_f32_16x16x32_bf16(anh[rt], rl, acc[rt][ti], 0, 0, 0);
                }
            }
        }
    }

    // epilogue: +bias, tanh, bn1; direct stores (C/D: col=lm, row=lq*4+r)
    #pragma unroll
    for (int ti = 0; ti < 2; ++ti) {
        int cc = (w + ti * 4) * 16 + lm;
        float bz = bias[cc];
        float s = bg[cc] * rsqrtf(bv[cc] + BN_EPS);
        float sb = bb[cc] - bm[cc] * s;
        #pragma unroll
        for (int rt = 0; rt < 4; ++rt) {
            #pragma unroll
            for (int r = 0; r < 4; ++r) {
                int ga = tileBase + rt * 16 + lq * 4 + r;
                if (ga < count)
                    Out[(size_t)(start + ga) * 128 + cc] =
                        fast_tanh(acc[rt][ti][r] + bz) * s + sb;
            }
        }
    }
}

// ---------- gc2 via MFMA split-bf16 (tanh + bn1 fused) — proven round-7 kernel ----------

template<int DEG>
__global__ __launch_bounds__(256)
void k_gc2m(const float* __restrict__ X, const int* __restrict__ adj,
            const ushort_t* __restrict__ Wsh, const ushort_t* __restrict__ Wsl,
            const ushort_t* __restrict__ Wrh, const ushort_t* __restrict__ Wrl,
            const float* __restrict__ bias,
            const float* __restrict__ bg, const float* __restrict__ bb,
            const float* __restrict__ bm, const float* __restrict__ bv,
            float* __restrict__ Out, int start, int count)
{
    __shared__ __align__(16) ushort_t Sh[64 * 128];
    __shared__ __align__(16) ushort_t Sl[64 * 128];
    __shared__ __align__(16) ushort_t Nh[(DEG > 0) ? 64 * 128 : 8];
    __shared__ __align__(16) ushort_t Nl[(DEG > 0) ? 64 * 128 : 8];

    const int tid = threadIdx.x;
    const int tileBase = blockIdx.x * 64;

    for (int idx = tid; idx < 1024; idx += 256) {
        int a = idx >> 4, c = idx & 15;
        int ga = tileBase + a;
        float fs[8] = {0, 0, 0, 0, 0, 0, 0, 0};
        float fn[8] = {0, 0, 0, 0, 0, 0, 0, 0};
        if (ga < count) {
            const float* row = X + (size_t)(start + ga) * 128 + c * 8;
            *(float4*)(&fs[0]) = *(const float4*)row;
            *(float4*)(&fs[4]) = *(const float4*)(row + 4);
            if constexpr (DEG > 0) {
                #pragma unroll
                for (int j = 0; j < DEG; ++j) {
                    int nb = adj[(size_t)ga * DEG + j];
                    const float* nr = X + (size_t)nb * 128 + c * 8;
                    float4 q0 = *(const float4*)nr;
                    float4 q1 = *(const float4*)(nr + 4);
                    fn[0] += q0.x; fn[1] += q0.y; fn[2] += q0.z; fn[3] += q0.w;
                    fn[4] += q1.x; fn[5] += q1.y; fn[6] += q1.z; fn[7] += q1.w;
                }
            }
        }
        int cs = c ^ (a & 15);
        uint4 h, lo;
        split8(fs, h, lo);
        *(uint4*)(Sh + a * 128 + cs * 8) = h;
        *(uint4*)(Sl + a * 128 + cs * 8) = lo;
        if constexpr (DEG > 0) {
            split8(fn, h, lo);
            *(uint4*)(Nh + a * 128 + cs * 8) = h;
            *(uint4*)(Nl + a * 128 + cs * 8) = lo;
        }
    }
    __syncthreads();

    const int w = tid >> 6, l = tid & 63;
    const int lm = l & 15, lq = l >> 4;

    f32x4 acc[4][2];
    #pragma unroll
    for (int rt = 0; rt < 4; ++rt)
        #pragma unroll
        for (int ti = 0; ti < 2; ++ti)
            acc[rt][ti] = (f32x4){0.f, 0.f, 0.f, 0.f};

    for (int ks = 0; ks < 4; ++ks) {
        short8v ash[4], asl[4], anh[4], anl[4];
        #pragma unroll
        for (int rt = 0; rt < 4; ++rt) {
            int a = rt * 16 + lm;
            int cs = (ks * 4 + lq) ^ lm;
            ash[rt] = *(const short8v*)(Sh + a * 128 + cs * 8);
            asl[rt] = *(const short8v*)(Sl + a * 128 + cs * 8);
            if constexpr (DEG > 0) {
                anh[rt] = *(const short8v*)(Nh + a * 128 + cs * 8);
                anl[rt] = *(const short8v*)(Nl + a * 128 + cs * 8);
            }
        }
        #pragma unroll
        for (int ti = 0; ti < 2; ++ti) {
            int fid = ((w + ti * 4) * 4 + ks) * 64 + l;
            short8v bh = *(const short8v*)(Wsh + (size_t)fid * 8);
            short8v bl = *(const short8v*)(Wsl + (size_t)fid * 8);
            #pragma unroll
            for (int rt = 0; rt < 4; ++rt) {
                acc[rt][ti] = __builtin_amdgcn_mfma_f32_16x16x32_bf16(ash[rt], bh, acc[rt][ti], 0, 0, 0);
                acc[rt][ti] = __builtin_amdgcn_mfma_f32_16x16x32_bf16(asl[rt], bh, acc[rt][ti], 0, 0, 0);
                acc[rt][ti] = __builtin_amdgcn_mfma_f32_16x16x32_bf16(ash[rt], bl, acc[rt][ti], 0, 0, 0);
            }
            if constexpr (DEG > 0) {
                short8v rh = *(const short8v*)(Wrh + (size_t)fid * 8);
                short8v rl = *(const short8v*)(Wrl + (size_t)fid * 8);
                #pragma unroll
                for (int rt = 0; rt < 4; ++rt) {
                    acc[rt][ti] = __builtin_amdgcn_mfma_f32_16x16x32_bf16(anh[rt], rh, acc[rt][ti], 0, 0, 0);
                    acc[rt][ti] = __builtin_amdgcn_mfma_f32_16x16x32_bf16(anl[rt], rh, acc[rt][ti], 0, 0, 0);
                    acc[rt][ti] = __builtin_amdgcn_mfma_f32_16x16x32_bf16(anh[rt], rl, acc[rt][ti], 0, 0, 0);
                }
            }
        }
    }

    #pragma unroll
    for (int ti = 0; ti < 2; ++ti) {
        int cc = (w + ti * 4) * 16 + lm;
        float bz = bias[cc];
        float s = bg[cc] * rsqrtf(bv[cc] + BN_EPS);
        float sb = bb[cc] - bm[cc] * s;
        #pragma unroll
        for (int rt = 0; rt < 4; ++rt) {
            #pragma unroll
            for (int r = 0; r < 4; ++r) {
                int ga = tileBase + rt * 16 + lq * 4 + r;
                if (ga < count)
                    Out[(size_t)(start + ga) * 128 + cc] =
                        fast_tanh(acc[rt][ti][r] + bz) * s + sb;
            }
        }
    }
}

// ---------- graph pool (f32 -> f32), used for pool1 ----------

template<int DEG>
__global__ void k_pool(const float* __restrict__ X, const int* __restrict__ adj,
                       float* __restrict__ Out, int start, int count)
{
    int t = blockIdx.x * 256 + threadIdx.x;
    int a = t >> 5;
    if (a >= count) return;
    int c4 = t & 31;
    const float4* X4 = (const float4*)X;
    float4 v = X4[(size_t)(start + a) * 32 + c4];
    #pragma unroll
    for (int j = 0; j < DEG; ++j) {
        int nb = adj[(size_t)a * DEG + j];
        float4 q = X4[(size_t)nb * 32 + c4];
        v.x = fmaxf(v.x, q.x); v.y = fmaxf(v.y, q.y);
        v.z = fmaxf(v.z, q.z); v.w = fmaxf(v.w, q.w);
    }
    ((float4*)Out)[(size_t)(start + a) * 32 + c4] = v;
}

// ---------- graph pool (f32 -> split bf16 hi/lo planes), used for pool2 ----------
// thread = (atom, 8 channels). Output consumed only by dense staging.

template<int DEG>
__global__ void k_pool_split(const float* __restrict__ X, const int* __restrict__ adj,
                             ushort_t* __restrict__ PH, ushort_t* __restrict__ PL,
                             int start, int count)
{
    int t = blockIdx.x * 256 + threadIdx.x;
    int a = t >> 4;
    if (a >= count) return;
    int c8 = (t & 15) * 8;
    const float* row = X + (size_t)(start + a) * 128 + c8;
    float f[8];
    *(float4*)(&f[0]) = *(const float4*)row;
    *(float4*)(&f[4]) = *(const float4*)(row + 4);
    #pragma unroll
    for (int j = 0; j < DEG; ++j) {
        int nb = adj[(size_t)a * DEG + j];
        const float* nr = X + (size_t)nb * 128 + c8;
        float4 q0 = *(const float4*)nr;
        float4 q1 = *(const float4*)(nr + 4);
        f[0] = fmaxf(f[0], q0.x); f[1] = fmaxf(f[1], q0.y);
        f[2] = fmaxf(f[2], q0.z); f[3] = fmaxf(f[3], q0.w);
        f[4] = fmaxf(f[4], q1.x); f[5] = fmaxf(f[5], q1.y);
        f[6] = fmaxf(f[6], q1.z); f[7] = fmaxf(f[7], q1.w);
    }
    uint4 h, lo; split8(f, h, lo);
    *(uint4*)(PH + (size_t)(start + a) * 128 + c8) = h;
    *(uint4*)(PL + (size_t)(start + a) * 128 + c8) = lo;
}

// ---------- dense via MFMA split-bf16 (tanh + bn3) + subtile partials ----------
// Staging is a pure copy of pre-split planes (no arithmetic).

__global__ __launch_bounds__(256)
void k_dense_mfma(const ushort_t* __restrict__ PH,  // [1M][128] bf16 hi plane
                  const ushort_t* __restrict__ PL,  // [1M][128] bf16 lo plane
                  const int*   __restrict__ memb,
                  const int*   __restrict__ perm,    // membership-ascending
                  const int*   __restrict__ cumSeg,  // [125000]
                  const ushort_t* __restrict__ Bh,   // W frag hi [4096][8]
                  const ushort_t* __restrict__ Bl,   // W frag lo
                  const float* __restrict__ bias,    // [256]
                  const float* __restrict__ bg, const float* __restrict__ bb,
                  const float* __restrict__ bm, const float* __restrict__ bv,
                  float* __restrict__ partials)
{
    __shared__ __align__(16) char smem[33792];   // Ah[16KB]+Al[16KB] / Yt[64][132]f32
    __shared__ int sM[64];
    __shared__ int sP[64];
    ushort_t* Ah = (ushort_t*)smem;
    ushort_t* Al = (ushort_t*)(smem + 16384);
    float*    Yt = (float*)smem;

    const int tid = threadIdx.x;
    const int tileBase = blockIdx.x * 64;
    if (tid < 64) {
        int p = perm[tileBase + tid];
        sP[tid] = p;
        sM[tid] = memb[p];
    }
    __syncthreads();

    // staging: copy pre-split 16B chunks (swizzled) — zero arithmetic
    for (int idx = tid; idx < 1024; idx += 256) {
        int a = idx >> 4, c = idx & 15;
        size_t off = (size_t)sP[a] * 128 + c * 8;
        uint4 h  = *(const uint4*)(PH + off);
        uint4 lo = *(const uint4*)(PL + off);
        int cs = c ^ (a & 15);
        *(uint4*)(Ah + a * 128 + cs * 8) = h;
        *(uint4*)(Al + a * 128 + cs * 8) = lo;
    }
    __syncthreads();

    const int w = tid >> 6, l = tid & 63;
    const int lm = l & 15, lq = l >> 4;

    f32x4 acc[4][4];
    #pragma unroll
    for (int rt = 0; rt < 4; ++rt)
        #pragma unroll
        for (int ti = 0; ti < 4; ++ti)
            acc[rt][ti] = (f32x4){0.f, 0.f, 0.f, 0.f};

    for (int ks = 0; ks < 4; ++ks) {
        short8v ah[4], al[4];
        #pragma unroll
        for (int rt = 0; rt < 4; ++rt) {
            int a = rt * 16 + lm;
            int cs = (ks * 4 + lq) ^ lm;
            ah[rt] = *(const short8v*)(Ah + a * 128 + cs * 8);
            al[rt] = *(const short8v*)(Al + a * 128 + cs * 8);
        }
        #pragma unroll
        for (int ti = 0; ti < 4; ++ti) {
            int fid = ((w + ti * 4) * 4 + ks) * 64 + l;
            short8v bh = *(const short8v*)(Bh + (size_t)fid * 8);
            short8v bl = *(const short8v*)(Bl + (size_t)fid * 8);
            #pragma unroll
            for (int rt = 0; rt < 4; ++rt) {
                acc[rt][ti] = __builtin_amdgcn_mfma_f32_16x16x32_bf16(ah[rt], bh, acc[rt][ti], 0, 0, 0);
                acc[rt][ti] = __builtin_amdgcn_mfma_f32_16x16x32_bf16(al[rt], bh, acc[rt][ti], 0, 0, 0);
                acc[rt][ti] = __builtin_amdgcn_mfma_f32_16x16x32_bf16(ah[rt], bl, acc[rt][ti], 0, 0, 0);
            }
        }
    }

    float bvz[4], scv[4], shv[4];
    #pragma unroll
    for (int ti = 0; ti < 4; ++ti) {
        int c = (w + ti * 4) * 16 + lm;
        bvz[ti] = bias[c];
        float s = bg[c] * rsqrtf(bv[c] + BN_EPS);
        scv[ti] = s;
        shv[ti] = bb[c] - bm[c] * s;
    }

    const int q = tid >> 5, cg = tid & 31;
    const int sub = blockIdx.x * 8 + q;
    const size_t slotBase = (size_t)cumSeg[sub];
    const int fs = sM[q * 8];

    #pragma unroll
    for (int hf = 0; hf < 2; ++hf) {
        __syncthreads();
        #pragma unroll
        for (int tj = 0; tj < 2; ++tj) {
            int ti = 2 * hf + tj;
            int colh = (w + ti * 4) * 16 + lm - hf * 128;
            #pragma unroll
            for (int rt = 0; rt < 4; ++rt)
                #pragma unroll
                for (int r = 0; r < 4; ++r) {
                    int row = rt * 16 + lq * 4 + r;
                    float y = fast_tanh(acc[rt][ti][r] + bvz[ti]) * scv[ti] + shv[ti];
                    Yt[row * 132 + colh] = y;
                }
        }
        __syncthreads();

        float4 ys, ym;
        int cur = sM[q * 8];
        {
            float4 v = *(const float4*)(Yt + (q * 8) * 132 + cg * 4);
            ys = v; ym = v;
        }
        #pragma unroll
        for (int i = 1; i < 8; ++i) {
            float4 v = *(const float4*)(Yt + (q * 8 + i) * 132 + cg * 4);
            int m = sM[q * 8 + i];
            if (m == cur) {
                ys.x += v.x; ys.y += v.y; ys.z += v.z; ys.w += v.w;
                ym.x = fmaxf(ym.x, v.x); ym.y = fmaxf(ym.y, v.y);
                ym.z = fmaxf(ym.z, v.z); ym.w = fmaxf(ym.w, v.w);
            } else {
                float* p = partials + (slotBase + (cur - fs)) * 512 + hf * 128 + cg * 4;
                *(float4*)p         = ys;
                *(float4*)(p + 256) = ym;
                cur = m; ys = v; ym = v;
            }
        }
        float* p = partials + (slotBase + (cur - fs)) * 512 + hf * 128 + cg * 4;
        *(float4*)p         = ys;
        *(float4*)(p + 256) = ym;
    }
}

// ---------- combine partials -> final out (tanh fused) ----------

__global__ __launch_bounds__(256)
void k_combine(const float* __restrict__ partials,
               const int* __restrict__ binBase, const int* __restrict__ binCnt,
               const int* __restrict__ firstSeg, const int* __restrict__ cumSeg,
               float* __restrict__ Out)
{
    int sid = blockIdx.x * 4 + (threadIdx.x >> 6);
    if (sid >= 40000) return;
    int lane = threadIdx.x & 63;
    int b = binBase[sid], n = binCnt[sid];

    float4 s = make_float4(0.f, 0.f, 0.f, 0.f);
    float4 m = make_float4(-INFINITY, -INFINITY, -INFINITY, -INFINITY);
    if (n > 0) {
        int s0 = b >> 3, s1 = (b + n - 1) >> 3;
        for (int t = s0; t <= s1; ++t) {
            size_t slot = (size_t)cumSeg[t] + (sid - firstSeg[t]);
            const float4* P = (const float4*)(partials + slot * 512);
            float4 a = P[lane];
            float4 x = P[64 + lane];
            s.x += a.x; s.y += a.y; s.z += a.z; s.w += a.w;
            m.x = fmaxf(m.x, x.x); m.y = fmaxf(m.y, x.y);
            m.z = fmaxf(m.z, x.z); m.w = fmaxf(m.w, x.w);
        }
    }
    float4 os = make_float4(fast_tanh(s.x), fast_tanh(s.y), fast_tanh(s.z), fast_tanh(s.w));
    float4 om = make_float4(fast_tanh(m.x), fast_tanh(m.y), fast_tanh(m.z), fast_tanh(m.w));
    *(float4*)(Out + (size_t)sid * 512 + lane * 4)       = os;
    *(float4*)(Out + (size_t)sid * 512 + 256 + lane * 4) = om;
}

// ---------- launcher ----------

extern "C" void kernel_launch(void* const* d_in, const int* in_sizes, int n_in,
                              void* d_out, int out_size, void* d_ws, size_t ws_size,
                              hipStream_t stream)
{
    const float* atom = (const float*)d_in[0];
    const int*   memb = (const int*)d_in[1];
    const int*   adj1 = (const int*)d_in[2];
    const int*   adj2 = (const int*)d_in[3];
    const int*   adj3 = (const int*)d_in[4];
    const int*   adj4 = (const int*)d_in[5];
    const float* g1Ws = (const float*)d_in[6];
    const float* g1Wr = (const float*)d_in[7];
    const float* g1b  = (const float*)d_in[8];
    const float* g2Ws = (const float*)d_in[9];
    const float* g2Wr = (const float*)d_in[10];
    const float* g2b  = (const float*)d_in[11];
    const float* bn1g = (const float*)d_in[12];
    const float* bn1b = (const float*)d_in[13];
    const float* bn1m = (const float*)d_in[14];
    const float* bn1v = (const float*)d_in[15];
    const float* bn3g = (const float*)d_in[16];
    const float* bn3b = (const float*)d_in[17];
    const float* bn3m = (const float*)d_in[18];
    const float* bn3v = (const float*)d_in[19];
    const float* dW   = (const float*)d_in[20];
    const float* db   = (const float*)d_in[21];

    char* ws = (char*)d_ws;
    float* bufA = (float*)ws;                    // [1M][128] f32, 512 MB
    float* bufB = (float*)(ws + 512000000);      // [1M][128] f32, 512 MB
    float* out  = (float*)d_out;                 // [40000][512]

    // pool2 split planes live in bufB (pool1 output consumed by then):
    ushort_t* PH = (ushort_t*)bufB;              // [1M][128] bf16 hi, 256 MB
    ushort_t* PL = PH + (size_t)1000000 * 128;   // [1M][128] bf16 lo, 256 MB

    // W fragments live in d_out (only combine writes d_out, at the very end):
    ushort_t* gFh  = (ushort_t*)out;             // gc2: 18432 frags x 16B
    ushort_t* gFl  = gFh + (size_t)18432 * 8;
    ushort_t* g1Fh = gFl + (size_t)18432 * 8;    // gc1: 13824 frags x 16B
    ushort_t* g1Fl = g1Fh + (size_t)13824 * 8;   // ends ~1.03 MB << 82 MB

    // scratch inside bufA (dead after pool2 reads it):
    int* perm     = (int*)bufA;                  // 1,000,000
    int* binCnt   = perm + 1000000;              // 40,000
    int* binBase  = binCnt + 40000;
    int* binFill  = binBase + 40000;
    int* firstSeg = binFill + 40000;             // 125,000
    int* segCnt   = firstSeg + 125000;
    int* cumSeg   = segCnt + 125000;             // ends < 6 MB
    ushort_t* dWh = (ushort_t*)(ws + 6200000);   // dense: 4096 frags x 16B
    ushort_t* dWl = (ushort_t*)(ws + 6400000);
    float* partials = (float*)(ws + 8000000);    // <=164,999 slots x 512 f32 = 338 MB

    // ---- W fragment prep (into d_out; read by gc kernels, overwritten by combine) ----
    k_prepW2<<<72, 256, 0, stream>>>(g2Ws, g2Wr, gFh, gFl);
    k_prepW1<<<54, 256, 0, stream>>>(g1Ws, g1Wr, g1Fh, g1Fl);

    // ---- gc1 (MFMA, v2 staging): atom -> bufA ----
    k_gc1m<0><<<(10000 + 63) / 64, 256, 0, stream>>>(atom, nullptr,
        g1Fh + (size_t)0 * 1536 * 8, g1Fl + (size_t)0 * 1536 * 8,
        nullptr, nullptr, g1b + 0 * 128,
        bn1g, bn1b, bn1m, bn1v, bufA, 0, 10000);
    k_gc1m<1><<<(240000 + 63) / 64, 256, 0, stream>>>(atom, adj1,
        g1Fh + (size_t)1 * 1536 * 8, g1Fl + (size_t)1 * 1536 * 8,
        g1Fh + (size_t)5 * 1536 * 8, g1Fl + (size_t)5 * 1536 * 8, g1b + 1 * 128,
        bn1g, bn1b, bn1m, bn1v, bufA, 10000, 240000);
    k_gc1m<2><<<(360000 + 63) / 64, 256, 0, stream>>>(atom, adj2,
        g1Fh + (size_t)2 * 1536 * 8, g1Fl + (size_t)2 * 1536 * 8,
        g1Fh + (size_t)6 * 1536 * 8, g1Fl + (size_t)6 * 1536 * 8, g1b + 2 * 128,
        bn1g, bn1b, bn1m, bn1v, bufA, 250000, 360000);
    k_gc1m<3><<<(250000 + 63) / 64, 256, 0, stream>>>(atom, adj3,
        g1Fh + (size_t)3 * 1536 * 8, g1Fl + (size_t)3 * 1536 * 8,
        g1Fh + (size_t)7 * 1536 * 8, g1Fl + (size_t)7 * 1536 * 8, g1b + 3 * 128,
        bn1g, bn1b, bn1m, bn1v, bufA, 610000, 250000);
    k_gc1m<4><<<(140000 + 63) / 64, 256, 0, stream>>>(atom, adj4,
        g1Fh + (size_t)4 * 1536 * 8, g1Fl + (size_t)4 * 1536 * 8,
        g1Fh + (size_t)8 * 1536 * 8, g1Fl + (size_t)8 * 1536 * 8, g1b + 4 * 128,
        bn1g, bn1b, bn1m, bn1v, bufA, 860000, 140000);

    // ---- pool1: bufA -> bufB (f32) ----
    k_pool<0><<<(10000 + 7) / 8, 256, 0, stream>>>(bufA, nullptr, bufB, 0, 10000);
    k_pool<1><<<(240000 + 7) / 8, 256, 0, stream>>>(bufA, adj1, bufB, 10000, 240000);
    k_pool<2><<<(360000 + 7) / 8, 256, 0, stream>>>(bufA, adj2, bufB, 250000, 360000);
    k_pool<3><<<(250000 + 7) / 8, 256, 0, stream>>>(bufA, adj3, bufB, 610000, 250000);
    k_pool<4><<<(140000 + 7) / 8, 256, 0, stream>>>(bufA, adj4, bufB, 860000, 140000);

    // ---- gc2 (MFMA): bufB -> bufA ----
    k_gc2m<0><<<(10000 + 63) / 64, 256, 0, stream>>>(bufB, nullptr,
        gFh + (size_t)0 * 2048 * 8, gFl + (size_t)0 * 2048 * 8,
        nullptr, nullptr, g2b + 0 * 128,
        bn1g, bn1b, bn1m, bn1v, bufA, 0, 10000);
    k_gc2m<1><<<(240000 + 63) / 64, 256, 0, stream>>>(bufB, adj1,
        gFh + (size_t)1 * 2048 * 8, gFl + (size_t)1 * 2048 * 8,
        gFh + (size_t)5 * 2048 * 8, gFl + (size_t)5 * 2048 * 8, g2b + 1 * 128,
        bn1g, bn1b, bn1m, bn1v, bufA, 10000, 240000);
    k_gc2m<2><<<(360000 + 63) / 64, 256, 0, stream>>>(bufB, adj2,
        gFh + (size_t)2 * 2048 * 8, gFl + (size_t)2 * 2048 * 8,
        gFh + (size_t)6 * 2048 * 8, gFl + (size_t)6 * 2048 * 8, g2b + 2 * 128,
        bn1g, bn1b, bn1m, bn1v, bufA, 250000, 360000);
    k_gc2m<3><<<(250000 + 63) / 64, 256, 0, stream>>>(bufB, adj3,
        gFh + (size_t)3 * 2048 * 8, gFl + (size_t)3 * 2048 * 8,
        gFh + (size_t)7 * 2048 * 8, gFl + (size_t)7 * 2048 * 8, g2b + 3 * 128,
        bn1g, bn1b, bn1m, bn1v, bufA, 610000, 250000);
    k_gc2m<4><<<(140000 + 63) / 64, 256, 0, stream>>>(bufB, adj4,
        gFh + (size_t)4 * 2048 * 8, gFl + (size_t)4 * 2048 * 8,
        gFh + (size_t)8 * 2048 * 8, gFl + (size_t)8 * 2048 * 8, g2b + 4 * 128,
        bn1g, bn1b, bn1m, bn1v, bufA, 860000, 140000);

    // ---- pool2: bufA -> split planes PH/PL in bufB ----
    k_pool_split<0><<<(10000 * 16 + 255) / 256, 256, 0, stream>>>(bufA, nullptr, PH, PL, 0, 10000);
    k_pool_split<1><<<(240000 * 16 + 255) / 256, 256, 0, stream>>>(bufA, adj1, PH, PL, 10000, 240000);
    k_pool_split<2><<<(360000 * 16 + 255) / 256, 256, 0, stream>>>(bufA, adj2, PH, PL, 250000, 360000);
    k_pool_split<3><<<(250000 * 16 + 255) / 256, 256, 0, stream>>>(bufA, adj3, PH, PL, 610000, 250000);
    k_pool_split<4><<<(140000 * 16 + 255) / 256, 256, 0, stream>>>(bufA, adj4, PH, PL, 860000, 140000);

    // ---- counting sort by membership + subtile meta + dense W frag prep ----
    k_zero_bins<<<(40000 + 255) / 256, 256, 0, stream>>>(binCnt, binFill);
    k_hist<<<(1000000 + 255) / 256, 256, 0, stream>>>(memb, binCnt);
    k_scan<<<1, 1024, 0, stream>>>(binCnt, binBase);
    k_scatter<<<(1000000 + 255) / 256, 256, 0, stream>>>(memb, binBase, binFill, perm);
    k_meta<<<(125000 + 255) / 256, 256, 0, stream>>>(memb, perm, firstSeg, segCnt);
    k_scan2<<<1, 1024, 0, stream>>>(segCnt, cumSeg);
    k_prepW<<<16, 256, 0, stream>>>(dW, dWh, dWl);

    // ---- dense via MFMA + tanh + bn3 -> subtile partials ----
    k_dense_mfma<<<15625, 256, 0, stream>>>(PH, PL, memb, perm, cumSeg, dWh, dWl,
        db, bn3g, bn3b, bn3m, bn3v, partials);

    // ---- combine partials -> out (fully overwrites d_out incl. frag regions) ----
    k_combine<<<10000, 256, 0, stream>>>(partials, binBase, binCnt,
        firstSeg, cumSeg, out);
}

// Round 12
// 3176.778 us; speedup vs baseline: 1.0182x; 1.0182x over previous
//
#include <hip/hip_runtime.h>
#include <hip/hip_bf16.h>
#include <cstdint>
#include <cstddef>

#define BN_EPS 1e-3f
typedef unsigned short ushort_t;
typedef unsigned int uint_t;
typedef __attribute__((ext_vector_type(8))) short short8v;   // 8 bf16 (4 VGPRs)
typedef __attribute__((ext_vector_type(4))) float f32x4;     // MFMA C/D

// ---------- numeric helpers ----------

__device__ __forceinline__ float fast_tanh(float x) {
    float xc = fminf(fmaxf(x, -12.0f), 12.0f);
    float e = __expf(2.0f * xc);
    return (e - 1.0f) / (e + 1.0f);
}

__device__ __forceinline__ float bf2f(uint_t u) {
    return __uint_as_float(u << 16);
}
__device__ __forceinline__ ushort_t f2bf(float f) {
    union { __hip_bfloat16 h; ushort_t u; } cv;
    cv.h = __float2bfloat16(f);   // RNE
    return cv.u;
}

// split 8 f32 -> 8 bf16 hi + 8 bf16 lo (lo = bf16(x - hi)), packed 16B each
__device__ __forceinline__ void split8(const float* f, uint4& h, uint4& lo) {
    uint_t hh[8], ll[8];
    #pragma unroll
    for (int j = 0; j < 8; ++j) {
        float x = f[j];
        ushort_t xh = f2bf(x);
        float xr = x - bf2f(xh);
        hh[j] = xh;
        ll[j] = f2bf(xr);
    }
    h  = make_uint4(hh[0] | (hh[1] << 16), hh[2] | (hh[3] << 16),
                    hh[4] | (hh[5] << 16), hh[6] | (hh[7] << 16));
    lo = make_uint4(ll[0] | (ll[1] << 16), ll[2] | (ll[3] << 16),
                    ll[4] | (ll[5] << 16), ll[6] | (ll[7] << 16));
}

// ---------- counting sort of atoms by membership (ascending) ----------

__global__ void k_zero_bins(int* __restrict__ binCnt, int* __restrict__ binFill) {
    int t = blockIdx.x * 256 + threadIdx.x;
    if (t < 40000) { binCnt[t] = 0; binFill[t] = 0; }
}

__global__ void k_hist(const int* __restrict__ memb, int* __restrict__ binCnt) {
    int t = blockIdx.x * 256 + threadIdx.x;
    if (t < 1000000) atomicAdd(&binCnt[memb[t]], 1);
}

__global__ __launch_bounds__(1024)
void k_scan(const int* __restrict__ binCnt, int* __restrict__ binBase) {
    __shared__ int part[1024];
    const int t = threadIdx.x;
    const int base = t * 40;
    int local[40];
    int s = 0;
    #pragma unroll
    for (int j = 0; j < 40; ++j) {
        int idx = base + j;
        int c = (idx < 40000) ? binCnt[idx] : 0;
        local[j] = s;
        s += c;
    }
    part[t] = s;
    __syncthreads();
    for (int off = 1; off < 1024; off <<= 1) {
        int v = (t >= off) ? part[t - off] : 0;
        __syncthreads();
        part[t] += v;
        __syncthreads();
    }
    int add = (t > 0) ? part[t - 1] : 0;
    #pragma unroll
    for (int j = 0; j < 40; ++j) {
        int idx = base + j;
        if (idx < 40000) binBase[idx] = add + local[j];
    }
}

// scatter: invperm[t] = sorted position of atom t; sortedMemb[pos] = membership
__global__ void k_scatter(const int* __restrict__ memb, const int* __restrict__ binBase,
                          int* __restrict__ binFill,
                          int* __restrict__ invperm, int* __restrict__ sortedMemb) {
    int t = blockIdx.x * 256 + threadIdx.x;
    if (t < 1000000) {
        int m = memb[t];
        int pos = binBase[m] + atomicAdd(&binFill[m], 1);
        invperm[t] = pos;
        sortedMemb[pos] = m;
    }
}

// ---------- subtile metadata: 125000 subtiles of 8 sorted rows ----------

__global__ void k_meta(const int* __restrict__ sortedMemb,
                       int* __restrict__ firstSeg, int* __restrict__ segCnt) {
    int t = blockIdx.x * 256 + threadIdx.x;
    if (t < 125000) {
        int f = sortedMemb[8 * t];
        int l = sortedMemb[8 * t + 7];
        firstSeg[t] = f;
        segCnt[t] = l - f + 1;
    }
}

__global__ __launch_bounds__(1024)
void k_scan2(const int* __restrict__ segCnt, int* __restrict__ cumSeg) {
    __shared__ int part[1024];
    const int t = threadIdx.x;
    const int base = t * 123;
    int s = 0;
    for (int j = 0; j < 123; ++j) {
        int idx = base + j;
        if (idx < 125000) s += segCnt[idx];
    }
    part[t] = s;
    __syncthreads();
    for (int off = 1; off < 1024; off <<= 1) {
        int v = (t >= off) ? part[t - off] : 0;
        __syncthreads();
        part[t] += v;
        __syncthreads();
    }
    int run = (t > 0) ? part[t - 1] : 0;
    for (int j = 0; j < 123; ++j) {
        int idx = base + j;
        if (idx < 125000) { cumSeg[idx] = run; run += segCnt[idx]; }
    }
}

// ---------- copy combine-metadata out of d_out (into bufA tail) ----------

__global__ void k_copymeta(const int* __restrict__ binBase, const int* __restrict__ binCnt,
                           const int* __restrict__ firstSeg, const int* __restrict__ cumSeg,
                           int* __restrict__ dBinBase, int* __restrict__ dBinCnt,
                           int* __restrict__ dFirstSeg, int* __restrict__ dCumSeg) {
    int t = blockIdx.x * 256 + threadIdx.x;
    if (t < 40000) { dBinBase[t] = binBase[t]; dBinCnt[t] = binCnt[t]; }
    if (t < 125000) { dFirstSeg[t] = firstSeg[t]; dCumSeg[t] = cumSeg[t]; }
}

// ---------- W fragment prep: dense [128][256] ----------
// fid = (tn*4 + ks)*64 + lane; lane j holds W[ks*32 + (lane>>4)*8 + j][tn*16 + (lane&15)]

__global__ void k_prepW(const float* __restrict__ W,
                        ushort_t* __restrict__ Bh, ushort_t* __restrict__ Bl) {
    int idx = blockIdx.x * 256 + threadIdx.x;
    if (idx >= 4096) return;
    int l = idx & 63, g = idx >> 6;       // g = tn*4 + ks
    int tn = g >> 2, ks = g & 3;
    int n = tn * 16 + (l & 15);
    int k0 = ks * 32 + (l >> 4) * 8;
    float f[8];
    #pragma unroll
    for (int j = 0; j < 8; ++j) f[j] = W[(size_t)(k0 + j) * 256 + n];
    uint4 h, lo; split8(f, h, lo);
    *(uint4*)(Bh + (size_t)idx * 8) = h;
    *(uint4*)(Bl + (size_t)idx * 8) = lo;
}

// ---------- W fragment prep: gc2's 9 matrices [128][128] (5 self + 4 rel) ----------

__global__ void k_prepW2(const float* __restrict__ Ws5, const float* __restrict__ Wr4,
                         ushort_t* __restrict__ Fh, ushort_t* __restrict__ Fl) {
    int idx = blockIdx.x * 256 + threadIdx.x;   // [0, 9*2048)
    if (idx >= 18432) return;
    int mat = idx >> 11;
    int fid = idx & 2047;
    int l = fid & 63, g = fid >> 6;
    int tn = g >> 2, ks = g & 3;
    int n = tn * 16 + (l & 15);
    int k0 = ks * 32 + (l >> 4) * 8;
    const float* W = (mat < 5) ? (Ws5 + (size_t)mat * 16384)
                               : (Wr4 + (size_t)(mat - 5) * 16384);
    float f[8];
    #pragma unroll
    for (int j = 0; j < 8; ++j) f[j] = W[(size_t)(k0 + j) * 128 + n];
    uint4 h, lo; split8(f, h, lo);
    *(uint4*)(Fh + (size_t)idx * 8) = h;
    *(uint4*)(Fl + (size_t)idx * 8) = lo;
}

// ---------- W fragment prep: gc1's 9 matrices [75][128], K padded to 96 ----------

__global__ void k_prepW1(const float* __restrict__ Ws5, const float* __restrict__ Wr4,
                         ushort_t* __restrict__ Fh, ushort_t* __restrict__ Fl) {
    int idx = blockIdx.x * 256 + threadIdx.x;   // [0, 9*1536)
    if (idx >= 13824) return;
    int mat = idx / 1536;
    int fid = idx - mat * 1536;
    int l = fid & 63, g = fid >> 6;             // g = tn*3 + ks
    int tn = g / 3, ks = g - tn * 3;
    int n = tn * 16 + (l & 15);
    int k0 = ks * 32 + (l >> 4) * 8;
    const float* W = (mat < 5) ? (Ws5 + (size_t)mat * 9600)
                               : (Wr4 + (size_t)(mat - 5) * 9600);
    float f[8];
    #pragma unroll
    for (int j = 0; j < 8; ++j)
        f[j] = (k0 + j < 75) ? W[(size_t)(k0 + j) * 128 + n] : 0.0f;
    uint4 h, lo; split8(f, h, lo);
    *(uint4*)(Fh + (size_t)idx * 8) = h;
    *(uint4*)(Fl + (size_t)idx * 8) = lo;
}

// ---------- gc1 via MFMA split-bf16 (tanh + bn1 fused), K=75 padded to 96 ----------
// v2 staging: thread owns (row, 8-k chunk), b128 LDS writes.

template<int DEG>
__global__ __launch_bounds__(256)
void k_gc1m(const float* __restrict__ X, const int* __restrict__ adj,
            const ushort_t* __restrict__ Wsh, const ushort_t* __restrict__ Wsl,
            const ushort_t* __restrict__ Wrh, const ushort_t* __restrict__ Wrl,
            const float* __restrict__ bias,
            const float* __restrict__ bg, const float* __restrict__ bb,
            const float* __restrict__ bm, const float* __restrict__ bv,
            float* __restrict__ Out, int start, int count)
{
    __shared__ __align__(16) ushort_t Sh[64 * 128];
    __shared__ __align__(16) ushort_t Sl[64 * 128];
    __shared__ __align__(16) ushort_t Nh[(DEG > 0) ? 64 * 128 : 8];
    __shared__ __align__(16) ushort_t Nl[(DEG > 0) ? 64 * 128 : 8];

    const int tid = threadIdx.x;
    const int tileBase = blockIdx.x * 64;

    for (int idx = tid; idx < 64 * 12; idx += 256) {
        int a = idx / 12;
        int c = idx - a * 12;
        int k0 = c * 8;
        int ga = tileBase + a;
        float fs[8] = {0, 0, 0, 0, 0, 0, 0, 0};
        float fn[8] = {0, 0, 0, 0, 0, 0, 0, 0};
        if (ga < count) {
            const float* row = X + (size_t)(start + ga) * 75;
            #pragma unroll
            for (int j = 0; j < 8; ++j) {
                int k = k0 + j;
                if (k < 75) fs[j] = row[k];
            }
            if constexpr (DEG > 0) {
                #pragma unroll
                for (int jj = 0; jj < DEG; ++jj) {
                    int nb = adj[(size_t)ga * DEG + jj];
                    const float* nr = X + (size_t)nb * 75;
                    #pragma unroll
                    for (int j = 0; j < 8; ++j) {
                        int k = k0 + j;
                        if (k < 75) fn[j] += nr[k];
                    }
                }
            }
        }
        int cs = c ^ (a & 15);
        uint4 h, lo;
        split8(fs, h, lo);
        *(uint4*)(Sh + a * 128 + cs * 8) = h;
        *(uint4*)(Sl + a * 128 + cs * 8) = lo;
        if constexpr (DEG > 0) {
            split8(fn, h, lo);
            *(uint4*)(Nh + a * 128 + cs * 8) = h;
            *(uint4*)(Nl + a * 128 + cs * 8) = lo;
        }
    }
    __syncthreads();

    const int w = tid >> 6, l = tid & 63;
    const int lm = l & 15, lq = l >> 4;

    f32x4 acc[4][2];
    #pragma unroll
    for (int rt = 0; rt < 4; ++rt)
        #pragma unroll
        for (int ti = 0; ti < 2; ++ti)
            acc[rt][ti] = (f32x4){0.f, 0.f, 0.f, 0.f};

    for (int ks = 0; ks < 3; ++ks) {
        short8v ash[4], asl[4], anh[4], anl[4];
        #pragma unroll
        for (int rt = 0; rt < 4; ++rt) {
            int a = rt * 16 + lm;
            int cs = (ks * 4 + lq) ^ lm;
            ash[rt] = *(const short8v*)(Sh + a * 128 + cs * 8);
            asl[rt] = *(const short8v*)(Sl + a * 128 + cs * 8);
            if constexpr (DEG > 0) {
                anh[rt] = *(const short8v*)(Nh + a * 128 + cs * 8);
                anl[rt] = *(const short8v*)(Nl + a * 128 + cs * 8);
            }
        }
        #pragma unroll
        for (int ti = 0; ti < 2; ++ti) {
            int fid = ((w + ti * 4) * 3 + ks) * 64 + l;
            short8v bh = *(const short8v*)(Wsh + (size_t)fid * 8);
            short8v bl = *(const short8v*)(Wsl + (size_t)fid * 8);
            #pragma unroll
            for (int rt = 0; rt < 4; ++rt) {
                acc[rt][ti] = __builtin_amdgcn_mfma_f32_16x16x32_bf16(ash[rt], bh, acc[rt][ti], 0, 0, 0);
                acc[rt][ti] = __builtin_amdgcn_mfma_f32_16x16x32_bf16(asl[rt], bh, acc[rt][ti], 0, 0, 0);
                acc[rt][ti] = __builtin_amdgcn_mfma_f32_16x16x32_bf16(ash[rt], bl, acc[rt][ti], 0, 0, 0);
            }
            if constexpr (DEG > 0) {
                short8v rh = *(const short8v*)(Wrh + (size_t)fid * 8);
                short8v rl = *(const short8v*)(Wrl + (size_t)fid * 8);
                #pragma unroll
                for (int rt = 0; rt < 4; ++rt) {
                    acc[rt][ti] = __builtin_amdgcn_mfma_f32_16x16x32_bf16(anh[rt], rh, acc[rt][ti], 0, 0, 0);
                    acc[rt][ti] = __builtin_amdgcn_mfma_f32_16x16x32_bf16(anl[rt], rh, acc[rt][ti], 0, 0, 0);
                    acc[rt][ti] = __builtin_amdgcn_mfma_f32_16x16x32_bf16(anh[rt], rl, acc[rt][ti], 0, 0, 0);
                }
            }
        }
    }

    #pragma unroll
    for (int ti = 0; ti < 2; ++ti) {
        int cc = (w + ti * 4) * 16 + lm;
        float bz = bias[cc];
        float s = bg[cc] * rsqrtf(bv[cc] + BN_EPS);
        float sb = bb[cc] - bm[cc] * s;
        #pragma unroll
        for (int rt = 0; rt < 4; ++rt) {
            #pragma unroll
            for (int r = 0; r < 4; ++r) {
                int ga = tileBase + rt * 16 + lq * 4 + r;
                if (ga < count)
                    Out[(size_t)(start + ga) * 128 + cc] =
                        fast_tanh(acc[rt][ti][r] + bz) * s + sb;
            }
        }
    }
}

// ---------- gc2 via MFMA split-bf16 (tanh + bn1 fused) ----------

template<int DEG>
__global__ __launch_bounds__(256)
void k_gc2m(const float* __restrict__ X, const int* __restrict__ adj,
            const ushort_t* __restrict__ Wsh, const ushort_t* __restrict__ Wsl,
            const ushort_t* __restrict__ Wrh, const ushort_t* __restrict__ Wrl,
            const float* __restrict__ bias,
            const float* __restrict__ bg, const float* __restrict__ bb,
            const float* __restrict__ bm, const float* __restrict__ bv,
            float* __restrict__ Out, int start, int count)
{
    __shared__ __align__(16) ushort_t Sh[64 * 128];
    __shared__ __align__(16) ushort_t Sl[64 * 128];
    __shared__ __align__(16) ushort_t Nh[(DEG > 0) ? 64 * 128 : 8];
    __shared__ __align__(16) ushort_t Nl[(DEG > 0) ? 64 * 128 : 8];

    const int tid = threadIdx.x;
    const int tileBase = blockIdx.x * 64;

    for (int idx = tid; idx < 1024; idx += 256) {
        int a = idx >> 4, c = idx & 15;
        int ga = tileBase + a;
        float fs[8] = {0, 0, 0, 0, 0, 0, 0, 0};
        float fn[8] = {0, 0, 0, 0, 0, 0, 0, 0};
        if (ga < count) {
            const float* row = X + (size_t)(start + ga) * 128 + c * 8;
            *(float4*)(&fs[0]) = *(const float4*)row;
            *(float4*)(&fs[4]) = *(const float4*)(row + 4);
            if constexpr (DEG > 0) {
                #pragma unroll
                for (int j = 0; j < DEG; ++j) {
                    int nb = adj[(size_t)ga * DEG + j];
                    const float* nr = X + (size_t)nb * 128 + c * 8;
                    float4 q0 = *(const float4*)nr;
                    float4 q1 = *(const float4*)(nr + 4);
                    fn[0] += q0.x; fn[1] += q0.y; fn[2] += q0.z; fn[3] += q0.w;
                    fn[4] += q1.x; fn[5] += q1.y; fn[6] += q1.z; fn[7] += q1.w;
                }
            }
        }
        int cs = c ^ (a & 15);
        uint4 h, lo;
        split8(fs, h, lo);
        *(uint4*)(Sh + a * 128 + cs * 8) = h;
        *(uint4*)(Sl + a * 128 + cs * 8) = lo;
        if constexpr (DEG > 0) {
            split8(fn, h, lo);
            *(uint4*)(Nh + a * 128 + cs * 8) = h;
            *(uint4*)(Nl + a * 128 + cs * 8) = lo;
        }
    }
    __syncthreads();

    const int w = tid >> 6, l = tid & 63;
    const int lm = l & 15, lq = l >> 4;

    f32x4 acc[4][2];
    #pragma unroll
    for (int rt = 0; rt < 4; ++rt)
        #pragma unroll
        for (int ti = 0; ti < 2; ++ti)
            acc[rt][ti] = (f32x4){0.f, 0.f, 0.f, 0.f};

    for (int ks = 0; ks < 4; ++ks) {
        short8v ash[4], asl[4], anh[4], anl[4];
        #pragma unroll
        for (int rt = 0; rt < 4; ++rt) {
            int a = rt * 16 + lm;
            int cs = (ks * 4 + lq) ^ lm;
            ash[rt] = *(const short8v*)(Sh + a * 128 + cs * 8);
            asl[rt] = *(const short8v*)(Sl + a * 128 + cs * 8);
            if constexpr (DEG > 0) {
                anh[rt] = *(const short8v*)(Nh + a * 128 + cs * 8);
                anl[rt] = *(const short8v*)(Nl + a * 128 + cs * 8);
            }
        }
        #pragma unroll
        for (int ti = 0; ti < 2; ++ti) {
            int fid = ((w + ti * 4) * 4 + ks) * 64 + l;
            short8v bh = *(const short8v*)(Wsh + (size_t)fid * 8);
            short8v bl = *(const short8v*)(Wsl + (size_t)fid * 8);
            #pragma unroll
            for (int rt = 0; rt < 4; ++rt) {
                acc[rt][ti] = __builtin_amdgcn_mfma_f32_16x16x32_bf16(ash[rt], bh, acc[rt][ti], 0, 0, 0);
                acc[rt][ti] = __builtin_amdgcn_mfma_f32_16x16x32_bf16(asl[rt], bh, acc[rt][ti], 0, 0, 0);
                acc[rt][ti] = __builtin_amdgcn_mfma_f32_16x16x32_bf16(ash[rt], bl, acc[rt][ti], 0, 0, 0);
            }
            if constexpr (DEG > 0) {
                short8v rh = *(const short8v*)(Wrh + (size_t)fid * 8);
                short8v rl = *(const short8v*)(Wrl + (size_t)fid * 8);
                #pragma unroll
                for (int rt = 0; rt < 4; ++rt) {
                    acc[rt][ti] = __builtin_amdgcn_mfma_f32_16x16x32_bf16(anh[rt], rh, acc[rt][ti], 0, 0, 0);
                    acc[rt][ti] = __builtin_amdgcn_mfma_f32_16x16x32_bf16(anl[rt], rh, acc[rt][ti], 0, 0, 0);
                    acc[rt][ti] = __builtin_amdgcn_mfma_f32_16x16x32_bf16(anh[rt], rl, acc[rt][ti], 0, 0, 0);
                }
            }
        }
    }

    #pragma unroll
    for (int ti = 0; ti < 2; ++ti) {
        int cc = (w + ti * 4) * 16 + lm;
        float bz = bias[cc];
        float s = bg[cc] * rsqrtf(bv[cc] + BN_EPS);
        float sb = bb[cc] - bm[cc] * s;
        #pragma unroll
        for (int rt = 0; rt < 4; ++rt) {
            #pragma unroll
            for (int r = 0; r < 4; ++r) {
                int ga = tileBase + rt * 16 + lq * 4 + r;
                if (ga < count)
                    Out[(size_t)(start + ga) * 128 + cc] =
                        fast_tanh(acc[rt][ti][r] + bz) * s + sb;
            }
        }
    }
}

// ---------- graph pool (f32 -> f32), used for pool1 ----------

template<int DEG>
__global__ void k_pool(const float* __restrict__ X, const int* __restrict__ adj,
                       float* __restrict__ Out, int start, int count)
{
    int t = blockIdx.x * 256 + threadIdx.x;
    int a = t >> 5;
    if (a >= count) return;
    int c4 = t & 31;
    const float4* X4 = (const float4*)X;
    float4 v = X4[(size_t)(start + a) * 32 + c4];
    #pragma unroll
    for (int j = 0; j < DEG; ++j) {
        int nb = adj[(size_t)a * DEG + j];
        float4 q = X4[(size_t)nb * 32 + c4];
        v.x = fmaxf(v.x, q.x); v.y = fmaxf(v.y, q.y);
        v.z = fmaxf(v.z, q.z); v.w = fmaxf(v.w, q.w);
    }
    ((float4*)Out)[(size_t)(start + a) * 32 + c4] = v;
}

// ---------- pool2: f32 -> split bf16 planes, scattered to SORTED row position ----------

template<int DEG>
__global__ void k_pool_split(const float* __restrict__ X, const int* __restrict__ adj,
                             const int* __restrict__ invperm,
                             ushort_t* __restrict__ PH, ushort_t* __restrict__ PL,
                             int start, int count)
{
    int t = blockIdx.x * 256 + threadIdx.x;
    int a = t >> 4;
    if (a >= count) return;
    int c8 = (t & 15) * 8;
    const float* row = X + (size_t)(start + a) * 128 + c8;
    float f[8];
    *(float4*)(&f[0]) = *(const float4*)row;
    *(float4*)(&f[4]) = *(const float4*)(row + 4);
    #pragma unroll
    for (int j = 0; j < DEG; ++j) {
        int nb = adj[(size_t)a * DEG + j];
        const float* nr = X + (size_t)nb * 128 + c8;
        float4 q0 = *(const float4*)nr;
        float4 q1 = *(const float4*)(nr + 4);
        f[0] = fmaxf(f[0], q0.x); f[1] = fmaxf(f[1], q0.y);
        f[2] = fmaxf(f[2], q0.z); f[3] = fmaxf(f[3], q0.w);
        f[4] = fmaxf(f[4], q1.x); f[5] = fmaxf(f[5], q1.y);
        f[6] = fmaxf(f[6], q1.z); f[7] = fmaxf(f[7], q1.w);
    }
    uint4 h, lo; split8(f, h, lo);
    int dst = invperm[start + a];
    *(uint4*)(PH + (size_t)dst * 128 + c8) = h;
    *(uint4*)(PL + (size_t)dst * 128 + c8) = lo;
}

// ---------- dense via MFMA split-bf16 (tanh + bn3) + subtile partials ----------
// Rows are pre-sorted: staging is a fully-sequential coalesced copy.

__global__ __launch_bounds__(256)
void k_dense_mfma(const ushort_t* __restrict__ PH,  // [1M][128] bf16 hi, sorted rows
                  const ushort_t* __restrict__ PL,  // [1M][128] bf16 lo, sorted rows
                  const int*   __restrict__ sortedMemb,  // [1M]
                  const int*   __restrict__ cumSeg,      // [125000]
                  const ushort_t* __restrict__ Bh,   // W frag hi [4096][8]
                  const ushort_t* __restrict__ Bl,   // W frag lo
                  const float* __restrict__ bias,    // [256]
                  const float* __restrict__ bg, const float* __restrict__ bb,
                  const float* __restrict__ bm, const float* __restrict__ bv,
                  float* __restrict__ partials)
{
    __shared__ __align__(16) char smem[33792];   // Ah[16KB]+Al[16KB] / Yt[64][132]f32
    __shared__ int sM[64];
    ushort_t* Ah = (ushort_t*)smem;
    ushort_t* Al = (ushort_t*)(smem + 16384);
    float*    Yt = (float*)smem;

    const int tid = threadIdx.x;
    const int tileBase = blockIdx.x * 64;
    if (tid < 64) sM[tid] = sortedMemb[tileBase + tid];

    // staging: sequential coalesced copy of pre-split 16B chunks (swizzled)
    for (int idx = tid; idx < 1024; idx += 256) {
        int a = idx >> 4, c = idx & 15;
        size_t off = (size_t)(tileBase + a) * 128 + c * 8;
        uint4 h  = *(const uint4*)(PH + off);
        uint4 lo = *(const uint4*)(PL + off);
        int cs = c ^ (a & 15);
        *(uint4*)(Ah + a * 128 + cs * 8) = h;
        *(uint4*)(Al + a * 128 + cs * 8) = lo;
    }
    __syncthreads();

    const int w = tid >> 6, l = tid & 63;
    const int lm = l & 15, lq = l >> 4;

    f32x4 acc[4][4];
    #pragma unroll
    for (int rt = 0; rt < 4; ++rt)
        #pragma unroll
        for (int ti = 0; ti < 4; ++ti)
            acc[rt][ti] = (f32x4){0.f, 0.f, 0.f, 0.f};

    for (int ks = 0; ks < 4; ++ks) {
        short8v ah[4], al[4];
        #pragma unroll
        for (int rt = 0; rt < 4; ++rt) {
            int a = rt * 16 + lm;
            int cs = (ks * 4 + lq) ^ lm;
            ah[rt] = *(const short8v*)(Ah + a * 128 + cs * 8);
            al[rt] = *(const short8v*)(Al + a * 128 + cs * 8);
        }
        #pragma unroll
        for (int ti = 0; ti < 4; ++ti) {
            int fid = ((w + ti * 4) * 4 + ks) * 64 + l;
            short8v bh = *(const short8v*)(Bh + (size_t)fid * 8);
            short8v bl = *(const short8v*)(Bl + (size_t)fid * 8);
            #pragma unroll
            for (int rt = 0; rt < 4; ++rt) {
                acc[rt][ti] = __builtin_amdgcn_mfma_f32_16x16x32_bf16(ah[rt], bh, acc[rt][ti], 0, 0, 0);
                acc[rt][ti] = __builtin_amdgcn_mfma_f32_16x16x32_bf16(al[rt], bh, acc[rt][ti], 0, 0, 0);
                acc[rt][ti] = __builtin_amdgcn_mfma_f32_16x16x32_bf16(ah[rt], bl, acc[rt][ti], 0, 0, 0);
            }
        }
    }

    float bvz[4], scv[4], shv[4];
    #pragma unroll
    for (int ti = 0; ti < 4; ++ti) {
        int c = (w + ti * 4) * 16 + lm;
        bvz[ti] = bias[c];
        float s = bg[c] * rsqrtf(bv[c] + BN_EPS);
        scv[ti] = s;
        shv[ti] = bb[c] - bm[c] * s;
    }

    const int q = tid >> 5, cg = tid & 31;
    const int sub = blockIdx.x * 8 + q;
    const size_t slotBase = (size_t)cumSeg[sub];
    const int fs = sM[q * 8];

    #pragma unroll
    for (int hf = 0; hf < 2; ++hf) {
        __syncthreads();
        #pragma unroll
        for (int tj = 0; tj < 2; ++tj) {
            int ti = 2 * hf + tj;
            int colh = (w + ti * 4) * 16 + lm - hf * 128;
            #pragma unroll
            for (int rt = 0; rt < 4; ++rt)
                #pragma unroll
                for (int r = 0; r < 4; ++r) {
                    int row = rt * 16 + lq * 4 + r;
                    float y = fast_tanh(acc[rt][ti][r] + bvz[ti]) * scv[ti] + shv[ti];
                    Yt[row * 132 + colh] = y;
                }
        }
        __syncthreads();

        float4 ys, ym;
        int cur = sM[q * 8];
        {
            float4 v = *(const float4*)(Yt + (q * 8) * 132 + cg * 4);
            ys = v; ym = v;
        }
        #pragma unroll
        for (int i = 1; i < 8; ++i) {
            float4 v = *(const float4*)(Yt + (q * 8 + i) * 132 + cg * 4);
            int m = sM[q * 8 + i];
            if (m == cur) {
                ys.x += v.x; ys.y += v.y; ys.z += v.z; ys.w += v.w;
                ym.x = fmaxf(ym.x, v.x); ym.y = fmaxf(ym.y, v.y);
                ym.z = fmaxf(ym.z, v.z); ym.w = fmaxf(ym.w, v.w);
            } else {
                float* p = partials + (slotBase + (cur - fs)) * 512 + hf * 128 + cg * 4;
                *(float4*)p         = ys;
                *(float4*)(p + 256) = ym;
                cur = m; ys = v; ym = v;
            }
        }
        float* p = partials + (slotBase + (cur - fs)) * 512 + hf * 128 + cg * 4;
        *(float4*)p         = ys;
        *(float4*)(p + 256) = ym;
    }
}

// ---------- combine partials -> final out (tanh fused) ----------

__global__ __launch_bounds__(256)
void k_combine(const float* __restrict__ partials,
               const int* __restrict__ binBase, const int* __restrict__ binCnt,
               const int* __restrict__ firstSeg, const int* __restrict__ cumSeg,
               float* __restrict__ Out)
{
    int sid = blockIdx.x * 4 + (threadIdx.x >> 6);
    if (sid >= 40000) return;
    int lane = threadIdx.x & 63;
    int b = binBase[sid], n = binCnt[sid];

    float4 s = make_float4(0.f, 0.f, 0.f, 0.f);
    float4 m = make_float4(-INFINITY, -INFINITY, -INFINITY, -INFINITY);
    if (n > 0) {
        int s0 = b >> 3, s1 = (b + n - 1) >> 3;
        for (int t = s0; t <= s1; ++t) {
            size_t slot = (size_t)cumSeg[t] + (sid - firstSeg[t]);
            const float4* P = (const float4*)(partials + slot * 512);
            float4 a = P[lane];
            float4 x = P[64 + lane];
            s.x += a.x; s.y += a.y; s.z += a.z; s.w += a.w;
            m.x = fmaxf(m.x, x.x); m.y = fmaxf(m.y, x.y);
            m.z = fmaxf(m.z, x.z); m.w = fmaxf(m.w, x.w);
        }
    }
    float4 os = make_float4(fast_tanh(s.x), fast_tanh(s.y), fast_tanh(s.z), fast_tanh(s.w));
    float4 om = make_float4(fast_tanh(m.x), fast_tanh(m.y), fast_tanh(m.z), fast_tanh(m.w));
    *(float4*)(Out + (size_t)sid * 512 + lane * 4)       = os;
    *(float4*)(Out + (size_t)sid * 512 + 256 + lane * 4) = om;
}

// ---------- launcher ----------

extern "C" void kernel_launch(void* const* d_in, const int* in_sizes, int n_in,
                              void* d_out, int out_size, void* d_ws, size_t ws_size,
                              hipStream_t stream)
{
    const float* atom = (const float*)d_in[0];
    const int*   memb = (const int*)d_in[1];
    const int*   adj1 = (const int*)d_in[2];
    const int*   adj2 = (const int*)d_in[3];
    const int*   adj3 = (const int*)d_in[4];
    const int*   adj4 = (const int*)d_in[5];
    const float* g1Ws = (const float*)d_in[6];
    const float* g1Wr = (const float*)d_in[7];
    const float* g1b  = (const float*)d_in[8];
    const float* g2Ws = (const float*)d_in[9];
    const float* g2Wr = (const float*)d_in[10];
    const float* g2b  = (const float*)d_in[11];
    const float* bn1g = (const float*)d_in[12];
    const float* bn1b = (const float*)d_in[13];
    const float* bn1m = (const float*)d_in[14];
    const float* bn1v = (const float*)d_in[15];
    const float* bn3g = (const float*)d_in[16];
    const float* bn3b = (const float*)d_in[17];
    const float* bn3m = (const float*)d_in[18];
    const float* bn3v = (const float*)d_in[19];
    const float* dW   = (const float*)d_in[20];
    const float* db   = (const float*)d_in[21];

    char* ws = (char*)d_ws;
    float* bufA = (float*)ws;                    // [1M][128] f32, 512 MB
    float* bufB = (float*)(ws + 512000000);      // [1M][128] f32, 512 MB
    char*  outc = (char*)d_out;                  // [40000][512] f32 = 81.92 MB
    float* out  = (float*)d_out;

    // pool2 split planes (sorted row order) live in bufB:
    ushort_t* PH = (ushort_t*)bufB;              // 256 MB
    ushort_t* PL = PH + (size_t)1000000 * 128;   // 256 MB

    // temp regions in d_out (all fully overwritten by k_combine at the end):
    ushort_t* gFh   = (ushort_t*)(outc);              // gc2 frags 294,912 B
    ushort_t* gFl   = (ushort_t*)(outc + 294912);
    ushort_t* g1Fh  = (ushort_t*)(outc + 589824);     // gc1 frags 221,184 B
    ushort_t* g1Fl  = (ushort_t*)(outc + 811008);
    ushort_t* dWh   = (ushort_t*)(outc + 1032192);    // dense frags 65,536 B
    ushort_t* dWl   = (ushort_t*)(outc + 1097728);
    int* invperm    = (int*)(outc + 1200000);         // 4,000,000 B
    int* sortedMemb = (int*)(outc + 5200000);         // 4,000,000 B
    int* binCnt     = (int*)(outc + 9200000);         // 160,000 B
    int* binBase    = (int*)(outc + 9360000);
    int* binFill    = (int*)(outc + 9520000);
    int* firstSeg   = (int*)(outc + 9680000);         // 500,000 B
    int* segCnt     = (int*)(outc + 10180000);
    int* cumSeg     = (int*)(outc + 10680000);        // ends ~11.2 MB << 82 MB

    // partials + combine-metadata copies live in bufA (dead after pool_split):
    float* partials = bufA;                           // <=165k slots x 2 KB = 338 MB
    int* cBinBase   = (int*)(ws + 400000000);
    int* cBinCnt    = (int*)(ws + 401000000);
    int* cFirstSeg  = (int*)(ws + 402000000);
    int* cCumSeg    = (int*)(ws + 403000000);

    // ---- W fragment prep + counting sort (depend only on inputs) ----
    k_prepW2<<<72, 256, 0, stream>>>(g2Ws, g2Wr, gFh, gFl);
    k_prepW1<<<54, 256, 0, stream>>>(g1Ws, g1Wr, g1Fh, g1Fl);
    k_prepW<<<16, 256, 0, stream>>>(dW, dWh, dWl);
    k_zero_bins<<<(40000 + 255) / 256, 256, 0, stream>>>(binCnt, binFill);
    k_hist<<<(1000000 + 255) / 256, 256, 0, stream>>>(memb, binCnt);
    k_scan<<<1, 1024, 0, stream>>>(binCnt, binBase);
    k_scatter<<<(1000000 + 255) / 256, 256, 0, stream>>>(memb, binBase, binFill,
        invperm, sortedMemb);
    k_meta<<<(125000 + 255) / 256, 256, 0, stream>>>(sortedMemb, firstSeg, segCnt);
    k_scan2<<<1, 1024, 0, stream>>>(segCnt, cumSeg);

    // ---- gc1 (MFMA): atom -> bufA ----
    k_gc1m<0><<<(10000 + 63) / 64, 256, 0, stream>>>(atom, nullptr,
        g1Fh + (size_t)0 * 1536 * 8, g1Fl + (size_t)0 * 1536 * 8,
        nullptr, nullptr, g1b + 0 * 128,
        bn1g, bn1b, bn1m, bn1v, bufA, 0, 10000);
    k_gc1m<1><<<(240000 + 63) / 64, 256, 0, stream>>>(atom, adj1,
        g1Fh + (size_t)1 * 1536 * 8, g1Fl + (size_t)1 * 1536 * 8,
        g1Fh + (size_t)5 * 1536 * 8, g1Fl + (size_t)5 * 1536 * 8, g1b + 1 * 128,
        bn1g, bn1b, bn1m, bn1v, bufA, 10000, 240000);
    k_gc1m<2><<<(360000 + 63) / 64, 256, 0, stream>>>(atom, adj2,
        g1Fh + (size_t)2 * 1536 * 8, g1Fl + (size_t)2 * 1536 * 8,
        g1Fh + (size_t)6 * 1536 * 8, g1Fl + (size_t)6 * 1536 * 8, g1b + 2 * 128,
        bn1g, bn1b, bn1m, bn1v, bufA, 250000, 360000);
    k_gc1m<3><<<(250000 + 63) / 64, 256, 0, stream>>>(atom, adj3,
        g1Fh + (size_t)3 * 1536 * 8, g1Fl + (size_t)3 * 1536 * 8,
        g1Fh + (size_t)7 * 1536 * 8, g1Fl + (size_t)7 * 1536 * 8, g1b + 3 * 128,
        bn1g, bn1b, bn1m, bn1v, bufA, 610000, 250000);
    k_gc1m<4><<<(140000 + 63) / 64, 256, 0, stream>>>(atom, adj4,
        g1Fh + (size_t)4 * 1536 * 8, g1Fl + (size_t)4 * 1536 * 8,
        g1Fh + (size_t)8 * 1536 * 8, g1Fl + (size_t)8 * 1536 * 8, g1b + 4 * 128,
        bn1g, bn1b, bn1m, bn1v, bufA, 860000, 140000);

    // ---- pool1: bufA -> bufB (f32) ----
    k_pool<0><<<(10000 + 7) / 8, 256, 0, stream>>>(bufA, nullptr, bufB, 0, 10000);
    k_pool<1><<<(240000 + 7) / 8, 256, 0, stream>>>(bufA, adj1, bufB, 10000, 240000);
    k_pool<2><<<(360000 + 7) / 8, 256, 0, stream>>>(bufA, adj2, bufB, 250000, 360000);
    k_pool<3><<<(250000 + 7) / 8, 256, 0, stream>>>(bufA, adj3, bufB, 610000, 250000);
    k_pool<4><<<(140000 + 7) / 8, 256, 0, stream>>>(bufA, adj4, bufB, 860000, 140000);

    // ---- gc2 (MFMA): bufB -> bufA ----
    k_gc2m<0><<<(10000 + 63) / 64, 256, 0, stream>>>(bufB, nullptr,
        gFh + (size_t)0 * 2048 * 8, gFl + (size_t)0 * 2048 * 8,
        nullptr, nullptr, g2b + 0 * 128,
        bn1g, bn1b, bn1m, bn1v, bufA, 0, 10000);
    k_gc2m<1><<<(240000 + 63) / 64, 256, 0, stream>>>(bufB, adj1,
        gFh + (size_t)1 * 2048 * 8, gFl + (size_t)1 * 2048 * 8,
        gFh + (size_t)5 * 2048 * 8, gFl + (size_t)5 * 2048 * 8, g2b + 1 * 128,
        bn1g, bn1b, bn1m, bn1v, bufA, 10000, 240000);
    k_gc2m<2><<<(360000 + 63) / 64, 256, 0, stream>>>(bufB, adj2,
        gFh + (size_t)2 * 2048 * 8, gFl + (size_t)2 * 2048 * 8,
        gFh + (size_t)6 * 2048 * 8, gFl + (size_t)6 * 2048 * 8, g2b + 2 * 128,
        bn1g, bn1b, bn1m, bn1v, bufA, 250000, 360000);
    k_gc2m<3><<<(250000 + 63) / 64, 256, 0, stream>>>(bufB, adj3,
        gFh + (size_t)3 * 2048 * 8, gFl + (size_t)3 * 2048 * 8,
        gFh + (size_t)7 * 2048 * 8, gFl + (size_t)7 * 2048 * 8, g2b + 3 * 128,
        bn1g, bn1b, bn1m, bn1v, bufA, 610000, 250000);
    k_gc2m<4><<<(140000 + 63) / 64, 256, 0, stream>>>(bufB, adj4,
        gFh + (size_t)4 * 2048 * 8, gFl + (size_t)4 * 2048 * 8,
        gFh + (size_t)8 * 2048 * 8, gFl + (size_t)8 * 2048 * 8, g2b + 4 * 128,
        bn1g, bn1b, bn1m, bn1v, bufA, 860000, 140000);

    // ---- pool2: bufA -> PH/PL at sorted positions (scattered writes) ----
    k_pool_split<0><<<(10000 * 16 + 255) / 256, 256, 0, stream>>>(bufA, nullptr, invperm, PH, PL, 0, 10000);
    k_pool_split<1><<<(240000 * 16 + 255) / 256, 256, 0, stream>>>(bufA, adj1, invperm, PH, PL, 10000, 240000);
    k_pool_split<2><<<(360000 * 16 + 255) / 256, 256, 0, stream>>>(bufA, adj2, invperm, PH, PL, 250000, 360000);
    k_pool_split<3><<<(250000 * 16 + 255) / 256, 256, 0, stream>>>(bufA, adj3, invperm, PH, PL, 610000, 250000);
    k_pool_split<4><<<(140000 * 16 + 255) / 256, 256, 0, stream>>>(bufA, adj4, invperm, PH, PL, 860000, 140000);

    // ---- copy combine-metadata out of d_out into bufA tail (bufA now dead) ----
    k_copymeta<<<(125000 + 255) / 256, 256, 0, stream>>>(binBase, binCnt,
        firstSeg, cumSeg, cBinBase, cBinCnt, cFirstSeg, cCumSeg);

    // ---- dense (MFMA, sequential staging) -> partials in bufA ----
    k_dense_mfma<<<15625, 256, 0, stream>>>(PH, PL, sortedMemb, cumSeg, dWh, dWl,
        db, bn3g, bn3b, bn3m, bn3v, partials);

    // ---- combine partials -> out (reads metadata from bufA copies) ----
    k_combine<<<10000, 256, 0, stream>>>(partials, cBinBase, cBinCnt,
        cFirstSeg, cCumSeg, out);
}

// Round 13
// 3114.851 us; speedup vs baseline: 1.0384x; 1.0199x over previous
//
#include <hip/hip_runtime.h>
#include <hip/hip_bf16.h>
#include <cstdint>
#include <cstddef>

#define BN_EPS 1e-3f
typedef unsigned short ushort_t;
typedef unsigned int uint_t;
typedef __attribute__((ext_vector_type(8))) short short8v;   // 8 bf16 (4 VGPRs)
typedef __attribute__((ext_vector_type(4))) float f32x4;     // MFMA C/D

// ---------- numeric helpers ----------

__device__ __forceinline__ float fast_tanh(float x) {
    float xc = fminf(fmaxf(x, -12.0f), 12.0f);
    float e = __expf(2.0f * xc);
    // hardware rcp (~1 ulp) instead of full-precision division sequence
    return (e - 1.0f) * __builtin_amdgcn_rcpf(e + 1.0f);
}

__device__ __forceinline__ float bf2f(uint_t u) {
    return __uint_as_float(u << 16);
}
__device__ __forceinline__ ushort_t f2bf(float f) {
    union { __hip_bfloat16 h; ushort_t u; } cv;
    cv.h = __float2bfloat16(f);   // RNE
    return cv.u;
}

// split 8 f32 -> 8 bf16 hi + 8 bf16 lo (lo = bf16(x - hi)), packed 16B each
__device__ __forceinline__ void split8(const float* f, uint4& h, uint4& lo) {
    uint_t hh[8], ll[8];
    #pragma unroll
    for (int j = 0; j < 8; ++j) {
        float x = f[j];
        ushort_t xh = f2bf(x);
        float xr = x - bf2f(xh);
        hh[j] = xh;
        ll[j] = f2bf(xr);
    }
    h  = make_uint4(hh[0] | (hh[1] << 16), hh[2] | (hh[3] << 16),
                    hh[4] | (hh[5] << 16), hh[6] | (hh[7] << 16));
    lo = make_uint4(ll[0] | (ll[1] << 16), ll[2] | (ll[3] << 16),
                    ll[4] | (ll[5] << 16), ll[6] | (ll[7] << 16));
}

// ---------- counting sort of atoms by membership (ascending) ----------

__global__ void k_zero_bins(int* __restrict__ binCnt, int* __restrict__ binFill) {
    int t = blockIdx.x * 256 + threadIdx.x;
    if (t < 40000) { binCnt[t] = 0; binFill[t] = 0; }
}

__global__ void k_hist(const int* __restrict__ memb, int* __restrict__ binCnt) {
    int t = blockIdx.x * 256 + threadIdx.x;
    if (t < 1000000) atomicAdd(&binCnt[memb[t]], 1);
}

__global__ __launch_bounds__(1024)
void k_scan(const int* __restrict__ binCnt, int* __restrict__ binBase) {
    __shared__ int part[1024];
    const int t = threadIdx.x;
    const int base = t * 40;
    int local[40];
    int s = 0;
    #pragma unroll
    for (int j = 0; j < 40; ++j) {
        int idx = base + j;
        int c = (idx < 40000) ? binCnt[idx] : 0;
        local[j] = s;
        s += c;
    }
    part[t] = s;
    __syncthreads();
    for (int off = 1; off < 1024; off <<= 1) {
        int v = (t >= off) ? part[t - off] : 0;
        __syncthreads();
        part[t] += v;
        __syncthreads();
    }
    int add = (t > 0) ? part[t - 1] : 0;
    #pragma unroll
    for (int j = 0; j < 40; ++j) {
        int idx = base + j;
        if (idx < 40000) binBase[idx] = add + local[j];
    }
}

// scatter: invperm[t] = sorted position of atom t; sortedMemb[pos] = membership
__global__ void k_scatter(const int* __restrict__ memb, const int* __restrict__ binBase,
                          int* __restrict__ binFill,
                          int* __restrict__ invperm, int* __restrict__ sortedMemb) {
    int t = blockIdx.x * 256 + threadIdx.x;
    if (t < 1000000) {
        int m = memb[t];
        int pos = binBase[m] + atomicAdd(&binFill[m], 1);
        invperm[t] = pos;
        sortedMemb[pos] = m;
    }
}

// ---------- subtile metadata: 125000 subtiles of 8 sorted rows ----------

__global__ void k_meta(const int* __restrict__ sortedMemb,
                       int* __restrict__ firstSeg, int* __restrict__ segCnt) {
    int t = blockIdx.x * 256 + threadIdx.x;
    if (t < 125000) {
        int f = sortedMemb[8 * t];
        int l = sortedMemb[8 * t + 7];
        firstSeg[t] = f;
        segCnt[t] = l - f + 1;
    }
}

__global__ __launch_bounds__(1024)
void k_scan2(const int* __restrict__ segCnt, int* __restrict__ cumSeg) {
    __shared__ int part[1024];
    const int t = threadIdx.x;
    const int base = t * 123;
    int s = 0;
    for (int j = 0; j < 123; ++j) {
        int idx = base + j;
        if (idx < 125000) s += segCnt[idx];
    }
    part[t] = s;
    __syncthreads();
    for (int off = 1; off < 1024; off <<= 1) {
        int v = (t >= off) ? part[t - off] : 0;
        __syncthreads();
        part[t] += v;
        __syncthreads();
    }
    int run = (t > 0) ? part[t - 1] : 0;
    for (int j = 0; j < 123; ++j) {
        int idx = base + j;
        if (idx < 125000) { cumSeg[idx] = run; run += segCnt[idx]; }
    }
}

// ---------- copy combine-metadata out of d_out (into bufA tail) ----------

__global__ void k_copymeta(const int* __restrict__ binBase, const int* __restrict__ binCnt,
                           const int* __restrict__ firstSeg, const int* __restrict__ cumSeg,
                           int* __restrict__ dBinBase, int* __restrict__ dBinCnt,
                           int* __restrict__ dFirstSeg, int* __restrict__ dCumSeg) {
    int t = blockIdx.x * 256 + threadIdx.x;
    if (t < 40000) { dBinBase[t] = binBase[t]; dBinCnt[t] = binCnt[t]; }
    if (t < 125000) { dFirstSeg[t] = firstSeg[t]; dCumSeg[t] = cumSeg[t]; }
}

// ---------- W fragment prep: dense [128][256] ----------
// fid = (tn*4 + ks)*64 + lane; lane j holds W[ks*32 + (lane>>4)*8 + j][tn*16 + (lane&15)]

__global__ void k_prepW(const float* __restrict__ W,
                        ushort_t* __restrict__ Bh, ushort_t* __restrict__ Bl) {
    int idx = blockIdx.x * 256 + threadIdx.x;
    if (idx >= 4096) return;
    int l = idx & 63, g = idx >> 6;       // g = tn*4 + ks
    int tn = g >> 2, ks = g & 3;
    int n = tn * 16 + (l & 15);
    int k0 = ks * 32 + (l >> 4) * 8;
    float f[8];
    #pragma unroll
    for (int j = 0; j < 8; ++j) f[j] = W[(size_t)(k0 + j) * 256 + n];
    uint4 h, lo; split8(f, h, lo);
    *(uint4*)(Bh + (size_t)idx * 8) = h;
    *(uint4*)(Bl + (size_t)idx * 8) = lo;
}

// ---------- W fragment prep: gc2's 9 matrices [128][128] (5 self + 4 rel) ----------

__global__ void k_prepW2(const float* __restrict__ Ws5, const float* __restrict__ Wr4,
                         ushort_t* __restrict__ Fh, ushort_t* __restrict__ Fl) {
    int idx = blockIdx.x * 256 + threadIdx.x;   // [0, 9*2048)
    if (idx >= 18432) return;
    int mat = idx >> 11;
    int fid = idx & 2047;
    int l = fid & 63, g = fid >> 6;
    int tn = g >> 2, ks = g & 3;
    int n = tn * 16 + (l & 15);
    int k0 = ks * 32 + (l >> 4) * 8;
    const float* W = (mat < 5) ? (Ws5 + (size_t)mat * 16384)
                               : (Wr4 + (size_t)(mat - 5) * 16384);
    float f[8];
    #pragma unroll
    for (int j = 0; j < 8; ++j) f[j] = W[(size_t)(k0 + j) * 128 + n];
    uint4 h, lo; split8(f, h, lo);
    *(uint4*)(Fh + (size_t)idx * 8) = h;
    *(uint4*)(Fl + (size_t)idx * 8) = lo;
}

// ---------- W fragment prep: gc1's 9 matrices [75][128], K padded to 96 ----------

__global__ void k_prepW1(const float* __restrict__ Ws5, const float* __restrict__ Wr4,
                         ushort_t* __restrict__ Fh, ushort_t* __restrict__ Fl) {
    int idx = blockIdx.x * 256 + threadIdx.x;   // [0, 9*1536)
    if (idx >= 13824) return;
    int mat = idx / 1536;
    int fid = idx - mat * 1536;
    int l = fid & 63, g = fid >> 6;             // g = tn*3 + ks
    int tn = g / 3, ks = g - tn * 3;
    int n = tn * 16 + (l & 15);
    int k0 = ks * 32 + (l >> 4) * 8;
    const float* W = (mat < 5) ? (Ws5 + (size_t)mat * 9600)
                               : (Wr4 + (size_t)(mat - 5) * 9600);
    float f[8];
    #pragma unroll
    for (int j = 0; j < 8; ++j)
        f[j] = (k0 + j < 75) ? W[(size_t)(k0 + j) * 128 + n] : 0.0f;
    uint4 h, lo; split8(f, h, lo);
    *(uint4*)(Fh + (size_t)idx * 8) = h;
    *(uint4*)(Fl + (size_t)idx * 8) = lo;
}

// ---------- gc1 via MFMA split-bf16 (tanh + bn1 fused), K=75 padded to 96 ----------
// v2 staging: thread owns (row, 8-k chunk), b128 LDS writes.

template<int DEG>
__global__ __launch_bounds__(256)
void k_gc1m(const float* __restrict__ X, const int* __restrict__ adj,
            const ushort_t* __restrict__ Wsh, const ushort_t* __restrict__ Wsl,
            const ushort_t* __restrict__ Wrh, const ushort_t* __restrict__ Wrl,
            const float* __restrict__ bias,
            const float* __restrict__ bg, const float* __restrict__ bb,
            const float* __restrict__ bm, const float* __restrict__ bv,
            float* __restrict__ Out, int start, int count)
{
    __shared__ __align__(16) ushort_t Sh[64 * 128];
    __shared__ __align__(16) ushort_t Sl[64 * 128];
    __shared__ __align__(16) ushort_t Nh[(DEG > 0) ? 64 * 128 : 8];
    __shared__ __align__(16) ushort_t Nl[(DEG > 0) ? 64 * 128 : 8];

    const int tid = threadIdx.x;
    const int tileBase = blockIdx.x * 64;

    for (int idx = tid; idx < 64 * 12; idx += 256) {
        int a = idx / 12;
        int c = idx - a * 12;
        int k0 = c * 8;
        int ga = tileBase + a;
        float fs[8] = {0, 0, 0, 0, 0, 0, 0, 0};
        float fn[8] = {0, 0, 0, 0, 0, 0, 0, 0};
        if (ga < count) {
            const float* row = X + (size_t)(start + ga) * 75;
            #pragma unroll
            for (int j = 0; j < 8; ++j) {
                int k = k0 + j;
                if (k < 75) fs[j] = row[k];
            }
            if constexpr (DEG > 0) {
                #pragma unroll
                for (int jj = 0; jj < DEG; ++jj) {
                    int nb = adj[(size_t)ga * DEG + jj];
                    const float* nr = X + (size_t)nb * 75;
                    #pragma unroll
                    for (int j = 0; j < 8; ++j) {
                        int k = k0 + j;
                        if (k < 75) fn[j] += nr[k];
                    }
                }
            }
        }
        int cs = c ^ (a & 15);
        uint4 h, lo;
        split8(fs, h, lo);
        *(uint4*)(Sh + a * 128 + cs * 8) = h;
        *(uint4*)(Sl + a * 128 + cs * 8) = lo;
        if constexpr (DEG > 0) {
            split8(fn, h, lo);
            *(uint4*)(Nh + a * 128 + cs * 8) = h;
            *(uint4*)(Nl + a * 128 + cs * 8) = lo;
        }
    }
    __syncthreads();

    const int w = tid >> 6, l = tid & 63;
    const int lm = l & 15, lq = l >> 4;

    f32x4 acc[4][2];
    #pragma unroll
    for (int rt = 0; rt < 4; ++rt)
        #pragma unroll
        for (int ti = 0; ti < 2; ++ti)
            acc[rt][ti] = (f32x4){0.f, 0.f, 0.f, 0.f};

    for (int ks = 0; ks < 3; ++ks) {
        short8v ash[4], asl[4], anh[4], anl[4];
        #pragma unroll
        for (int rt = 0; rt < 4; ++rt) {
            int a = rt * 16 + lm;
            int cs = (ks * 4 + lq) ^ lm;
            ash[rt] = *(const short8v*)(Sh + a * 128 + cs * 8);
            asl[rt] = *(const short8v*)(Sl + a * 128 + cs * 8);
            if constexpr (DEG > 0) {
                anh[rt] = *(const short8v*)(Nh + a * 128 + cs * 8);
                anl[rt] = *(const short8v*)(Nl + a * 128 + cs * 8);
            }
        }
        #pragma unroll
        for (int ti = 0; ti < 2; ++ti) {
            int fid = ((w + ti * 4) * 3 + ks) * 64 + l;
            short8v bh = *(const short8v*)(Wsh + (size_t)fid * 8);
            short8v bl = *(const short8v*)(Wsl + (size_t)fid * 8);
            #pragma unroll
            for (int rt = 0; rt < 4; ++rt) {
                acc[rt][ti] = __builtin_amdgcn_mfma_f32_16x16x32_bf16(ash[rt], bh, acc[rt][ti], 0, 0, 0);
                acc[rt][ti] = __builtin_amdgcn_mfma_f32_16x16x32_bf16(asl[rt], bh, acc[rt][ti], 0, 0, 0);
                acc[rt][ti] = __builtin_amdgcn_mfma_f32_16x16x32_bf16(ash[rt], bl, acc[rt][ti], 0, 0, 0);
            }
            if constexpr (DEG > 0) {
                short8v rh = *(const short8v*)(Wrh + (size_t)fid * 8);
                short8v rl = *(const short8v*)(Wrl + (size_t)fid * 8);
                #pragma unroll
                for (int rt = 0; rt < 4; ++rt) {
                    acc[rt][ti] = __builtin_amdgcn_mfma_f32_16x16x32_bf16(anh[rt], rh, acc[rt][ti], 0, 0, 0);
                    acc[rt][ti] = __builtin_amdgcn_mfma_f32_16x16x32_bf16(anl[rt], rh, acc[rt][ti], 0, 0, 0);
                    acc[rt][ti] = __builtin_amdgcn_mfma_f32_16x16x32_bf16(anh[rt], rl, acc[rt][ti], 0, 0, 0);
                }
            }
        }
    }

    #pragma unroll
    for (int ti = 0; ti < 2; ++ti) {
        int cc = (w + ti * 4) * 16 + lm;
        float bz = bias[cc];
        float s = bg[cc] * rsqrtf(bv[cc] + BN_EPS);
        float sb = bb[cc] - bm[cc] * s;
        #pragma unroll
        for (int rt = 0; rt < 4; ++rt) {
            #pragma unroll
            for (int r = 0; r < 4; ++r) {
                int ga = tileBase + rt * 16 + lq * 4 + r;
                if (ga < count)
                    Out[(size_t)(start + ga) * 128 + cc] =
                        fast_tanh(acc[rt][ti][r] + bz) * s + sb;
            }
        }
    }
}

// ---------- gc2 via MFMA split-bf16 (tanh + bn1 fused) ----------

template<int DEG>
__global__ __launch_bounds__(256)
void k_gc2m(const float* __restrict__ X, const int* __restrict__ adj,
            const ushort_t* __restrict__ Wsh, const ushort_t* __restrict__ Wsl,
            const ushort_t* __restrict__ Wrh, const ushort_t* __restrict__ Wrl,
            const float* __restrict__ bias,
            const float* __restrict__ bg, const float* __restrict__ bb,
            const float* __restrict__ bm, const float* __restrict__ bv,
            float* __restrict__ Out, int start, int count)
{
    __shared__ __align__(16) ushort_t Sh[64 * 128];
    __shared__ __align__(16) ushort_t Sl[64 * 128];
    __shared__ __align__(16) ushort_t Nh[(DEG > 0) ? 64 * 128 : 8];
    __shared__ __align__(16) ushort_t Nl[(DEG > 0) ? 64 * 128 : 8];

    const int tid = threadIdx.x;
    const int tileBase = blockIdx.x * 64;

    for (int idx = tid; idx < 1024; idx += 256) {
        int a = idx >> 4, c = idx & 15;
        int ga = tileBase + a;
        float fs[8] = {0, 0, 0, 0, 0, 0, 0, 0};
        float fn[8] = {0, 0, 0, 0, 0, 0, 0, 0};
        if (ga < count) {
            const float* row = X + (size_t)(start + ga) * 128 + c * 8;
            *(float4*)(&fs[0]) = *(const float4*)row;
            *(float4*)(&fs[4]) = *(const float4*)(row + 4);
            if constexpr (DEG > 0) {
                #pragma unroll
                for (int j = 0; j < DEG; ++j) {
                    int nb = adj[(size_t)ga * DEG + j];
                    const float* nr = X + (size_t)nb * 128 + c * 8;
                    float4 q0 = *(const float4*)nr;
                    float4 q1 = *(const float4*)(nr + 4);
                    fn[0] += q0.x; fn[1] += q0.y; fn[2] += q0.z; fn[3] += q0.w;
                    fn[4] += q1.x; fn[5] += q1.y; fn[6] += q1.z; fn[7] += q1.w;
                }
            }
        }
        int cs = c ^ (a & 15);
        uint4 h, lo;
        split8(fs, h, lo);
        *(uint4*)(Sh + a * 128 + cs * 8) = h;
        *(uint4*)(Sl + a * 128 + cs * 8) = lo;
        if constexpr (DEG > 0) {
            split8(fn, h, lo);
            *(uint4*)(Nh + a * 128 + cs * 8) = h;
            *(uint4*)(Nl + a * 128 + cs * 8) = lo;
        }
    }
    __syncthreads();

    const int w = tid >> 6, l = tid & 63;
    const int lm = l & 15, lq = l >> 4;

    f32x4 acc[4][2];
    #pragma unroll
    for (int rt = 0; rt < 4; ++rt)
        #pragma unroll
        for (int ti = 0; ti < 2; ++ti)
            acc[rt][ti] = (f32x4){0.f, 0.f, 0.f, 0.f};

    for (int ks = 0; ks < 4; ++ks) {
        short8v ash[4], asl[4], anh[4], anl[4];
        #pragma unroll
        for (int rt = 0; rt < 4; ++rt) {
            int a = rt * 16 + lm;
            int cs = (ks * 4 + lq) ^ lm;
            ash[rt] = *(const short8v*)(Sh + a * 128 + cs * 8);
            asl[rt] = *(const short8v*)(Sl + a * 128 + cs * 8);
            if constexpr (DEG > 0) {
                anh[rt] = *(const short8v*)(Nh + a * 128 + cs * 8);
                anl[rt] = *(const short8v*)(Nl + a * 128 + cs * 8);
            }
        }
        #pragma unroll
        for (int ti = 0; ti < 2; ++ti) {
            int fid = ((w + ti * 4) * 4 + ks) * 64 + l;
            short8v bh = *(const short8v*)(Wsh + (size_t)fid * 8);
            short8v bl = *(const short8v*)(Wsl + (size_t)fid * 8);
            #pragma unroll
            for (int rt = 0; rt < 4; ++rt) {
                acc[rt][ti] = __builtin_amdgcn_mfma_f32_16x16x32_bf16(ash[rt], bh, acc[rt][ti], 0, 0, 0);
                acc[rt][ti] = __builtin_amdgcn_mfma_f32_16x16x32_bf16(asl[rt], bh, acc[rt][ti], 0, 0, 0);
                acc[rt][ti] = __builtin_amdgcn_mfma_f32_16x16x32_bf16(ash[rt], bl, acc[rt][ti], 0, 0, 0);
            }
            if constexpr (DEG > 0) {
                short8v rh = *(const short8v*)(Wrh + (size_t)fid * 8);
                short8v rl = *(const short8v*)(Wrl + (size_t)fid * 8);
                #pragma unroll
                for (int rt = 0; rt < 4; ++rt) {
                    acc[rt][ti] = __builtin_amdgcn_mfma_f32_16x16x32_bf16(anh[rt], rh, acc[rt][ti], 0, 0, 0);
                    acc[rt][ti] = __builtin_amdgcn_mfma_f32_16x16x32_bf16(anl[rt], rh, acc[rt][ti], 0, 0, 0);
                    acc[rt][ti] = __builtin_amdgcn_mfma_f32_16x16x32_bf16(anh[rt], rl, acc[rt][ti], 0, 0, 0);
                }
            }
        }
    }

    #pragma unroll
    for (int ti = 0; ti < 2; ++ti) {
        int cc = (w + ti * 4) * 16 + lm;
        float bz = bias[cc];
        float s = bg[cc] * rsqrtf(bv[cc] + BN_EPS);
        float sb = bb[cc] - bm[cc] * s;
        #pragma unroll
        for (int rt = 0; rt < 4; ++rt) {
            #pragma unroll
            for (int r = 0; r < 4; ++r) {
                int ga = tileBase + rt * 16 + lq * 4 + r;
                if (ga < count)
                    Out[(size_t)(start + ga) * 128 + cc] =
                        fast_tanh(acc[rt][ti][r] + bz) * s + sb;
            }
        }
    }
}

// ---------- graph pool (f32 -> f32), used for pool1 ----------

template<int DEG>
__global__ void k_pool(const float* __restrict__ X, const int* __restrict__ adj,
                       float* __restrict__ Out, int start, int count)
{
    int t = blockIdx.x * 256 + threadIdx.x;
    int a = t >> 5;
    if (a >= count) return;
    int c4 = t & 31;
    const float4* X4 = (const float4*)X;
    float4 v = X4[(size_t)(start + a) * 32 + c4];
    #pragma unroll
    for (int j = 0; j < DEG; ++j) {
        int nb = adj[(size_t)a * DEG + j];
        float4 q = X4[(size_t)nb * 32 + c4];
        v.x = fmaxf(v.x, q.x); v.y = fmaxf(v.y, q.y);
        v.z = fmaxf(v.z, q.z); v.w = fmaxf(v.w, q.w);
    }
    ((float4*)Out)[(size_t)(start + a) * 32 + c4] = v;
}

// ---------- pool2: f32 -> split bf16 planes, scattered to SORTED row position ----------

template<int DEG>
__global__ void k_pool_split(const float* __restrict__ X, const int* __restrict__ adj,
                             const int* __restrict__ invperm,
                             ushort_t* __restrict__ PH, ushort_t* __restrict__ PL,
                             int start, int count)
{
    int t = blockIdx.x * 256 + threadIdx.x;
    int a = t >> 4;
    if (a >= count) return;
    int c8 = (t & 15) * 8;
    const float* row = X + (size_t)(start + a) * 128 + c8;
    float f[8];
    *(float4*)(&f[0]) = *(const float4*)row;
    *(float4*)(&f[4]) = *(const float4*)(row + 4);
    #pragma unroll
    for (int j = 0; j < DEG; ++j) {
        int nb = adj[(size_t)a * DEG + j];
        const float* nr = X + (size_t)nb * 128 + c8;
        float4 q0 = *(const float4*)nr;
        float4 q1 = *(const float4*)(nr + 4);
        f[0] = fmaxf(f[0], q0.x); f[1] = fmaxf(f[1], q0.y);
        f[2] = fmaxf(f[2], q0.z); f[3] = fmaxf(f[3], q0.w);
        f[4] = fmaxf(f[4], q1.x); f[5] = fmaxf(f[5], q1.y);
        f[6] = fmaxf(f[6], q1.z); f[7] = fmaxf(f[7], q1.w);
    }
    uint4 h, lo; split8(f, h, lo);
    int dst = invperm[start + a];
    *(uint4*)(PH + (size_t)dst * 128 + c8) = h;
    *(uint4*)(PL + (size_t)dst * 128 + c8) = lo;
}

// ---------- dense via MFMA split-bf16 (tanh + bn3) + subtile partials ----------
// Rows are pre-sorted: staging is a fully-sequential coalesced copy.

__global__ __launch_bounds__(256)
void k_dense_mfma(const ushort_t* __restrict__ PH,  // [1M][128] bf16 hi, sorted rows
                  const ushort_t* __restrict__ PL,  // [1M][128] bf16 lo, sorted rows
                  const int*   __restrict__ sortedMemb,  // [1M]
                  const int*   __restrict__ cumSeg,      // [125000]
                  const ushort_t* __restrict__ Bh,   // W frag hi [4096][8]
                  const ushort_t* __restrict__ Bl,   // W frag lo
                  const float* __restrict__ bias,    // [256]
                  const float* __restrict__ bg, const float* __restrict__ bb,
                  const float* __restrict__ bm, const float* __restrict__ bv,
                  float* __restrict__ partials)
{
    __shared__ __align__(16) char smem[33792];   // Ah[16KB]+Al[16KB] / Yt[64][132]f32
    __shared__ int sM[64];
    ushort_t* Ah = (ushort_t*)smem;
    ushort_t* Al = (ushort_t*)(smem + 16384);
    float*    Yt = (float*)smem;

    const int tid = threadIdx.x;
    const int tileBase = blockIdx.x * 64;
    if (tid < 64) sM[tid] = sortedMemb[tileBase + tid];

    // staging: sequential coalesced copy of pre-split 16B chunks (swizzled)
    for (int idx = tid; idx < 1024; idx += 256) {
        int a = idx >> 4, c = idx & 15;
        size_t off = (size_t)(tileBase + a) * 128 + c * 8;
        uint4 h  = *(const uint4*)(PH + off);
        uint4 lo = *(const uint4*)(PL + off);
        int cs = c ^ (a & 15);
        *(uint4*)(Ah + a * 128 + cs * 8) = h;
        *(uint4*)(Al + a * 128 + cs * 8) = lo;
    }
    __syncthreads();

    const int w = tid >> 6, l = tid & 63;
    const int lm = l & 15, lq = l >> 4;

    f32x4 acc[4][4];
    #pragma unroll
    for (int rt = 0; rt < 4; ++rt)
        #pragma unroll
        for (int ti = 0; ti < 4; ++ti)
            acc[rt][ti] = (f32x4){0.f, 0.f, 0.f, 0.f};

    for (int ks = 0; ks < 4; ++ks) {
        short8v ah[4], al[4];
        #pragma unroll
        for (int rt = 0; rt < 4; ++rt) {
            int a = rt * 16 + lm;
            int cs = (ks * 4 + lq) ^ lm;
            ah[rt] = *(const short8v*)(Ah + a * 128 + cs * 8);
            al[rt] = *(const short8v*)(Al + a * 128 + cs * 8);
        }
        #pragma unroll
        for (int ti = 0; ti < 4; ++ti) {
            int fid = ((w + ti * 4) * 4 + ks) * 64 + l;
            short8v bh = *(const short8v*)(Bh + (size_t)fid * 8);
            short8v bl = *(const short8v*)(Bl + (size_t)fid * 8);
            #pragma unroll
            for (int rt = 0; rt < 4; ++rt) {
                acc[rt][ti] = __builtin_amdgcn_mfma_f32_16x16x32_bf16(ah[rt], bh, acc[rt][ti], 0, 0, 0);
                acc[rt][ti] = __builtin_amdgcn_mfma_f32_16x16x32_bf16(al[rt], bh, acc[rt][ti], 0, 0, 0);
                acc[rt][ti] = __builtin_amdgcn_mfma_f32_16x16x32_bf16(ah[rt], bl, acc[rt][ti], 0, 0, 0);
            }
        }
    }

    float bvz[4], scv[4], shv[4];
    #pragma unroll
    for (int ti = 0; ti < 4; ++ti) {
        int c = (w + ti * 4) * 16 + lm;
        bvz[ti] = bias[c];
        float s = bg[c] * rsqrtf(bv[c] + BN_EPS);
        scv[ti] = s;
        shv[ti] = bb[c] - bm[c] * s;
    }

    const int q = tid >> 5, cg = tid & 31;
    const int sub = blockIdx.x * 8 + q;
    const size_t slotBase = (size_t)cumSeg[sub];
    const int fs = sM[q * 8];

    #pragma unroll
    for (int hf = 0; hf < 2; ++hf) {
        __syncthreads();
        #pragma unroll
        for (int tj = 0; tj < 2; ++tj) {
            int ti = 2 * hf + tj;
            int colh = (w + ti * 4) * 16 + lm - hf * 128;
            #pragma unroll
            for (int rt = 0; rt < 4; ++rt)
                #pragma unroll
                for (int r = 0; r < 4; ++r) {
                    int row = rt * 16 + lq * 4 + r;
                    float y = fast_tanh(acc[rt][ti][r] + bvz[ti]) * scv[ti] + shv[ti];
                    Yt[row * 132 + colh] = y;
                }
        }
        __syncthreads();

        float4 ys, ym;
        int cur = sM[q * 8];
        {
            float4 v = *(const float4*)(Yt + (q * 8) * 132 + cg * 4);
            ys = v; ym = v;
        }
        #pragma unroll
        for (int i = 1; i < 8; ++i) {
            float4 v = *(const float4*)(Yt + (q * 8 + i) * 132 + cg * 4);
            int m = sM[q * 8 + i];
            if (m == cur) {
                ys.x += v.x; ys.y += v.y; ys.z += v.z; ys.w += v.w;
                ym.x = fmaxf(ym.x, v.x); ym.y = fmaxf(ym.y, v.y);
                ym.z = fmaxf(ym.z, v.z); ym.w = fmaxf(ym.w, v.w);
            } else {
                float* p = partials + (slotBase + (cur - fs)) * 512 + hf * 128 + cg * 4;
                *(float4*)p         = ys;
                *(float4*)(p + 256) = ym;
                cur = m; ys = v; ym = v;
            }
        }
        float* p = partials + (slotBase + (cur - fs)) * 512 + hf * 128 + cg * 4;
        *(float4*)p         = ys;
        *(float4*)(p + 256) = ym;
    }
}

// ---------- combine partials -> final out (tanh fused) ----------

__global__ __launch_bounds__(256)
void k_combine(const float* __restrict__ partials,
               const int* __restrict__ binBase, const int* __restrict__ binCnt,
               const int* __restrict__ firstSeg, const int* __restrict__ cumSeg,
               float* __restrict__ Out)
{
    int sid = blockIdx.x * 4 + (threadIdx.x >> 6);
    if (sid >= 40000) return;
    int lane = threadIdx.x & 63;
    int b = binBase[sid], n = binCnt[sid];

    float4 s = make_float4(0.f, 0.f, 0.f, 0.f);
    float4 m = make_float4(-INFINITY, -INFINITY, -INFINITY, -INFINITY);
    if (n > 0) {
        int s0 = b >> 3, s1 = (b + n - 1) >> 3;
        for (int t = s0; t <= s1; ++t) {
            size_t slot = (size_t)cumSeg[t] + (sid - firstSeg[t]);
            const float4* P = (const float4*)(partials + slot * 512);
            float4 a = P[lane];
            float4 x = P[64 + lane];
            s.x += a.x; s.y += a.y; s.z += a.z; s.w += a.w;
            m.x = fmaxf(m.x, x.x); m.y = fmaxf(m.y, x.y);
            m.z = fmaxf(m.z, x.z); m.w = fmaxf(m.w, x.w);
        }
    }
    float4 os = make_float4(fast_tanh(s.x), fast_tanh(s.y), fast_tanh(s.z), fast_tanh(s.w));
    float4 om = make_float4(fast_tanh(m.x), fast_tanh(m.y), fast_tanh(m.z), fast_tanh(m.w));
    *(float4*)(Out + (size_t)sid * 512 + lane * 4)       = os;
    *(float4*)(Out + (size_t)sid * 512 + 256 + lane * 4) = om;
}

// ---------- launcher ----------

extern "C" void kernel_launch(void* const* d_in, const int* in_sizes, int n_in,
                              void* d_out, int out_size, void* d_ws, size_t ws_size,
                              hipStream_t stream)
{
    const float* atom = (const float*)d_in[0];
    const int*   memb = (const int*)d_in[1];
    const int*   adj1 = (const int*)d_in[2];
    const int*   adj2 = (const int*)d_in[3];
    const int*   adj3 = (const int*)d_in[4];
    const int*   adj4 = (const int*)d_in[5];
    const float* g1Ws = (const float*)d_in[6];
    const float* g1Wr = (const float*)d_in[7];
    const float* g1b  = (const float*)d_in[8];
    const float* g2Ws = (const float*)d_in[9];
    const float* g2Wr = (const float*)d_in[10];
    const float* g2b  = (const float*)d_in[11];
    const float* bn1g = (const float*)d_in[12];
    const float* bn1b = (const float*)d_in[13];
    const float* bn1m = (const float*)d_in[14];
    const float* bn1v = (const float*)d_in[15];
    const float* bn3g = (const float*)d_in[16];
    const float* bn3b = (const float*)d_in[17];
    const float* bn3m = (const float*)d_in[18];
    const float* bn3v = (const float*)d_in[19];
    const float* dW   = (const float*)d_in[20];
    const float* db   = (const float*)d_in[21];

    char* ws = (char*)d_ws;
    float* bufA = (float*)ws;                    // [1M][128] f32, 512 MB
    float* bufB = (float*)(ws + 512000000);      // [1M][128] f32, 512 MB
    char*  outc = (char*)d_out;                  // [40000][512] f32 = 81.92 MB
    float* out  = (float*)d_out;

    // pool2 split planes (sorted row order) live in bufB:
    ushort_t* PH = (ushort_t*)bufB;              // 256 MB
    ushort_t* PL = PH + (size_t)1000000 * 128;   // 256 MB

    // temp regions in d_out (all fully overwritten by k_combine at the end):
    ushort_t* gFh   = (ushort_t*)(outc);              // gc2 frags 294,912 B
    ushort_t* gFl   = (ushort_t*)(outc + 294912);
    ushort_t* g1Fh  = (ushort_t*)(outc + 589824);     // gc1 frags 221,184 B
    ushort_t* g1Fl  = (ushort_t*)(outc + 811008);
    ushort_t* dWh   = (ushort_t*)(outc + 1032192);    // dense frags 65,536 B
    ushort_t* dWl   = (ushort_t*)(outc + 1097728);
    int* invperm    = (int*)(outc + 1200000);         // 4,000,000 B
    int* sortedMemb = (int*)(outc + 5200000);         // 4,000,000 B
    int* binCnt     = (int*)(outc + 9200000);         // 160,000 B
    int* binBase    = (int*)(outc + 9360000);
    int* binFill    = (int*)(outc + 9520000);
    int* firstSeg   = (int*)(outc + 9680000);         // 500,000 B
    int* segCnt     = (int*)(outc + 10180000);
    int* cumSeg     = (int*)(outc + 10680000);        // ends ~11.2 MB << 82 MB

    // partials + combine-metadata copies live in bufA (dead after pool_split):
    float* partials = bufA;                           // <=165k slots x 2 KB = 338 MB
    int* cBinBase   = (int*)(ws + 400000000);
    int* cBinCnt    = (int*)(ws + 401000000);
    int* cFirstSeg  = (int*)(ws + 402000000);
    int* cCumSeg    = (int*)(ws + 403000000);

    // ---- W fragment prep + counting sort (depend only on inputs) ----
    k_prepW2<<<72, 256, 0, stream>>>(g2Ws, g2Wr, gFh, gFl);
    k_prepW1<<<54, 256, 0, stream>>>(g1Ws, g1Wr, g1Fh, g1Fl);
    k_prepW<<<16, 256, 0, stream>>>(dW, dWh, dWl);
    k_zero_bins<<<(40000 + 255) / 256, 256, 0, stream>>>(binCnt, binFill);
    k_hist<<<(1000000 + 255) / 256, 256, 0, stream>>>(memb, binCnt);
    k_scan<<<1, 1024, 0, stream>>>(binCnt, binBase);
    k_scatter<<<(1000000 + 255) / 256, 256, 0, stream>>>(memb, binBase, binFill,
        invperm, sortedMemb);
    k_meta<<<(125000 + 255) / 256, 256, 0, stream>>>(sortedMemb, firstSeg, segCnt);
    k_scan2<<<1, 1024, 0, stream>>>(segCnt, cumSeg);

    // ---- gc1 (MFMA): atom -> bufA ----
    k_gc1m<0><<<(10000 + 63) / 64, 256, 0, stream>>>(atom, nullptr,
        g1Fh + (size_t)0 * 1536 * 8, g1Fl + (size_t)0 * 1536 * 8,
        nullptr, nullptr, g1b + 0 * 128,
        bn1g, bn1b, bn1m, bn1v, bufA, 0, 10000);
    k_gc1m<1><<<(240000 + 63) / 64, 256, 0, stream>>>(atom, adj1,
        g1Fh + (size_t)1 * 1536 * 8, g1Fl + (size_t)1 * 1536 * 8,
        g1Fh + (size_t)5 * 1536 * 8, g1Fl + (size_t)5 * 1536 * 8, g1b + 1 * 128,
        bn1g, bn1b, bn1m, bn1v, bufA, 10000, 240000);
    k_gc1m<2><<<(360000 + 63) / 64, 256, 0, stream>>>(atom, adj2,
        g1Fh + (size_t)2 * 1536 * 8, g1Fl + (size_t)2 * 1536 * 8,
        g1Fh + (size_t)6 * 1536 * 8, g1Fl + (size_t)6 * 1536 * 8, g1b + 2 * 128,
        bn1g, bn1b, bn1m, bn1v, bufA, 250000, 360000);
    k_gc1m<3><<<(250000 + 63) / 64, 256, 0, stream>>>(atom, adj3,
        g1Fh + (size_t)3 * 1536 * 8, g1Fl + (size_t)3 * 1536 * 8,
        g1Fh + (size_t)7 * 1536 * 8, g1Fl + (size_t)7 * 1536 * 8, g1b + 3 * 128,
        bn1g, bn1b, bn1m, bn1v, bufA, 610000, 250000);
    k_gc1m<4><<<(140000 + 63) / 64, 256, 0, stream>>>(atom, adj4,
        g1Fh + (size_t)4 * 1536 * 8, g1Fl + (size_t)4 * 1536 * 8,
        g1Fh + (size_t)8 * 1536 * 8, g1Fl + (size_t)8 * 1536 * 8, g1b + 4 * 128,
        bn1g, bn1b, bn1m, bn1v, bufA, 860000, 140000);

    // ---- pool1: bufA -> bufB (f32) ----
    k_pool<0><<<(10000 + 7) / 8, 256, 0, stream>>>(bufA, nullptr, bufB, 0, 10000);
    k_pool<1><<<(240000 + 7) / 8, 256, 0, stream>>>(bufA, adj1, bufB, 10000, 240000);
    k_pool<2><<<(360000 + 7) / 8, 256, 0, stream>>>(bufA, adj2, bufB, 250000, 360000);
    k_pool<3><<<(250000 + 7) / 8, 256, 0, stream>>>(bufA, adj3, bufB, 610000, 250000);
    k_pool<4><<<(140000 + 7) / 8, 256, 0, stream>>>(bufA, adj4, bufB, 860000, 140000);

    // ---- gc2 (MFMA): bufB -> bufA ----
    k_gc2m<0><<<(10000 + 63) / 64, 256, 0, stream>>>(bufB, nullptr,
        gFh + (size_t)0 * 2048 * 8, gFl + (size_t)0 * 2048 * 8,
        nullptr, nullptr, g2b + 0 * 128,
        bn1g, bn1b, bn1m, bn1v, bufA, 0, 10000);
    k_gc2m<1><<<(240000 + 63) / 64, 256, 0, stream>>>(bufB, adj1,
        gFh + (size_t)1 * 2048 * 8, gFl + (size_t)1 * 2048 * 8,
        gFh + (size_t)5 * 2048 * 8, gFl + (size_t)5 * 2048 * 8, g2b + 1 * 128,
        bn1g, bn1b, bn1m, bn1v, bufA, 10000, 240000);
    k_gc2m<2><<<(360000 + 63) / 64, 256, 0, stream>>>(bufB, adj2,
        gFh + (size_t)2 * 2048 * 8, gFl + (size_t)2 * 2048 * 8,
        gFh + (size_t)6 * 2048 * 8, gFl + (size_t)6 * 2048 * 8, g2b + 2 * 128,
        bn1g, bn1b, bn1m, bn1v, bufA, 250000, 360000);
    k_gc2m<3><<<(250000 + 63) / 64, 256, 0, stream>>>(bufB, adj3,
        gFh + (size_t)3 * 2048 * 8, gFl + (size_t)3 * 2048 * 8,
        gFh + (size_t)7 * 2048 * 8, gFl + (size_t)7 * 2048 * 8, g2b + 3 * 128,
        bn1g, bn1b, bn1m, bn1v, bufA, 610000, 250000);
    k_gc2m<4><<<(140000 + 63) / 64, 256, 0, stream>>>(bufB, adj4,
        gFh + (size_t)4 * 2048 * 8, gFl + (size_t)4 * 2048 * 8,
        gFh + (size_t)8 * 2048 * 8, gFl + (size_t)8 * 2048 * 8, g2b + 4 * 128,
        bn1g, bn1b, bn1m, bn1v, bufA, 860000, 140000);

    // ---- pool2: bufA -> PH/PL at sorted positions (scattered writes) ----
    k_pool_split<0><<<(10000 * 16 + 255) / 256, 256, 0, stream>>>(bufA, nullptr, invperm, PH, PL, 0, 10000);
    k_pool_split<1><<<(240000 * 16 + 255) / 256, 256, 0, stream>>>(bufA, adj1, invperm, PH, PL, 10000, 240000);
    k_pool_split<2><<<(360000 * 16 + 255) / 256, 256, 0, stream>>>(bufA, adj2, invperm, PH, PL, 250000, 360000);
    k_pool_split<3><<<(250000 * 16 + 255) / 256, 256, 0, stream>>>(bufA, adj3, invperm, PH, PL, 610000, 250000);
    k_pool_split<4><<<(140000 * 16 + 255) / 256, 256, 0, stream>>>(bufA, adj4, invperm, PH, PL, 860000, 140000);

    // ---- copy combine-metadata out of d_out into bufA tail (bufA now dead) ----
    k_copymeta<<<(125000 + 255) / 256, 256, 0, stream>>>(binBase, binCnt,
        firstSeg, cumSeg, cBinBase, cBinCnt, cFirstSeg, cCumSeg);

    // ---- dense (MFMA, sequential staging) -> partials in bufA ----
    k_dense_mfma<<<15625, 256, 0, stream>>>(PH, PL, sortedMemb, cumSeg, dWh, dWl,
        db, bn3g, bn3b, bn3m, bn3v, partials);

    // ---- combine partials -> out (reads metadata from bufA copies) ----
    k_combine<<<10000, 256, 0, stream>>>(partials, cBinBase, cBinCnt,
        cFirstSeg, cCumSeg, out);
}

// Round 14
// 2857.108 us; speedup vs baseline: 1.1321x; 1.0902x over previous
//
#include <hip/hip_runtime.h>
#include <hip/hip_bf16.h>
#include <cstdint>
#include <cstddef>

#define BN_EPS 1e-3f
typedef unsigned short ushort_t;
typedef unsigned int uint_t;
typedef __attribute__((ext_vector_type(8))) short short8v;   // 8 bf16 (4 VGPRs)
typedef __attribute__((ext_vector_type(4))) float f32x4;     // MFMA C/D

// ---------- numeric helpers ----------

__device__ __forceinline__ float fast_tanh(float x) {
    float xc = fminf(fmaxf(x, -12.0f), 12.0f);
    float e = __expf(2.0f * xc);
    return (e - 1.0f) * __builtin_amdgcn_rcpf(e + 1.0f);
}

__device__ __forceinline__ float bf2f(uint_t u) {
    return __uint_as_float(u << 16);
}
__device__ __forceinline__ ushort_t f2bf(float f) {
    union { __hip_bfloat16 h; ushort_t u; } cv;
    cv.h = __float2bfloat16(f);   // RNE
    return cv.u;
}

__device__ __forceinline__ void split8(const float* f, uint4& h, uint4& lo) {
    uint_t hh[8], ll[8];
    #pragma unroll
    for (int j = 0; j < 8; ++j) {
        float x = f[j];
        ushort_t xh = f2bf(x);
        float xr = x - bf2f(xh);
        hh[j] = xh;
        ll[j] = f2bf(xr);
    }
    h  = make_uint4(hh[0] | (hh[1] << 16), hh[2] | (hh[3] << 16),
                    hh[4] | (hh[5] << 16), hh[6] | (hh[7] << 16));
    lo = make_uint4(ll[0] | (ll[1] << 16), ll[2] | (ll[3] << 16),
                    ll[4] | (ll[5] << 16), ll[6] | (ll[7] << 16));
}

// ---------- counting sort of atoms by membership (ascending) ----------

__global__ void k_zero_bins(int* __restrict__ binCnt, int* __restrict__ binFill) {
    int t = blockIdx.x * 256 + threadIdx.x;
    if (t < 40000) { binCnt[t] = 0; binFill[t] = 0; }
}

__global__ void k_hist(const int* __restrict__ memb, int* __restrict__ binCnt) {
    int t = blockIdx.x * 256 + threadIdx.x;
    if (t < 1000000) atomicAdd(&binCnt[memb[t]], 1);
}

__global__ __launch_bounds__(1024)
void k_scan(const int* __restrict__ binCnt, int* __restrict__ binBase) {
    __shared__ int part[1024];
    const int t = threadIdx.x;
    const int base = t * 40;
    int local[40];
    int s = 0;
    #pragma unroll
    for (int j = 0; j < 40; ++j) {
        int idx = base + j;
        int c = (idx < 40000) ? binCnt[idx] : 0;
        local[j] = s;
        s += c;
    }
    part[t] = s;
    __syncthreads();
    for (int off = 1; off < 1024; off <<= 1) {
        int v = (t >= off) ? part[t - off] : 0;
        __syncthreads();
        part[t] += v;
        __syncthreads();
    }
    int add = (t > 0) ? part[t - 1] : 0;
    #pragma unroll
    for (int j = 0; j < 40; ++j) {
        int idx = base + j;
        if (idx < 40000) binBase[idx] = add + local[j];
    }
}

__global__ void k_scatter(const int* __restrict__ memb, const int* __restrict__ binBase,
                          int* __restrict__ binFill,
                          int* __restrict__ invperm, int* __restrict__ sortedMemb) {
    int t = blockIdx.x * 256 + threadIdx.x;
    if (t < 1000000) {
        int m = memb[t];
        int pos = binBase[m] + atomicAdd(&binFill[m], 1);
        invperm[t] = pos;
        sortedMemb[pos] = m;
    }
}

// ---------- subtile metadata ----------

__global__ void k_meta(const int* __restrict__ sortedMemb,
                       int* __restrict__ firstSeg, int* __restrict__ segCnt) {
    int t = blockIdx.x * 256 + threadIdx.x;
    if (t < 125000) {
        int f = sortedMemb[8 * t];
        int l = sortedMemb[8 * t + 7];
        firstSeg[t] = f;
        segCnt[t] = l - f + 1;
    }
}

__global__ __launch_bounds__(1024)
void k_scan2(const int* __restrict__ segCnt, int* __restrict__ cumSeg) {
    __shared__ int part[1024];
    const int t = threadIdx.x;
    const int base = t * 123;
    int s = 0;
    for (int j = 0; j < 123; ++j) {
        int idx = base + j;
        if (idx < 125000) s += segCnt[idx];
    }
    part[t] = s;
    __syncthreads();
    for (int off = 1; off < 1024; off <<= 1) {
        int v = (t >= off) ? part[t - off] : 0;
        __syncthreads();
        part[t] += v;
        __syncthreads();
    }
    int run = (t > 0) ? part[t - 1] : 0;
    for (int j = 0; j < 123; ++j) {
        int idx = base + j;
        if (idx < 125000) { cumSeg[idx] = run; run += segCnt[idx]; }
    }
}

__global__ void k_copymeta(const int* __restrict__ binBase, const int* __restrict__ binCnt,
                           const int* __restrict__ firstSeg, const int* __restrict__ cumSeg,
                           int* __restrict__ dBinBase, int* __restrict__ dBinCnt,
                           int* __restrict__ dFirstSeg, int* __restrict__ dCumSeg) {
    int t = blockIdx.x * 256 + threadIdx.x;
    if (t < 40000) { dBinBase[t] = binBase[t]; dBinCnt[t] = binCnt[t]; }
    if (t < 125000) { dFirstSeg[t] = firstSeg[t]; dCumSeg[t] = cumSeg[t]; }
}

// ---------- W fragment prep ----------

__global__ void k_prepW(const float* __restrict__ W,
                        ushort_t* __restrict__ Bh, ushort_t* __restrict__ Bl) {
    int idx = blockIdx.x * 256 + threadIdx.x;
    if (idx >= 4096) return;
    int l = idx & 63, g = idx >> 6;
    int tn = g >> 2, ks = g & 3;
    int n = tn * 16 + (l & 15);
    int k0 = ks * 32 + (l >> 4) * 8;
    float f[8];
    #pragma unroll
    for (int j = 0; j < 8; ++j) f[j] = W[(size_t)(k0 + j) * 256 + n];
    uint4 h, lo; split8(f, h, lo);
    *(uint4*)(Bh + (size_t)idx * 8) = h;
    *(uint4*)(Bl + (size_t)idx * 8) = lo;
}

__global__ void k_prepW2(const float* __restrict__ Ws5, const float* __restrict__ Wr4,
                         ushort_t* __restrict__ Fh, ushort_t* __restrict__ Fl) {
    int idx = blockIdx.x * 256 + threadIdx.x;
    if (idx >= 18432) return;
    int mat = idx >> 11;
    int fid = idx & 2047;
    int l = fid & 63, g = fid >> 6;
    int tn = g >> 2, ks = g & 3;
    int n = tn * 16 + (l & 15);
    int k0 = ks * 32 + (l >> 4) * 8;
    const float* W = (mat < 5) ? (Ws5 + (size_t)mat * 16384)
                               : (Wr4 + (size_t)(mat - 5) * 16384);
    float f[8];
    #pragma unroll
    for (int j = 0; j < 8; ++j) f[j] = W[(size_t)(k0 + j) * 128 + n];
    uint4 h, lo; split8(f, h, lo);
    *(uint4*)(Fh + (size_t)idx * 8) = h;
    *(uint4*)(Fl + (size_t)idx * 8) = lo;
}

__global__ void k_prepW1(const float* __restrict__ Ws5, const float* __restrict__ Wr4,
                         ushort_t* __restrict__ Fh, ushort_t* __restrict__ Fl) {
    int idx = blockIdx.x * 256 + threadIdx.x;
    if (idx >= 13824) return;
    int mat = idx / 1536;
    int fid = idx - mat * 1536;
    int l = fid & 63, g = fid >> 6;
    int tn = g / 3, ks = g - tn * 3;
    int n = tn * 16 + (l & 15);
    int k0 = ks * 32 + (l >> 4) * 8;
    const float* W = (mat < 5) ? (Ws5 + (size_t)mat * 9600)
                               : (Wr4 + (size_t)(mat - 5) * 9600);
    float f[8];
    #pragma unroll
    for (int j = 0; j < 8; ++j)
        f[j] = (k0 + j < 75) ? W[(size_t)(k0 + j) * 128 + n] : 0.0f;
    uint4 h, lo; split8(f, h, lo);
    *(uint4*)(Fh + (size_t)idx * 8) = h;
    *(uint4*)(Fl + (size_t)idx * 8) = lo;
}

// ---------- gc1 body (MFMA split-bf16, K=75 padded to 96) ----------

template<int DEG>
__device__ __forceinline__ void gc1m_body(
    int blk, ushort_t* Sh, ushort_t* Sl, ushort_t* Nh, ushort_t* Nl,
    const float* __restrict__ X, const int* __restrict__ adj,
    const ushort_t* __restrict__ Wsh, const ushort_t* __restrict__ Wsl,
    const ushort_t* __restrict__ Wrh, const ushort_t* __restrict__ Wrl,
    const float* __restrict__ bias,
    const float* __restrict__ bg, const float* __restrict__ bbeta,
    const float* __restrict__ bm, const float* __restrict__ bv,
    float* __restrict__ Out, int start, int count)
{
    const int tid = threadIdx.x;
    const int tileBase = blk * 64;

    for (int idx = tid; idx < 64 * 12; idx += 256) {
        int a = idx / 12;
        int c = idx - a * 12;
        int k0 = c * 8;
        int ga = tileBase + a;
        float fs[8] = {0, 0, 0, 0, 0, 0, 0, 0};
        float fn[8] = {0, 0, 0, 0, 0, 0, 0, 0};
        if (ga < count) {
            const float* row = X + (size_t)(start + ga) * 75;
            #pragma unroll
            for (int j = 0; j < 8; ++j) {
                int k = k0 + j;
                if (k < 75) fs[j] = row[k];
            }
            if constexpr (DEG > 0) {
                #pragma unroll
                for (int jj = 0; jj < DEG; ++jj) {
                    int nb = adj[(size_t)ga * DEG + jj];
                    const float* nr = X + (size_t)nb * 75;
                    #pragma unroll
                    for (int j = 0; j < 8; ++j) {
                        int k = k0 + j;
                        if (k < 75) fn[j] += nr[k];
                    }
                }
            }
        }
        int cs = c ^ (a & 15);
        uint4 h, lo;
        split8(fs, h, lo);
        *(uint4*)(Sh + a * 128 + cs * 8) = h;
        *(uint4*)(Sl + a * 128 + cs * 8) = lo;
        if constexpr (DEG > 0) {
            split8(fn, h, lo);
            *(uint4*)(Nh + a * 128 + cs * 8) = h;
            *(uint4*)(Nl + a * 128 + cs * 8) = lo;
        }
    }
    __syncthreads();

    const int w = tid >> 6, l = tid & 63;
    const int lm = l & 15, lq = l >> 4;

    f32x4 acc[4][2];
    #pragma unroll
    for (int rt = 0; rt < 4; ++rt)
        #pragma unroll
        for (int ti = 0; ti < 2; ++ti)
            acc[rt][ti] = (f32x4){0.f, 0.f, 0.f, 0.f};

    for (int ks = 0; ks < 3; ++ks) {
        short8v ash[4], asl[4], anh[4], anl[4];
        #pragma unroll
        for (int rt = 0; rt < 4; ++rt) {
            int a = rt * 16 + lm;
            int cs = (ks * 4 + lq) ^ lm;
            ash[rt] = *(const short8v*)(Sh + a * 128 + cs * 8);
            asl[rt] = *(const short8v*)(Sl + a * 128 + cs * 8);
            if constexpr (DEG > 0) {
                anh[rt] = *(const short8v*)(Nh + a * 128 + cs * 8);
                anl[rt] = *(const short8v*)(Nl + a * 128 + cs * 8);
            }
        }
        #pragma unroll
        for (int ti = 0; ti < 2; ++ti) {
            int fid = ((w + ti * 4) * 3 + ks) * 64 + l;
            short8v bh = *(const short8v*)(Wsh + (size_t)fid * 8);
            short8v bl = *(const short8v*)(Wsl + (size_t)fid * 8);
            #pragma unroll
            for (int rt = 0; rt < 4; ++rt) {
                acc[rt][ti] = __builtin_amdgcn_mfma_f32_16x16x32_bf16(ash[rt], bh, acc[rt][ti], 0, 0, 0);
                acc[rt][ti] = __builtin_amdgcn_mfma_f32_16x16x32_bf16(asl[rt], bh, acc[rt][ti], 0, 0, 0);
                acc[rt][ti] = __builtin_amdgcn_mfma_f32_16x16x32_bf16(ash[rt], bl, acc[rt][ti], 0, 0, 0);
            }
            if constexpr (DEG > 0) {
                short8v rh = *(const short8v*)(Wrh + (size_t)fid * 8);
                short8v rl = *(const short8v*)(Wrl + (size_t)fid * 8);
                #pragma unroll
                for (int rt = 0; rt < 4; ++rt) {
                    acc[rt][ti] = __builtin_amdgcn_mfma_f32_16x16x32_bf16(anh[rt], rh, acc[rt][ti], 0, 0, 0);
                    acc[rt][ti] = __builtin_amdgcn_mfma_f32_16x16x32_bf16(anl[rt], rh, acc[rt][ti], 0, 0, 0);
                    acc[rt][ti] = __builtin_amdgcn_mfma_f32_16x16x32_bf16(anh[rt], rl, acc[rt][ti], 0, 0, 0);
                }
            }
        }
    }

    #pragma unroll
    for (int ti = 0; ti < 2; ++ti) {
        int cc = (w + ti * 4) * 16 + lm;
        float bz = bias[cc];
        float s = bg[cc] * rsqrtf(bv[cc] + BN_EPS);
        float sb = bbeta[cc] - bm[cc] * s;
        #pragma unroll
        for (int rt = 0; rt < 4; ++rt) {
            #pragma unroll
            for (int r = 0; r < 4; ++r) {
                int ga = tileBase + rt * 16 + lq * 4 + r;
                if (ga < count)
                    Out[(size_t)(start + ga) * 128 + cc] =
                        fast_tanh(acc[rt][ti][r] + bz) * s + sb;
            }
        }
    }
}

// merged gc1: blocks [0,157) d0 | [157,3907) d1 | [3907,9532) d2 | [9532,13439) d3 | [13439,15627) d4
__global__ __launch_bounds__(256)
void k_gc1m_all(const float* __restrict__ X,
                const int* __restrict__ adj1, const int* __restrict__ adj2,
                const int* __restrict__ adj3, const int* __restrict__ adj4,
                const ushort_t* __restrict__ Fh, const ushort_t* __restrict__ Fl,
                const float* __restrict__ g1b,
                const float* __restrict__ bg, const float* __restrict__ bbeta,
                const float* __restrict__ bm, const float* __restrict__ bv,
                float* __restrict__ Out)
{
    __shared__ __align__(16) ushort_t Sh[64 * 128];
    __shared__ __align__(16) ushort_t Sl[64 * 128];
    __shared__ __align__(16) ushort_t Nh[64 * 128];
    __shared__ __align__(16) ushort_t Nl[64 * 128];
    const size_t MS = (size_t)1536 * 8;
    int b = blockIdx.x;
    if (b < 157)
        gc1m_body<0>(b, Sh, Sl, Nh, Nl, X, nullptr,
            Fh + 0 * MS, Fl + 0 * MS, nullptr, nullptr,
            g1b + 0 * 128, bg, bbeta, bm, bv, Out, 0, 10000);
    else if (b < 3907)
        gc1m_body<1>(b - 157, Sh, Sl, Nh, Nl, X, adj1,
            Fh + 1 * MS, Fl + 1 * MS, Fh + 5 * MS, Fl + 5 * MS,
            g1b + 1 * 128, bg, bbeta, bm, bv, Out, 10000, 240000);
    else if (b < 9532)
        gc1m_body<2>(b - 3907, Sh, Sl, Nh, Nl, X, adj2,
            Fh + 2 * MS, Fl + 2 * MS, Fh + 6 * MS, Fl + 6 * MS,
            g1b + 2 * 128, bg, bbeta, bm, bv, Out, 250000, 360000);
    else if (b < 13439)
        gc1m_body<3>(b - 9532, Sh, Sl, Nh, Nl, X, adj3,
            Fh + 3 * MS, Fl + 3 * MS, Fh + 7 * MS, Fl + 7 * MS,
            g1b + 3 * 128, bg, bbeta, bm, bv, Out, 610000, 250000);
    else
        gc1m_body<4>(b - 13439, Sh, Sl, Nh, Nl, X, adj4,
            Fh + 4 * MS, Fl + 4 * MS, Fh + 8 * MS, Fl + 8 * MS,
            g1b + 4 * 128, bg, bbeta, bm, bv, Out, 860000, 140000);
}

// ---------- gc2 body (MFMA split-bf16, K=128) ----------

template<int DEG>
__device__ __forceinline__ void gc2m_body(
    int blk, ushort_t* Sh, ushort_t* Sl, ushort_t* Nh, ushort_t* Nl,
    const float* __restrict__ X, const int* __restrict__ adj,
    const ushort_t* __restrict__ Wsh, const ushort_t* __restrict__ Wsl,
    const ushort_t* __restrict__ Wrh, const ushort_t* __restrict__ Wrl,
    const float* __restrict__ bias,
    const float* __restrict__ bg, const float* __restrict__ bbeta,
    const float* __restrict__ bm, const float* __restrict__ bv,
    float* __restrict__ Out, int start, int count)
{
    const int tid = threadIdx.x;
    const int tileBase = blk * 64;

    for (int idx = tid; idx < 1024; idx += 256) {
        int a = idx >> 4, c = idx & 15;
        int ga = tileBase + a;
        float fs[8] = {0, 0, 0, 0, 0, 0, 0, 0};
        float fn[8] = {0, 0, 0, 0, 0, 0, 0, 0};
        if (ga < count) {
            const float* row = X + (size_t)(start + ga) * 128 + c * 8;
            *(float4*)(&fs[0]) = *(const float4*)row;
            *(float4*)(&fs[4]) = *(const float4*)(row + 4);
            if constexpr (DEG > 0) {
                #pragma unroll
                for (int j = 0; j < DEG; ++j) {
                    int nb = adj[(size_t)ga * DEG + j];
                    const float* nr = X + (size_t)nb * 128 + c * 8;
                    float4 q0 = *(const float4*)nr;
                    float4 q1 = *(const float4*)(nr + 4);
                    fn[0] += q0.x; fn[1] += q0.y; fn[2] += q0.z; fn[3] += q0.w;
                    fn[4] += q1.x; fn[5] += q1.y; fn[6] += q1.z; fn[7] += q1.w;
                }
            }
        }
        int cs = c ^ (a & 15);
        uint4 h, lo;
        split8(fs, h, lo);
        *(uint4*)(Sh + a * 128 + cs * 8) = h;
        *(uint4*)(Sl + a * 128 + cs * 8) = lo;
        if constexpr (DEG > 0) {
            split8(fn, h, lo);
            *(uint4*)(Nh + a * 128 + cs * 8) = h;
            *(uint4*)(Nl + a * 128 + cs * 8) = lo;
        }
    }
    __syncthreads();

    const int w = tid >> 6, l = tid & 63;
    const int lm = l & 15, lq = l >> 4;

    f32x4 acc[4][2];
    #pragma unroll
    for (int rt = 0; rt < 4; ++rt)
        #pragma unroll
        for (int ti = 0; ti < 2; ++ti)
            acc[rt][ti] = (f32x4){0.f, 0.f, 0.f, 0.f};

    for (int ks = 0; ks < 4; ++ks) {
        short8v ash[4], asl[4], anh[4], anl[4];
        #pragma unroll
        for (int rt = 0; rt < 4; ++rt) {
            int a = rt * 16 + lm;
            int cs = (ks * 4 + lq) ^ lm;
            ash[rt] = *(const short8v*)(Sh + a * 128 + cs * 8);
            asl[rt] = *(const short8v*)(Sl + a * 128 + cs * 8);
            if constexpr (DEG > 0) {
                anh[rt] = *(const short8v*)(Nh + a * 128 + cs * 8);
                anl[rt] = *(const short8v*)(Nl + a * 128 + cs * 8);
            }
        }
        #pragma unroll
        for (int ti = 0; ti < 2; ++ti) {
            int fid = ((w + ti * 4) * 4 + ks) * 64 + l;
            short8v bh = *(const short8v*)(Wsh + (size_t)fid * 8);
            short8v bl = *(const short8v*)(Wsl + (size_t)fid * 8);
            #pragma unroll
            for (int rt = 0; rt < 4; ++rt) {
                acc[rt][ti] = __builtin_amdgcn_mfma_f32_16x16x32_bf16(ash[rt], bh, acc[rt][ti], 0, 0, 0);
                acc[rt][ti] = __builtin_amdgcn_mfma_f32_16x16x32_bf16(asl[rt], bh, acc[rt][ti], 0, 0, 0);
                acc[rt][ti] = __builtin_amdgcn_mfma_f32_16x16x32_bf16(ash[rt], bl, acc[rt][ti], 0, 0, 0);
            }
            if constexpr (DEG > 0) {
                short8v rh = *(const short8v*)(Wrh + (size_t)fid * 8);
                short8v rl = *(const short8v*)(Wrl + (size_t)fid * 8);
                #pragma unroll
                for (int rt = 0; rt < 4; ++rt) {
                    acc[rt][ti] = __builtin_amdgcn_mfma_f32_16x16x32_bf16(anh[rt], rh, acc[rt][ti], 0, 0, 0);
                    acc[rt][ti] = __builtin_amdgcn_mfma_f32_16x16x32_bf16(anl[rt], rh, acc[rt][ti], 0, 0, 0);
                    acc[rt][ti] = __builtin_amdgcn_mfma_f32_16x16x32_bf16(anh[rt], rl, acc[rt][ti], 0, 0, 0);
                }
            }
        }
    }

    #pragma unroll
    for (int ti = 0; ti < 2; ++ti) {
        int cc = (w + ti * 4) * 16 + lm;
        float bz = bias[cc];
        float s = bg[cc] * rsqrtf(bv[cc] + BN_EPS);
        float sb = bbeta[cc] - bm[cc] * s;
        #pragma unroll
        for (int rt = 0; rt < 4; ++rt) {
            #pragma unroll
            for (int r = 0; r < 4; ++r) {
                int ga = tileBase + rt * 16 + lq * 4 + r;
                if (ga < count)
                    Out[(size_t)(start + ga) * 128 + cc] =
                        fast_tanh(acc[rt][ti][r] + bz) * s + sb;
            }
        }
    }
}

// merged gc2: same block boundaries as gc1
__global__ __launch_bounds__(256)
void k_gc2m_all(const float* __restrict__ X,
                const int* __restrict__ adj1, const int* __restrict__ adj2,
                const int* __restrict__ adj3, const int* __restrict__ adj4,
                const ushort_t* __restrict__ Fh, const ushort_t* __restrict__ Fl,
                const float* __restrict__ g2b,
                const float* __restrict__ bg, const float* __restrict__ bbeta,
                const float* __restrict__ bm, const float* __restrict__ bv,
                float* __restrict__ Out)
{
    __shared__ __align__(16) ushort_t Sh[64 * 128];
    __shared__ __align__(16) ushort_t Sl[64 * 128];
    __shared__ __align__(16) ushort_t Nh[64 * 128];
    __shared__ __align__(16) ushort_t Nl[64 * 128];
    const size_t MS = (size_t)2048 * 8;
    int b = blockIdx.x;
    if (b < 157)
        gc2m_body<0>(b, Sh, Sl, Nh, Nl, X, nullptr,
            Fh + 0 * MS, Fl + 0 * MS, nullptr, nullptr,
            g2b + 0 * 128, bg, bbeta, bm, bv, Out, 0, 10000);
    else if (b < 3907)
        gc2m_body<1>(b - 157, Sh, Sl, Nh, Nl, X, adj1,
            Fh + 1 * MS, Fl + 1 * MS, Fh + 5 * MS, Fl + 5 * MS,
            g2b + 1 * 128, bg, bbeta, bm, bv, Out, 10000, 240000);
    else if (b < 9532)
        gc2m_body<2>(b - 3907, Sh, Sl, Nh, Nl, X, adj2,
            Fh + 2 * MS, Fl + 2 * MS, Fh + 6 * MS, Fl + 6 * MS,
            g2b + 2 * 128, bg, bbeta, bm, bv, Out, 250000, 360000);
    else if (b < 13439)
        gc2m_body<3>(b - 9532, Sh, Sl, Nh, Nl, X, adj3,
            Fh + 3 * MS, Fl + 3 * MS, Fh + 7 * MS, Fl + 7 * MS,
            g2b + 3 * 128, bg, bbeta, bm, bv, Out, 610000, 250000);
    else
        gc2m_body<4>(b - 13439, Sh, Sl, Nh, Nl, X, adj4,
            Fh + 4 * MS, Fl + 4 * MS, Fh + 8 * MS, Fl + 8 * MS,
            g2b + 4 * 128, bg, bbeta, bm, bv, Out, 860000, 140000);
}

// ---------- pool1 body (f32 -> f32) ----------

template<int DEG>
__device__ __forceinline__ void pool_body(
    int blk, const float* __restrict__ X, const int* __restrict__ adj,
    float* __restrict__ Out, int start, int count)
{
    int t = blk * 256 + threadIdx.x;
    int a = t >> 5;
    if (a >= count) return;
    int c4 = t & 31;
    const float4* X4 = (const float4*)X;
    float4 v = X4[(size_t)(start + a) * 32 + c4];
    #pragma unroll
    for (int j = 0; j < DEG; ++j) {
        int nb = adj[(size_t)a * DEG + j];
        float4 q = X4[(size_t)nb * 32 + c4];
        v.x = fmaxf(v.x, q.x); v.y = fmaxf(v.y, q.y);
        v.z = fmaxf(v.z, q.z); v.w = fmaxf(v.w, q.w);
    }
    ((float4*)Out)[(size_t)(start + a) * 32 + c4] = v;
}

// merged pool1: blocks [0,1250) d0 | [1250,31250) d1 | [31250,76250) d2 | [76250,107500) d3 | [107500,125000) d4
__global__ void k_pool_all(const float* __restrict__ X,
                           const int* __restrict__ adj1, const int* __restrict__ adj2,
                           const int* __restrict__ adj3, const int* __restrict__ adj4,
                           float* __restrict__ Out)
{
    int b = blockIdx.x;
    if (b < 1250)        pool_body<0>(b, X, nullptr, Out, 0, 10000);
    else if (b < 31250)  pool_body<1>(b - 1250, X, adj1, Out, 10000, 240000);
    else if (b < 76250)  pool_body<2>(b - 31250, X, adj2, Out, 250000, 360000);
    else if (b < 107500) pool_body<3>(b - 76250, X, adj3, Out, 610000, 250000);
    else                 pool_body<4>(b - 107500, X, adj4, Out, 860000, 140000);
}

// ---------- pool2 body (f32 -> split bf16 planes, sorted scatter) ----------

template<int DEG>
__device__ __forceinline__ void pool_split_body(
    int blk, const float* __restrict__ X, const int* __restrict__ adj,
    const int* __restrict__ invperm,
    ushort_t* __restrict__ PH, ushort_t* __restrict__ PL,
    int start, int count)
{
    int t = blk * 256 + threadIdx.x;
    int a = t >> 4;
    if (a >= count) return;
    int c8 = (t & 15) * 8;
    const float* row = X + (size_t)(start + a) * 128 + c8;
    float f[8];
    *(float4*)(&f[0]) = *(const float4*)row;
    *(float4*)(&f[4]) = *(const float4*)(row + 4);
    #pragma unroll
    for (int j = 0; j < DEG; ++j) {
        int nb = adj[(size_t)a * DEG + j];
        const float* nr = X + (size_t)nb * 128 + c8;
        float4 q0 = *(const float4*)nr;
        float4 q1 = *(const float4*)(nr + 4);
        f[0] = fmaxf(f[0], q0.x); f[1] = fmaxf(f[1], q0.y);
        f[2] = fmaxf(f[2], q0.z); f[3] = fmaxf(f[3], q0.w);
        f[4] = fmaxf(f[4], q1.x); f[5] = fmaxf(f[5], q1.y);
        f[6] = fmaxf(f[6], q1.z); f[7] = fmaxf(f[7], q1.w);
    }
    uint4 h, lo; split8(f, h, lo);
    int dst = invperm[start + a];
    *(uint4*)(PH + (size_t)dst * 128 + c8) = h;
    *(uint4*)(PL + (size_t)dst * 128 + c8) = lo;
}

// merged pool2: blocks [0,625) d0 | [625,15625) d1 | [15625,38125) d2 | [38125,53750) d3 | [53750,62500) d4
__global__ void k_pool_split_all(const float* __restrict__ X,
                                 const int* __restrict__ adj1, const int* __restrict__ adj2,
                                 const int* __restrict__ adj3, const int* __restrict__ adj4,
                                 const int* __restrict__ invperm,
                                 ushort_t* __restrict__ PH, ushort_t* __restrict__ PL)
{
    int b = blockIdx.x;
    if (b < 625)        pool_split_body<0>(b, X, nullptr, invperm, PH, PL, 0, 10000);
    else if (b < 15625) pool_split_body<1>(b - 625, X, adj1, invperm, PH, PL, 10000, 240000);
    else if (b < 38125) pool_split_body<2>(b - 15625, X, adj2, invperm, PH, PL, 250000, 360000);
    else if (b < 53750) pool_split_body<3>(b - 38125, X, adj3, invperm, PH, PL, 610000, 250000);
    else                pool_split_body<4>(b - 53750, X, adj4, invperm, PH, PL, 860000, 140000);
}

// ---------- dense via MFMA split-bf16 (tanh + bn3) + subtile partials ----------

__global__ __launch_bounds__(256)
void k_dense_mfma(const ushort_t* __restrict__ PH,
                  const ushort_t* __restrict__ PL,
                  const int*   __restrict__ sortedMemb,
                  const int*   __restrict__ cumSeg,
                  const ushort_t* __restrict__ Bh,
                  const ushort_t* __restrict__ Bl,
                  const float* __restrict__ bias,
                  const float* __restrict__ bg, const float* __restrict__ bbeta,
                  const float* __restrict__ bm, const float* __restrict__ bv,
                  float* __restrict__ partials)
{
    __shared__ __align__(16) char smem[33792];
    __shared__ int sM[64];
    ushort_t* Ah = (ushort_t*)smem;
    ushort_t* Al = (ushort_t*)(smem + 16384);
    float*    Yt = (float*)smem;

    const int tid = threadIdx.x;
    const int tileBase = blockIdx.x * 64;
    if (tid < 64) sM[tid] = sortedMemb[tileBase + tid];

    for (int idx = tid; idx < 1024; idx += 256) {
        int a = idx >> 4, c = idx & 15;
        size_t off = (size_t)(tileBase + a) * 128 + c * 8;
        uint4 h  = *(const uint4*)(PH + off);
        uint4 lo = *(const uint4*)(PL + off);
        int cs = c ^ (a & 15);
        *(uint4*)(Ah + a * 128 + cs * 8) = h;
        *(uint4*)(Al + a * 128 + cs * 8) = lo;
    }
    __syncthreads();

    const int w = tid >> 6, l = tid & 63;
    const int lm = l & 15, lq = l >> 4;

    f32x4 acc[4][4];
    #pragma unroll
    for (int rt = 0; rt < 4; ++rt)
        #pragma unroll
        for (int ti = 0; ti < 4; ++ti)
            acc[rt][ti] = (f32x4){0.f, 0.f, 0.f, 0.f};

    for (int ks = 0; ks < 4; ++ks) {
        short8v ah[4], al[4];
        #pragma unroll
        for (int rt = 0; rt < 4; ++rt) {
            int a = rt * 16 + lm;
            int cs = (ks * 4 + lq) ^ lm;
            ah[rt] = *(const short8v*)(Ah + a * 128 + cs * 8);
            al[rt] = *(const short8v*)(Al + a * 128 + cs * 8);
        }
        #pragma unroll
        for (int ti = 0; ti < 4; ++ti) {
            int fid = ((w + ti * 4) * 4 + ks) * 64 + l;
            short8v bh = *(const short8v*)(Bh + (size_t)fid * 8);
            short8v bl = *(const short8v*)(Bl + (size_t)fid * 8);
            #pragma unroll
            for (int rt = 0; rt < 4; ++rt) {
                acc[rt][ti] = __builtin_amdgcn_mfma_f32_16x16x32_bf16(ah[rt], bh, acc[rt][ti], 0, 0, 0);
                acc[rt][ti] = __builtin_amdgcn_mfma_f32_16x16x32_bf16(al[rt], bh, acc[rt][ti], 0, 0, 0);
                acc[rt][ti] = __builtin_amdgcn_mfma_f32_16x16x32_bf16(ah[rt], bl, acc[rt][ti], 0, 0, 0);
            }
        }
    }

    float bvz[4], scv[4], shv[4];
    #pragma unroll
    for (int ti = 0; ti < 4; ++ti) {
        int c = (w + ti * 4) * 16 + lm;
        bvz[ti] = bias[c];
        float s = bg[c] * rsqrtf(bv[c] + BN_EPS);
        scv[ti] = s;
        shv[ti] = bbeta[c] - bm[c] * s;
    }

    const int q = tid >> 5, cg = tid & 31;
    const int sub = blockIdx.x * 8 + q;
    const size_t slotBase = (size_t)cumSeg[sub];
    const int fs = sM[q * 8];

    #pragma unroll
    for (int hf = 0; hf < 2; ++hf) {
        __syncthreads();
        #pragma unroll
        for (int tj = 0; tj < 2; ++tj) {
            int ti = 2 * hf + tj;
            int colh = (w + ti * 4) * 16 + lm - hf * 128;
            #pragma unroll
            for (int rt = 0; rt < 4; ++rt)
                #pragma unroll
                for (int r = 0; r < 4; ++r) {
                    int row = rt * 16 + lq * 4 + r;
                    float y = fast_tanh(acc[rt][ti][r] + bvz[ti]) * scv[ti] + shv[ti];
                    Yt[row * 132 + colh] = y;
                }
        }
        __syncthreads();

        float4 ys, ym;
        int cur = sM[q * 8];
        {
            float4 v = *(const float4*)(Yt + (q * 8) * 132 + cg * 4);
            ys = v; ym = v;
        }
        #pragma unroll
        for (int i = 1; i < 8; ++i) {
            float4 v = *(const float4*)(Yt + (q * 8 + i) * 132 + cg * 4);
            int m = sM[q * 8 + i];
            if (m == cur) {
                ys.x += v.x; ys.y += v.y; ys.z += v.z; ys.w += v.w;
                ym.x = fmaxf(ym.x, v.x); ym.y = fmaxf(ym.y, v.y);
                ym.z = fmaxf(ym.z, v.z); ym.w = fmaxf(ym.w, v.w);
            } else {
                float* p = partials + (slotBase + (cur - fs)) * 512 + hf * 128 + cg * 4;
                *(float4*)p         = ys;
                *(float4*)(p + 256) = ym;
                cur = m; ys = v; ym = v;
            }
        }
        float* p = partials + (slotBase + (cur - fs)) * 512 + hf * 128 + cg * 4;
        *(float4*)p         = ys;
        *(float4*)(p + 256) = ym;
    }
}

// ---------- combine partials -> final out (tanh fused) ----------

__global__ __launch_bounds__(256)
void k_combine(const float* __restrict__ partials,
               const int* __restrict__ binBase, const int* __restrict__ binCnt,
               const int* __restrict__ firstSeg, const int* __restrict__ cumSeg,
               float* __restrict__ Out)
{
    int sid = blockIdx.x * 4 + (threadIdx.x >> 6);
    if (sid >= 40000) return;
    int lane = threadIdx.x & 63;
    int b = binBase[sid], n = binCnt[sid];

    float4 s = make_float4(0.f, 0.f, 0.f, 0.f);
    float4 m = make_float4(-INFINITY, -INFINITY, -INFINITY, -INFINITY);
    if (n > 0) {
        int s0 = b >> 3, s1 = (b + n - 1) >> 3;
        for (int t = s0; t <= s1; ++t) {
            size_t slot = (size_t)cumSeg[t] + (sid - firstSeg[t]);
            const float4* P = (const float4*)(partials + slot * 512);
            float4 a = P[lane];
            float4 x = P[64 + lane];
            s.x += a.x; s.y += a.y; s.z += a.z; s.w += a.w;
            m.x = fmaxf(m.x, x.x); m.y = fmaxf(m.y, x.y);
            m.z = fmaxf(m.z, x.z); m.w = fmaxf(m.w, x.w);
        }
    }
    float4 os = make_float4(fast_tanh(s.x), fast_tanh(s.y), fast_tanh(s.z), fast_tanh(s.w));
    float4 om = make_float4(fast_tanh(m.x), fast_tanh(m.y), fast_tanh(m.z), fast_tanh(m.w));
    *(float4*)(Out + (size_t)sid * 512 + lane * 4)       = os;
    *(float4*)(Out + (size_t)sid * 512 + 256 + lane * 4) = om;
}

// ---------- launcher ----------

extern "C" void kernel_launch(void* const* d_in, const int* in_sizes, int n_in,
                              void* d_out, int out_size, void* d_ws, size_t ws_size,
                              hipStream_t stream)
{
    const float* atom = (const float*)d_in[0];
    const int*   memb = (const int*)d_in[1];
    const int*   adj1 = (const int*)d_in[2];
    const int*   adj2 = (const int*)d_in[3];
    const int*   adj3 = (const int*)d_in[4];
    const int*   adj4 = (const int*)d_in[5];
    const float* g1Ws = (const float*)d_in[6];
    const float* g1Wr = (const float*)d_in[7];
    const float* g1b  = (const float*)d_in[8];
    const float* g2Ws = (const float*)d_in[9];
    const float* g2Wr = (const float*)d_in[10];
    const float* g2b  = (const float*)d_in[11];
    const float* bn1g = (const float*)d_in[12];
    const float* bn1b = (const float*)d_in[13];
    const float* bn1m = (const float*)d_in[14];
    const float* bn1v = (const float*)d_in[15];
    const float* bn3g = (const float*)d_in[16];
    const float* bn3b = (const float*)d_in[17];
    const float* bn3m = (const float*)d_in[18];
    const float* bn3v = (const float*)d_in[19];
    const float* dW   = (const float*)d_in[20];
    const float* db   = (const float*)d_in[21];

    char* ws = (char*)d_ws;
    float* bufA = (float*)ws;                    // [1M][128] f32, 512 MB
    float* bufB = (float*)(ws + 512000000);      // [1M][128] f32, 512 MB
    char*  outc = (char*)d_out;                  // [40000][512] f32 = 81.92 MB
    float* out  = (float*)d_out;

    // pool2 split planes (sorted row order) live in bufB:
    ushort_t* PH = (ushort_t*)bufB;              // 256 MB
    ushort_t* PL = PH + (size_t)1000000 * 128;   // 256 MB

    // temp regions in d_out (all fully overwritten by k_combine at the end):
    ushort_t* gFh   = (ushort_t*)(outc);              // gc2 frags 294,912 B
    ushort_t* gFl   = (ushort_t*)(outc + 294912);
    ushort_t* g1Fh  = (ushort_t*)(outc + 589824);     // gc1 frags 221,184 B
    ushort_t* g1Fl  = (ushort_t*)(outc + 811008);
    ushort_t* dWh   = (ushort_t*)(outc + 1032192);    // dense frags 65,536 B
    ushort_t* dWl   = (ushort_t*)(outc + 1097728);
    int* invperm    = (int*)(outc + 1200000);         // 4,000,000 B
    int* sortedMemb = (int*)(outc + 5200000);         // 4,000,000 B
    int* binCnt     = (int*)(outc + 9200000);         // 160,000 B
    int* binBase    = (int*)(outc + 9360000);
    int* binFill    = (int*)(outc + 9520000);
    int* firstSeg   = (int*)(outc + 9680000);         // 500,000 B
    int* segCnt     = (int*)(outc + 10180000);
    int* cumSeg     = (int*)(outc + 10680000);        // ends ~11.2 MB << 82 MB

    // partials + combine-metadata copies live in bufA (dead after pool_split):
    float* partials = bufA;                           // <=165k slots x 2 KB = 338 MB
    int* cBinBase   = (int*)(ws + 400000000);
    int* cBinCnt    = (int*)(ws + 401000000);
    int* cFirstSeg  = (int*)(ws + 402000000);
    int* cCumSeg    = (int*)(ws + 403000000);

    // ---- W fragment prep + counting sort (depend only on inputs) ----
    k_prepW2<<<72, 256, 0, stream>>>(g2Ws, g2Wr, gFh, gFl);
    k_prepW1<<<54, 256, 0, stream>>>(g1Ws, g1Wr, g1Fh, g1Fl);
    k_prepW<<<16, 256, 0, stream>>>(dW, dWh, dWl);
    k_zero_bins<<<(40000 + 255) / 256, 256, 0, stream>>>(binCnt, binFill);
    k_hist<<<(1000000 + 255) / 256, 256, 0, stream>>>(memb, binCnt);
    k_scan<<<1, 1024, 0, stream>>>(binCnt, binBase);
    k_scatter<<<(1000000 + 255) / 256, 256, 0, stream>>>(memb, binBase, binFill,
        invperm, sortedMemb);
    k_meta<<<(125000 + 255) / 256, 256, 0, stream>>>(sortedMemb, firstSeg, segCnt);
    k_scan2<<<1, 1024, 0, stream>>>(segCnt, cumSeg);

    // ---- gc1 (MFMA, merged): atom -> bufA ----
    k_gc1m_all<<<15627, 256, 0, stream>>>(atom, adj1, adj2, adj3, adj4,
        g1Fh, g1Fl, g1b, bn1g, bn1b, bn1m, bn1v, bufA);

    // ---- pool1 (merged): bufA -> bufB (f32) ----
    k_pool_all<<<125000, 256, 0, stream>>>(bufA, adj1, adj2, adj3, adj4, bufB);

    // ---- gc2 (MFMA, merged): bufB -> bufA ----
    k_gc2m_all<<<15627, 256, 0, stream>>>(bufB, adj1, adj2, adj3, adj4,
        gFh, gFl, g2b, bn1g, bn1b, bn1m, bn1v, bufA);

    // ---- pool2 (merged): bufA -> PH/PL at sorted positions ----
    k_pool_split_all<<<62500, 256, 0, stream>>>(bufA, adj1, adj2, adj3, adj4,
        invperm, PH, PL);

    // ---- copy combine-metadata out of d_out into bufA tail (bufA now dead) ----
    k_copymeta<<<(125000 + 255) / 256, 256, 0, stream>>>(binBase, binCnt,
        firstSeg, cumSeg, cBinBase, cBinCnt, cFirstSeg, cCumSeg);

    // ---- dense (MFMA, sequential staging) -> partials in bufA ----
    k_dense_mfma<<<15625, 256, 0, stream>>>(PH, PL, sortedMemb, cumSeg, dWh, dWl,
        db, bn3g, bn3b, bn3m, bn3v, partials);

    // ---- combine partials -> out (reads metadata from bufA copies) ----
    k_combine<<<10000, 256, 0, stream>>>(partials, cBinBase, cBinCnt,
        cFirstSeg, cCumSeg, out);
}

// Round 15
// 2655.797 us; speedup vs baseline: 1.2179x; 1.0758x over previous
//
#include <hip/hip_runtime.h>
#include <hip/hip_bf16.h>
#include <cstdint>
#include <cstddef>

#define BN_EPS 1e-3f
typedef unsigned short ushort_t;
typedef unsigned int uint_t;
typedef __attribute__((ext_vector_type(8))) short short8v;   // 8 bf16 (4 VGPRs)
typedef __attribute__((ext_vector_type(4))) float f32x4;     // MFMA C/D

// ---------- numeric helpers ----------

__device__ __forceinline__ float fast_tanh(float x) {
    float xc = fminf(fmaxf(x, -12.0f), 12.0f);
    float e = __expf(2.0f * xc);
    return (e - 1.0f) * __builtin_amdgcn_rcpf(e + 1.0f);
}

__device__ __forceinline__ float bf2f(uint_t u) {
    return __uint_as_float(u << 16);
}
__device__ __forceinline__ ushort_t f2bf(float f) {
    union { __hip_bfloat16 h; ushort_t u; } cv;
    cv.h = __float2bfloat16(f);   // RNE
    return cv.u;
}

__device__ __forceinline__ void split8(const float* f, uint4& h, uint4& lo) {
    uint_t hh[8], ll[8];
    #pragma unroll
    for (int j = 0; j < 8; ++j) {
        float x = f[j];
        ushort_t xh = f2bf(x);
        float xr = x - bf2f(xh);
        hh[j] = xh;
        ll[j] = f2bf(xr);
    }
    h  = make_uint4(hh[0] | (hh[1] << 16), hh[2] | (hh[3] << 16),
                    hh[4] | (hh[5] << 16), hh[6] | (hh[7] << 16));
    lo = make_uint4(ll[0] | (ll[1] << 16), ll[2] | (ll[3] << 16),
                    ll[4] | (ll[5] << 16), ll[6] | (ll[7] << 16));
}

// accumulate 8 packed bf16 (one uint4) into f[8]
__device__ __forceinline__ void add8(float* f, uint4 v) {
    f[0] += bf2f(v.x & 0xffffu); f[1] += bf2f(v.x >> 16);
    f[2] += bf2f(v.y & 0xffffu); f[3] += bf2f(v.y >> 16);
    f[4] += bf2f(v.z & 0xffffu); f[5] += bf2f(v.z >> 16);
    f[6] += bf2f(v.w & 0xffffu); f[7] += bf2f(v.w >> 16);
}

// ---------- atom features -> pre-split padded bf16 planes [1M][96] ----------

__global__ void k_prepX(const float* __restrict__ atom,
                        ushort_t* __restrict__ XH, ushort_t* __restrict__ XL) {
    int idx = blockIdx.x * 256 + threadIdx.x;   // [0, 12M)
    if (idx >= 12000000) return;
    int row = idx / 12;
    int c = idx - row * 12;
    int k0 = c * 8;
    const float* r = atom + (size_t)row * 75;
    float f[8];
    #pragma unroll
    for (int j = 0; j < 8; ++j)
        f[j] = (k0 + j < 75) ? r[k0 + j] : 0.0f;
    uint4 h, lo; split8(f, h, lo);
    *(uint4*)(XH + (size_t)row * 96 + k0) = h;
    *(uint4*)(XL + (size_t)row * 96 + k0) = lo;
}

// ---------- counting sort of atoms by membership (ascending) ----------

__global__ void k_zero_bins(int* __restrict__ binCnt, int* __restrict__ binFill) {
    int t = blockIdx.x * 256 + threadIdx.x;
    if (t < 40000) { binCnt[t] = 0; binFill[t] = 0; }
}

__global__ void k_hist(const int* __restrict__ memb, int* __restrict__ binCnt) {
    int t = blockIdx.x * 256 + threadIdx.x;
    if (t < 1000000) atomicAdd(&binCnt[memb[t]], 1);
}

__global__ __launch_bounds__(1024)
void k_scan(const int* __restrict__ binCnt, int* __restrict__ binBase) {
    __shared__ int part[1024];
    const int t = threadIdx.x;
    const int base = t * 40;
    int local[40];
    int s = 0;
    #pragma unroll
    for (int j = 0; j < 40; ++j) {
        int idx = base + j;
        int c = (idx < 40000) ? binCnt[idx] : 0;
        local[j] = s;
        s += c;
    }
    part[t] = s;
    __syncthreads();
    for (int off = 1; off < 1024; off <<= 1) {
        int v = (t >= off) ? part[t - off] : 0;
        __syncthreads();
        part[t] += v;
        __syncthreads();
    }
    int add = (t > 0) ? part[t - 1] : 0;
    #pragma unroll
    for (int j = 0; j < 40; ++j) {
        int idx = base + j;
        if (idx < 40000) binBase[idx] = add + local[j];
    }
}

__global__ void k_scatter(const int* __restrict__ memb, const int* __restrict__ binBase,
                          int* __restrict__ binFill,
                          int* __restrict__ invperm, int* __restrict__ sortedMemb) {
    int t = blockIdx.x * 256 + threadIdx.x;
    if (t < 1000000) {
        int m = memb[t];
        int pos = binBase[m] + atomicAdd(&binFill[m], 1);
        invperm[t] = pos;
        sortedMemb[pos] = m;
    }
}

// ---------- subtile metadata ----------

__global__ void k_meta(const int* __restrict__ sortedMemb,
                       int* __restrict__ firstSeg, int* __restrict__ segCnt) {
    int t = blockIdx.x * 256 + threadIdx.x;
    if (t < 125000) {
        int f = sortedMemb[8 * t];
        int l = sortedMemb[8 * t + 7];
        firstSeg[t] = f;
        segCnt[t] = l - f + 1;
    }
}

__global__ __launch_bounds__(1024)
void k_scan2(const int* __restrict__ segCnt, int* __restrict__ cumSeg) {
    __shared__ int part[1024];
    const int t = threadIdx.x;
    const int base = t * 123;
    int s = 0;
    for (int j = 0; j < 123; ++j) {
        int idx = base + j;
        if (idx < 125000) s += segCnt[idx];
    }
    part[t] = s;
    __syncthreads();
    for (int off = 1; off < 1024; off <<= 1) {
        int v = (t >= off) ? part[t - off] : 0;
        __syncthreads();
        part[t] += v;
        __syncthreads();
    }
    int run = (t > 0) ? part[t - 1] : 0;
    for (int j = 0; j < 123; ++j) {
        int idx = base + j;
        if (idx < 125000) { cumSeg[idx] = run; run += segCnt[idx]; }
    }
}

__global__ void k_copymeta(const int* __restrict__ binBase, const int* __restrict__ binCnt,
                           const int* __restrict__ firstSeg, const int* __restrict__ cumSeg,
                           int* __restrict__ dBinBase, int* __restrict__ dBinCnt,
                           int* __restrict__ dFirstSeg, int* __restrict__ dCumSeg) {
    int t = blockIdx.x * 256 + threadIdx.x;
    if (t < 40000) { dBinBase[t] = binBase[t]; dBinCnt[t] = binCnt[t]; }
    if (t < 125000) { dFirstSeg[t] = firstSeg[t]; dCumSeg[t] = cumSeg[t]; }
}

// ---------- W fragment prep ----------

__global__ void k_prepW(const float* __restrict__ W,
                        ushort_t* __restrict__ Bh, ushort_t* __restrict__ Bl) {
    int idx = blockIdx.x * 256 + threadIdx.x;
    if (idx >= 4096) return;
    int l = idx & 63, g = idx >> 6;
    int tn = g >> 2, ks = g & 3;
    int n = tn * 16 + (l & 15);
    int k0 = ks * 32 + (l >> 4) * 8;
    float f[8];
    #pragma unroll
    for (int j = 0; j < 8; ++j) f[j] = W[(size_t)(k0 + j) * 256 + n];
    uint4 h, lo; split8(f, h, lo);
    *(uint4*)(Bh + (size_t)idx * 8) = h;
    *(uint4*)(Bl + (size_t)idx * 8) = lo;
}

__global__ void k_prepW2(const float* __restrict__ Ws5, const float* __restrict__ Wr4,
                         ushort_t* __restrict__ Fh, ushort_t* __restrict__ Fl) {
    int idx = blockIdx.x * 256 + threadIdx.x;
    if (idx >= 18432) return;
    int mat = idx >> 11;
    int fid = idx & 2047;
    int l = fid & 63, g = fid >> 6;
    int tn = g >> 2, ks = g & 3;
    int n = tn * 16 + (l & 15);
    int k0 = ks * 32 + (l >> 4) * 8;
    const float* W = (mat < 5) ? (Ws5 + (size_t)mat * 16384)
                               : (Wr4 + (size_t)(mat - 5) * 16384);
    float f[8];
    #pragma unroll
    for (int j = 0; j < 8; ++j) f[j] = W[(size_t)(k0 + j) * 128 + n];
    uint4 h, lo; split8(f, h, lo);
    *(uint4*)(Fh + (size_t)idx * 8) = h;
    *(uint4*)(Fl + (size_t)idx * 8) = lo;
}

__global__ void k_prepW1(const float* __restrict__ Ws5, const float* __restrict__ Wr4,
                         ushort_t* __restrict__ Fh, ushort_t* __restrict__ Fl) {
    int idx = blockIdx.x * 256 + threadIdx.x;
    if (idx >= 13824) return;
    int mat = idx / 1536;
    int fid = idx - mat * 1536;
    int l = fid & 63, g = fid >> 6;
    int tn = g / 3, ks = g - tn * 3;
    int n = tn * 16 + (l & 15);
    int k0 = ks * 32 + (l >> 4) * 8;
    const float* W = (mat < 5) ? (Ws5 + (size_t)mat * 9600)
                               : (Wr4 + (size_t)(mat - 5) * 9600);
    float f[8];
    #pragma unroll
    for (int j = 0; j < 8; ++j)
        f[j] = (k0 + j < 75) ? W[(size_t)(k0 + j) * 128 + n] : 0.0f;
    uint4 h, lo; split8(f, h, lo);
    *(uint4*)(Fh + (size_t)idx * 8) = h;
    *(uint4*)(Fl + (size_t)idx * 8) = lo;
}

// ---------- gc1 body (MFMA split-bf16, K=96; pre-split input planes) ----------

template<int DEG>
__device__ __forceinline__ void gc1m_body(
    int blk, ushort_t* Sh, ushort_t* Sl, ushort_t* Nh, ushort_t* Nl,
    const ushort_t* __restrict__ XH, const ushort_t* __restrict__ XL,
    const int* __restrict__ adj,
    const ushort_t* __restrict__ Wsh, const ushort_t* __restrict__ Wsl,
    const ushort_t* __restrict__ Wrh, const ushort_t* __restrict__ Wrl,
    const float* __restrict__ bias,
    const float* __restrict__ bg, const float* __restrict__ bbeta,
    const float* __restrict__ bm, const float* __restrict__ bv,
    float* __restrict__ Out, int start, int count)
{
    const int tid = threadIdx.x;
    const int tileBase = blk * 64;

    for (int idx = tid; idx < 64 * 12; idx += 256) {
        int a = idx / 12;
        int c = idx - a * 12;
        int ga = tileBase + a;
        uint4 sh = make_uint4(0u, 0u, 0u, 0u);
        uint4 sl = make_uint4(0u, 0u, 0u, 0u);
        float fn[8] = {0, 0, 0, 0, 0, 0, 0, 0};
        if (ga < count) {
            size_t off = (size_t)(start + ga) * 96 + c * 8;
            sh = *(const uint4*)(XH + off);
            sl = *(const uint4*)(XL + off);
            if constexpr (DEG > 0) {
                #pragma unroll
                for (int jj = 0; jj < DEG; ++jj) {
                    int nb = adj[(size_t)ga * DEG + jj];
                    size_t noff = (size_t)nb * 96 + c * 8;
                    add8(fn, *(const uint4*)(XH + noff));
                    add8(fn, *(const uint4*)(XL + noff));
                }
            }
        }
        int cs = c ^ (a & 15);
        *(uint4*)(Sh + a * 128 + cs * 8) = sh;
        *(uint4*)(Sl + a * 128 + cs * 8) = sl;
        if constexpr (DEG > 0) {
            uint4 h, lo;
            split8(fn, h, lo);
            *(uint4*)(Nh + a * 128 + cs * 8) = h;
            *(uint4*)(Nl + a * 128 + cs * 8) = lo;
        }
    }
    __syncthreads();

    const int w = tid >> 6, l = tid & 63;
    const int lm = l & 15, lq = l >> 4;

    f32x4 acc[4][2];
    #pragma unroll
    for (int rt = 0; rt < 4; ++rt)
        #pragma unroll
        for (int ti = 0; ti < 2; ++ti)
            acc[rt][ti] = (f32x4){0.f, 0.f, 0.f, 0.f};

    for (int ks = 0; ks < 3; ++ks) {
        short8v ash[4], asl[4], anh[4], anl[4];
        #pragma unroll
        for (int rt = 0; rt < 4; ++rt) {
            int a = rt * 16 + lm;
            int cs = (ks * 4 + lq) ^ lm;
            ash[rt] = *(const short8v*)(Sh + a * 128 + cs * 8);
            asl[rt] = *(const short8v*)(Sl + a * 128 + cs * 8);
            if constexpr (DEG > 0) {
                anh[rt] = *(const short8v*)(Nh + a * 128 + cs * 8);
                anl[rt] = *(const short8v*)(Nl + a * 128 + cs * 8);
            }
        }
        #pragma unroll
        for (int ti = 0; ti < 2; ++ti) {
            int fid = ((w + ti * 4) * 3 + ks) * 64 + l;
            short8v bh = *(const short8v*)(Wsh + (size_t)fid * 8);
            short8v bl = *(const short8v*)(Wsl + (size_t)fid * 8);
            #pragma unroll
            for (int rt = 0; rt < 4; ++rt) {
                acc[rt][ti] = __builtin_amdgcn_mfma_f32_16x16x32_bf16(ash[rt], bh, acc[rt][ti], 0, 0, 0);
                acc[rt][ti] = __builtin_amdgcn_mfma_f32_16x16x32_bf16(asl[rt], bh, acc[rt][ti], 0, 0, 0);
                acc[rt][ti] = __builtin_amdgcn_mfma_f32_16x16x32_bf16(ash[rt], bl, acc[rt][ti], 0, 0, 0);
            }
            if constexpr (DEG > 0) {
                short8v rh = *(const short8v*)(Wrh + (size_t)fid * 8);
                short8v rl = *(const short8v*)(Wrl + (size_t)fid * 8);
                #pragma unroll
                for (int rt = 0; rt < 4; ++rt) {
                    acc[rt][ti] = __builtin_amdgcn_mfma_f32_16x16x32_bf16(anh[rt], rh, acc[rt][ti], 0, 0, 0);
                    acc[rt][ti] = __builtin_amdgcn_mfma_f32_16x16x32_bf16(anl[rt], rh, acc[rt][ti], 0, 0, 0);
                    acc[rt][ti] = __builtin_amdgcn_mfma_f32_16x16x32_bf16(anh[rt], rl, acc[rt][ti], 0, 0, 0);
                }
            }
        }
    }

    #pragma unroll
    for (int ti = 0; ti < 2; ++ti) {
        int cc = (w + ti * 4) * 16 + lm;
        float bz = bias[cc];
        float s = bg[cc] * rsqrtf(bv[cc] + BN_EPS);
        float sb = bbeta[cc] - bm[cc] * s;
        #pragma unroll
        for (int rt = 0; rt < 4; ++rt) {
            #pragma unroll
            for (int r = 0; r < 4; ++r) {
                int ga = tileBase + rt * 16 + lq * 4 + r;
                if (ga < count)
                    Out[(size_t)(start + ga) * 128 + cc] =
                        fast_tanh(acc[rt][ti][r] + bz) * s + sb;
            }
        }
    }
}

// merged gc1: blocks [0,157) d0 | [157,3907) d1 | [3907,9532) d2 | [9532,13439) d3 | [13439,15627) d4
__global__ __launch_bounds__(256)
void k_gc1m_all(const ushort_t* __restrict__ XH, const ushort_t* __restrict__ XL,
                const int* __restrict__ adj1, const int* __restrict__ adj2,
                const int* __restrict__ adj3, const int* __restrict__ adj4,
                const ushort_t* __restrict__ Fh, const ushort_t* __restrict__ Fl,
                const float* __restrict__ g1b,
                const float* __restrict__ bg, const float* __restrict__ bbeta,
                const float* __restrict__ bm, const float* __restrict__ bv,
                float* __restrict__ Out)
{
    __shared__ __align__(16) ushort_t Sh[64 * 128];
    __shared__ __align__(16) ushort_t Sl[64 * 128];
    __shared__ __align__(16) ushort_t Nh[64 * 128];
    __shared__ __align__(16) ushort_t Nl[64 * 128];
    const size_t MS = (size_t)1536 * 8;
    int b = blockIdx.x;
    if (b < 157)
        gc1m_body<0>(b, Sh, Sl, Nh, Nl, XH, XL, nullptr,
            Fh + 0 * MS, Fl + 0 * MS, nullptr, nullptr,
            g1b + 0 * 128, bg, bbeta, bm, bv, Out, 0, 10000);
    else if (b < 3907)
        gc1m_body<1>(b - 157, Sh, Sl, Nh, Nl, XH, XL, adj1,
            Fh + 1 * MS, Fl + 1 * MS, Fh + 5 * MS, Fl + 5 * MS,
            g1b + 1 * 128, bg, bbeta, bm, bv, Out, 10000, 240000);
    else if (b < 9532)
        gc1m_body<2>(b - 3907, Sh, Sl, Nh, Nl, XH, XL, adj2,
            Fh + 2 * MS, Fl + 2 * MS, Fh + 6 * MS, Fl + 6 * MS,
            g1b + 2 * 128, bg, bbeta, bm, bv, Out, 250000, 360000);
    else if (b < 13439)
        gc1m_body<3>(b - 9532, Sh, Sl, Nh, Nl, XH, XL, adj3,
            Fh + 3 * MS, Fl + 3 * MS, Fh + 7 * MS, Fl + 7 * MS,
            g1b + 3 * 128, bg, bbeta, bm, bv, Out, 610000, 250000);
    else
        gc1m_body<4>(b - 13439, Sh, Sl, Nh, Nl, XH, XL, adj4,
            Fh + 4 * MS, Fl + 4 * MS, Fh + 8 * MS, Fl + 8 * MS,
            g1b + 4 * 128, bg, bbeta, bm, bv, Out, 860000, 140000);
}

// ---------- gc2 body (MFMA split-bf16, K=128) ----------

template<int DEG>
__device__ __forceinline__ void gc2m_body(
    int blk, ushort_t* Sh, ushort_t* Sl, ushort_t* Nh, ushort_t* Nl,
    const float* __restrict__ X, const int* __restrict__ adj,
    const ushort_t* __restrict__ Wsh, const ushort_t* __restrict__ Wsl,
    const ushort_t* __restrict__ Wrh, const ushort_t* __restrict__ Wrl,
    const float* __restrict__ bias,
    const float* __restrict__ bg, const float* __restrict__ bbeta,
    const float* __restrict__ bm, const float* __restrict__ bv,
    float* __restrict__ Out, int start, int count)
{
    const int tid = threadIdx.x;
    const int tileBase = blk * 64;

    for (int idx = tid; idx < 1024; idx += 256) {
        int a = idx >> 4, c = idx & 15;
        int ga = tileBase + a;
        float fs[8] = {0, 0, 0, 0, 0, 0, 0, 0};
        float fn[8] = {0, 0, 0, 0, 0, 0, 0, 0};
        if (ga < count) {
            const float* row = X + (size_t)(start + ga) * 128 + c * 8;
            *(float4*)(&fs[0]) = *(const float4*)row;
            *(float4*)(&fs[4]) = *(const float4*)(row + 4);
            if constexpr (DEG > 0) {
                #pragma unroll
                for (int j = 0; j < DEG; ++j) {
                    int nb = adj[(size_t)ga * DEG + j];
                    const float* nr = X + (size_t)nb * 128 + c * 8;
                    float4 q0 = *(const float4*)nr;
                    float4 q1 = *(const float4*)(nr + 4);
                    fn[0] += q0.x; fn[1] += q0.y; fn[2] += q0.z; fn[3] += q0.w;
                    fn[4] += q1.x; fn[5] += q1.y; fn[6] += q1.z; fn[7] += q1.w;
                }
            }
        }
        int cs = c ^ (a & 15);
        uint4 h, lo;
        split8(fs, h, lo);
        *(uint4*)(Sh + a * 128 + cs * 8) = h;
        *(uint4*)(Sl + a * 128 + cs * 8) = lo;
        if constexpr (DEG > 0) {
            split8(fn, h, lo);
            *(uint4*)(Nh + a * 128 + cs * 8) = h;
            *(uint4*)(Nl + a * 128 + cs * 8) = lo;
        }
    }
    __syncthreads();

    const int w = tid >> 6, l = tid & 63;
    const int lm = l & 15, lq = l >> 4;

    f32x4 acc[4][2];
    #pragma unroll
    for (int rt = 0; rt < 4; ++rt)
        #pragma unroll
        for (int ti = 0; ti < 2; ++ti)
            acc[rt][ti] = (f32x4){0.f, 0.f, 0.f, 0.f};

    for (int ks = 0; ks < 4; ++ks) {
        short8v ash[4], asl[4], anh[4], anl[4];
        #pragma unroll
        for (int rt = 0; rt < 4; ++rt) {
            int a = rt * 16 + lm;
            int cs = (ks * 4 + lq) ^ lm;
            ash[rt] = *(const short8v*)(Sh + a * 128 + cs * 8);
            asl[rt] = *(const short8v*)(Sl + a * 128 + cs * 8);
            if constexpr (DEG > 0) {
                anh[rt] = *(const short8v*)(Nh + a * 128 + cs * 8);
                anl[rt] = *(const short8v*)(Nl + a * 128 + cs * 8);
            }
        }
        #pragma unroll
        for (int ti = 0; ti < 2; ++ti) {
            int fid = ((w + ti * 4) * 4 + ks) * 64 + l;
            short8v bh = *(const short8v*)(Wsh + (size_t)fid * 8);
            short8v bl = *(const short8v*)(Wsl + (size_t)fid * 8);
            #pragma unroll
            for (int rt = 0; rt < 4; ++rt) {
                acc[rt][ti] = __builtin_amdgcn_mfma_f32_16x16x32_bf16(ash[rt], bh, acc[rt][ti], 0, 0, 0);
                acc[rt][ti] = __builtin_amdgcn_mfma_f32_16x16x32_bf16(asl[rt], bh, acc[rt][ti], 0, 0, 0);
                acc[rt][ti] = __builtin_amdgcn_mfma_f32_16x16x32_bf16(ash[rt], bl, acc[rt][ti], 0, 0, 0);
            }
            if constexpr (DEG > 0) {
                short8v rh = *(const short8v*)(Wrh + (size_t)fid * 8);
                short8v rl = *(const short8v*)(Wrl + (size_t)fid * 8);
                #pragma unroll
                for (int rt = 0; rt < 4; ++rt) {
                    acc[rt][ti] = __builtin_amdgcn_mfma_f32_16x16x32_bf16(anh[rt], rh, acc[rt][ti], 0, 0, 0);
                    acc[rt][ti] = __builtin_amdgcn_mfma_f32_16x16x32_bf16(anl[rt], rh, acc[rt][ti], 0, 0, 0);
                    acc[rt][ti] = __builtin_amdgcn_mfma_f32_16x16x32_bf16(anh[rt], rl, acc[rt][ti], 0, 0, 0);
                }
            }
        }
    }

    #pragma unroll
    for (int ti = 0; ti < 2; ++ti) {
        int cc = (w + ti * 4) * 16 + lm;
        float bz = bias[cc];
        float s = bg[cc] * rsqrtf(bv[cc] + BN_EPS);
        float sb = bbeta[cc] - bm[cc] * s;
        #pragma unroll
        for (int rt = 0; rt < 4; ++rt) {
            #pragma unroll
            for (int r = 0; r < 4; ++r) {
                int ga = tileBase + rt * 16 + lq * 4 + r;
                if (ga < count)
                    Out[(size_t)(start + ga) * 128 + cc] =
                        fast_tanh(acc[rt][ti][r] + bz) * s + sb;
            }
        }
    }
}

__global__ __launch_bounds__(256)
void k_gc2m_all(const float* __restrict__ X,
                const int* __restrict__ adj1, const int* __restrict__ adj2,
                const int* __restrict__ adj3, const int* __restrict__ adj4,
                const ushort_t* __restrict__ Fh, const ushort_t* __restrict__ Fl,
                const float* __restrict__ g2b,
                const float* __restrict__ bg, const float* __restrict__ bbeta,
                const float* __restrict__ bm, const float* __restrict__ bv,
                float* __restrict__ Out)
{
    __shared__ __align__(16) ushort_t Sh[64 * 128];
    __shared__ __align__(16) ushort_t Sl[64 * 128];
    __shared__ __align__(16) ushort_t Nh[64 * 128];
    __shared__ __align__(16) ushort_t Nl[64 * 128];
    const size_t MS = (size_t)2048 * 8;
    int b = blockIdx.x;
    if (b < 157)
        gc2m_body<0>(b, Sh, Sl, Nh, Nl, X, nullptr,
            Fh + 0 * MS, Fl + 0 * MS, nullptr, nullptr,
            g2b + 0 * 128, bg, bbeta, bm, bv, Out, 0, 10000);
    else if (b < 3907)
        gc2m_body<1>(b - 157, Sh, Sl, Nh, Nl, X, adj1,
            Fh + 1 * MS, Fl + 1 * MS, Fh + 5 * MS, Fl + 5 * MS,
            g2b + 1 * 128, bg, bbeta, bm, bv, Out, 10000, 240000);
    else if (b < 9532)
        gc2m_body<2>(b - 3907, Sh, Sl, Nh, Nl, X, adj2,
            Fh + 2 * MS, Fl + 2 * MS, Fh + 6 * MS, Fl + 6 * MS,
            g2b + 2 * 128, bg, bbeta, bm, bv, Out, 250000, 360000);
    else if (b < 13439)
        gc2m_body<3>(b - 9532, Sh, Sl, Nh, Nl, X, adj3,
            Fh + 3 * MS, Fl + 3 * MS, Fh + 7 * MS, Fl + 7 * MS,
            g2b + 3 * 128, bg, bbeta, bm, bv, Out, 610000, 250000);
    else
        gc2m_body<4>(b - 13439, Sh, Sl, Nh, Nl, X, adj4,
            Fh + 4 * MS, Fl + 4 * MS, Fh + 8 * MS, Fl + 8 * MS,
            g2b + 4 * 128, bg, bbeta, bm, bv, Out, 860000, 140000);
}

// ---------- pool1 body (f32 -> f32) ----------

template<int DEG>
__device__ __forceinline__ void pool_body(
    int blk, const float* __restrict__ X, const int* __restrict__ adj,
    float* __restrict__ Out, int start, int count)
{
    int t = blk * 256 + threadIdx.x;
    int a = t >> 5;
    if (a >= count) return;
    int c4 = t & 31;
    const float4* X4 = (const float4*)X;
    float4 v = X4[(size_t)(start + a) * 32 + c4];
    #pragma unroll
    for (int j = 0; j < DEG; ++j) {
        int nb = adj[(size_t)a * DEG + j];
        float4 q = X4[(size_t)nb * 32 + c4];
        v.x = fmaxf(v.x, q.x); v.y = fmaxf(v.y, q.y);
        v.z = fmaxf(v.z, q.z); v.w = fmaxf(v.w, q.w);
    }
    ((float4*)Out)[(size_t)(start + a) * 32 + c4] = v;
}

__global__ void k_pool_all(const float* __restrict__ X,
                           const int* __restrict__ adj1, const int* __restrict__ adj2,
                           const int* __restrict__ adj3, const int* __restrict__ adj4,
                           float* __restrict__ Out)
{
    int b = blockIdx.x;
    if (b < 1250)        pool_body<0>(b, X, nullptr, Out, 0, 10000);
    else if (b < 31250)  pool_body<1>(b - 1250, X, adj1, Out, 10000, 240000);
    else if (b < 76250)  pool_body<2>(b - 31250, X, adj2, Out, 250000, 360000);
    else if (b < 107500) pool_body<3>(b - 76250, X, adj3, Out, 610000, 250000);
    else                 pool_body<4>(b - 107500, X, adj4, Out, 860000, 140000);
}

// ---------- pool2 body (f32 -> split bf16 planes, sorted scatter) ----------

template<int DEG>
__device__ __forceinline__ void pool_split_body(
    int blk, const float* __restrict__ X, const int* __restrict__ adj,
    const int* __restrict__ invperm,
    ushort_t* __restrict__ PH, ushort_t* __restrict__ PL,
    int start, int count)
{
    int t = blk * 256 + threadIdx.x;
    int a = t >> 4;
    if (a >= count) return;
    int c8 = (t & 15) * 8;
    const float* row = X + (size_t)(start + a) * 128 + c8;
    float f[8];
    *(float4*)(&f[0]) = *(const float4*)row;
    *(float4*)(&f[4]) = *(const float4*)(row + 4);
    #pragma unroll
    for (int j = 0; j < DEG; ++j) {
        int nb = adj[(size_t)a * DEG + j];
        const float* nr = X + (size_t)nb * 128 + c8;
        float4 q0 = *(const float4*)nr;
        float4 q1 = *(const float4*)(nr + 4);
        f[0] = fmaxf(f[0], q0.x); f[1] = fmaxf(f[1], q0.y);
        f[2] = fmaxf(f[2], q0.z); f[3] = fmaxf(f[3], q0.w);
        f[4] = fmaxf(f[4], q1.x); f[5] = fmaxf(f[5], q1.y);
        f[6] = fmaxf(f[6], q1.z); f[7] = fmaxf(f[7], q1.w);
    }
    uint4 h, lo; split8(f, h, lo);
    int dst = invperm[start + a];
    *(uint4*)(PH + (size_t)dst * 128 + c8) = h;
    *(uint4*)(PL + (size_t)dst * 128 + c8) = lo;
}

__global__ void k_pool_split_all(const float* __restrict__ X,
                                 const int* __restrict__ adj1, const int* __restrict__ adj2,
                                 const int* __restrict__ adj3, const int* __restrict__ adj4,
                                 const int* __restrict__ invperm,
                                 ushort_t* __restrict__ PH, ushort_t* __restrict__ PL)
{
    int b = blockIdx.x;
    if (b < 625)        pool_split_body<0>(b, X, nullptr, invperm, PH, PL, 0, 10000);
    else if (b < 15625) pool_split_body<1>(b - 625, X, adj1, invperm, PH, PL, 10000, 240000);
    else if (b < 38125) pool_split_body<2>(b - 15625, X, adj2, invperm, PH, PL, 250000, 360000);
    else if (b < 53750) pool_split_body<3>(b - 38125, X, adj3, invperm, PH, PL, 610000, 250000);
    else                pool_split_body<4>(b - 53750, X, adj4, invperm, PH, PL, 860000, 140000);
}

// ---------- dense via MFMA split-bf16 (tanh + bn3) + subtile partials ----------

__global__ __launch_bounds__(256)
void k_dense_mfma(const ushort_t* __restrict__ PH,
                  const ushort_t* __restrict__ PL,
                  const int*   __restrict__ sortedMemb,
                  const int*   __restrict__ cumSeg,
                  const ushort_t* __restrict__ Bh,
                  const ushort_t* __restrict__ Bl,
                  const float* __restrict__ bias,
                  const float* __restrict__ bg, const float* __restrict__ bbeta,
                  const float* __restrict__ bm, const float* __restrict__ bv,
                  float* __restrict__ partials)
{
    __shared__ __align__(16) char smem[33792];
    __shared__ int sM[64];
    ushort_t* Ah = (ushort_t*)smem;
    ushort_t* Al = (ushort_t*)(smem + 16384);
    float*    Yt = (float*)smem;

    const int tid = threadIdx.x;
    const int tileBase = blockIdx.x * 64;
    if (tid < 64) sM[tid] = sortedMemb[tileBase + tid];

    for (int idx = tid; idx < 1024; idx += 256) {
        int a = idx >> 4, c = idx & 15;
        size_t off = (size_t)(tileBase + a) * 128 + c * 8;
        uint4 h  = *(const uint4*)(PH + off);
        uint4 lo = *(const uint4*)(PL + off);
        int cs = c ^ (a & 15);
        *(uint4*)(Ah + a * 128 + cs * 8) = h;
        *(uint4*)(Al + a * 128 + cs * 8) = lo;
    }
    __syncthreads();

    const int w = tid >> 6, l = tid & 63;
    const int lm = l & 15, lq = l >> 4;

    f32x4 acc[4][4];
    #pragma unroll
    for (int rt = 0; rt < 4; ++rt)
        #pragma unroll
        for (int ti = 0; ti < 4; ++ti)
            acc[rt][ti] = (f32x4){0.f, 0.f, 0.f, 0.f};

    for (int ks = 0; ks < 4; ++ks) {
        short8v ah[4], al[4];
        #pragma unroll
        for (int rt = 0; rt < 4; ++rt) {
            int a = rt * 16 + lm;
            int cs = (ks * 4 + lq) ^ lm;
            ah[rt] = *(const short8v*)(Ah + a * 128 + cs * 8);
            al[rt] = *(const short8v*)(Al + a * 128 + cs * 8);
        }
        #pragma unroll
        for (int ti = 0; ti < 4; ++ti) {
            int fid = ((w + ti * 4) * 4 + ks) * 64 + l;
            short8v bh = *(const short8v*)(Bh + (size_t)fid * 8);
            short8v bl = *(const short8v*)(Bl + (size_t)fid * 8);
            #pragma unroll
            for (int rt = 0; rt < 4; ++rt) {
                acc[rt][ti] = __builtin_amdgcn_mfma_f32_16x16x32_bf16(ah[rt], bh, acc[rt][ti], 0, 0, 0);
                acc[rt][ti] = __builtin_amdgcn_mfma_f32_16x16x32_bf16(al[rt], bh, acc[rt][ti], 0, 0, 0);
                acc[rt][ti] = __builtin_amdgcn_mfma_f32_16x16x32_bf16(ah[rt], bl, acc[rt][ti], 0, 0, 0);
            }
        }
    }

    float bvz[4], scv[4], shv[4];
    #pragma unroll
    for (int ti = 0; ti < 4; ++ti) {
        int c = (w + ti * 4) * 16 + lm;
        bvz[ti] = bias[c];
        float s = bg[c] * rsqrtf(bv[c] + BN_EPS);
        scv[ti] = s;
        shv[ti] = bbeta[c] - bm[c] * s;
    }

    const int q = tid >> 5, cg = tid & 31;
    const int sub = blockIdx.x * 8 + q;
    const size_t slotBase = (size_t)cumSeg[sub];
    const int fs = sM[q * 8];

    #pragma unroll
    for (int hf = 0; hf < 2; ++hf) {
        __syncthreads();
        #pragma unroll
        for (int tj = 0; tj < 2; ++tj) {
            int ti = 2 * hf + tj;
            int colh = (w + ti * 4) * 16 + lm - hf * 128;
            #pragma unroll
            for (int rt = 0; rt < 4; ++rt)
                #pragma unroll
                for (int r = 0; r < 4; ++r) {
                    int row = rt * 16 + lq * 4 + r;
                    float y = fast_tanh(acc[rt][ti][r] + bvz[ti]) * scv[ti] + shv[ti];
                    Yt[row * 132 + colh] = y;
                }
        }
        __syncthreads();

        float4 ys, ym;
        int cur = sM[q * 8];
        {
            float4 v = *(const float4*)(Yt + (q * 8) * 132 + cg * 4);
            ys = v; ym = v;
        }
        #pragma unroll
        for (int i = 1; i < 8; ++i) {
            float4 v = *(const float4*)(Yt + (q * 8 + i) * 132 + cg * 4);
            int m = sM[q * 8 + i];
            if (m == cur) {
                ys.x += v.x; ys.y += v.y; ys.z += v.z; ys.w += v.w;
                ym.x = fmaxf(ym.x, v.x); ym.y = fmaxf(ym.y, v.y);
                ym.z = fmaxf(ym.z, v.z); ym.w = fmaxf(ym.w, v.w);
            } else {
                float* p = partials + (slotBase + (cur - fs)) * 512 + hf * 128 + cg * 4;
                *(float4*)p         = ys;
                *(float4*)(p + 256) = ym;
                cur = m; ys = v; ym = v;
            }
        }
        float* p = partials + (slotBase + (cur - fs)) * 512 + hf * 128 + cg * 4;
        *(float4*)p         = ys;
        *(float4*)(p + 256) = ym;
    }
}

// ---------- combine partials -> final out (tanh fused) ----------

__global__ __launch_bounds__(256)
void k_combine(const float* __restrict__ partials,
               const int* __restrict__ binBase, const int* __restrict__ binCnt,
               const int* __restrict__ firstSeg, const int* __restrict__ cumSeg,
               float* __restrict__ Out)
{
    int sid = blockIdx.x * 4 + (threadIdx.x >> 6);
    if (sid >= 40000) return;
    int lane = threadIdx.x & 63;
    int b = binBase[sid], n = binCnt[sid];

    float4 s = make_float4(0.f, 0.f, 0.f, 0.f);
    float4 m = make_float4(-INFINITY, -INFINITY, -INFINITY, -INFINITY);
    if (n > 0) {
        int s0 = b >> 3, s1 = (b + n - 1) >> 3;
        for (int t = s0; t <= s1; ++t) {
            size_t slot = (size_t)cumSeg[t] + (sid - firstSeg[t]);
            const float4* P = (const float4*)(partials + slot * 512);
            float4 a = P[lane];
            float4 x = P[64 + lane];
            s.x += a.x; s.y += a.y; s.z += a.z; s.w += a.w;
            m.x = fmaxf(m.x, x.x); m.y = fmaxf(m.y, x.y);
            m.z = fmaxf(m.z, x.z); m.w = fmaxf(m.w, x.w);
        }
    }
    float4 os = make_float4(fast_tanh(s.x), fast_tanh(s.y), fast_tanh(s.z), fast_tanh(s.w));
    float4 om = make_float4(fast_tanh(m.x), fast_tanh(m.y), fast_tanh(m.z), fast_tanh(m.w));
    *(float4*)(Out + (size_t)sid * 512 + lane * 4)       = os;
    *(float4*)(Out + (size_t)sid * 512 + 256 + lane * 4) = om;
}

// ---------- launcher ----------

extern "C" void kernel_launch(void* const* d_in, const int* in_sizes, int n_in,
                              void* d_out, int out_size, void* d_ws, size_t ws_size,
                              hipStream_t stream)
{
    const float* atom = (const float*)d_in[0];
    const int*   memb = (const int*)d_in[1];
    const int*   adj1 = (const int*)d_in[2];
    const int*   adj2 = (const int*)d_in[3];
    const int*   adj3 = (const int*)d_in[4];
    const int*   adj4 = (const int*)d_in[5];
    const float* g1Ws = (const float*)d_in[6];
    const float* g1Wr = (const float*)d_in[7];
    const float* g1b  = (const float*)d_in[8];
    const float* g2Ws = (const float*)d_in[9];
    const float* g2Wr = (const float*)d_in[10];
    const float* g2b  = (const float*)d_in[11];
    const float* bn1g = (const float*)d_in[12];
    const float* bn1b = (const float*)d_in[13];
    const float* bn1m = (const float*)d_in[14];
    const float* bn1v = (const float*)d_in[15];
    const float* bn3g = (const float*)d_in[16];
    const float* bn3b = (const float*)d_in[17];
    const float* bn3m = (const float*)d_in[18];
    const float* bn3v = (const float*)d_in[19];
    const float* dW   = (const float*)d_in[20];
    const float* db   = (const float*)d_in[21];

    char* ws = (char*)d_ws;
    float* bufA = (float*)ws;                    // [1M][128] f32, 512 MB
    float* bufB = (float*)(ws + 512000000);      // [1M][128] f32, 512 MB
    char*  outc = (char*)d_out;                  // [40000][512] f32 = 81.92 MB
    float* out  = (float*)d_out;

    // gc1 pre-split atom planes live in bufB (dead before pool1 writes it):
    ushort_t* XH = (ushort_t*)bufB;              // [1M][96] bf16, 192 MB
    ushort_t* XL = XH + (size_t)1000000 * 96;    // 192 MB

    // pool2 split planes (sorted row order) also live in bufB (after gc2 reads pool1):
    ushort_t* PH = (ushort_t*)bufB;              // 256 MB
    ushort_t* PL = PH + (size_t)1000000 * 128;   // 256 MB

    // temp regions in d_out (all fully overwritten by k_combine at the end):
    ushort_t* gFh   = (ushort_t*)(outc);              // gc2 frags 294,912 B
    ushort_t* gFl   = (ushort_t*)(outc + 294912);
    ushort_t* g1Fh  = (ushort_t*)(outc + 589824);     // gc1 frags 221,184 B
    ushort_t* g1Fl  = (ushort_t*)(outc + 811008);
    ushort_t* dWh   = (ushort_t*)(outc + 1032192);    // dense frags 65,536 B
    ushort_t* dWl   = (ushort_t*)(outc + 1097728);
    int* invperm    = (int*)(outc + 1200000);         // 4,000,000 B
    int* sortedMemb = (int*)(outc + 5200000);         // 4,000,000 B
    int* binCnt     = (int*)(outc + 9200000);         // 160,000 B
    int* binBase    = (int*)(outc + 9360000);
    int* binFill    = (int*)(outc + 9520000);
    int* firstSeg   = (int*)(outc + 9680000);         // 500,000 B
    int* segCnt     = (int*)(outc + 10180000);
    int* cumSeg     = (int*)(outc + 10680000);        // ends ~11.2 MB << 82 MB

    // partials + combine-metadata copies live in bufA (dead after pool_split):
    float* partials = bufA;                           // <=165k slots x 2 KB = 338 MB
    int* cBinBase   = (int*)(ws + 400000000);
    int* cBinCnt    = (int*)(ws + 401000000);
    int* cFirstSeg  = (int*)(ws + 402000000);
    int* cCumSeg    = (int*)(ws + 403000000);

    // ---- W fragment prep + atom pre-split + counting sort (input-only deps) ----
    k_prepW2<<<72, 256, 0, stream>>>(g2Ws, g2Wr, gFh, gFl);
    k_prepW1<<<54, 256, 0, stream>>>(g1Ws, g1Wr, g1Fh, g1Fl);
    k_prepW<<<16, 256, 0, stream>>>(dW, dWh, dWl);
    k_prepX<<<46875, 256, 0, stream>>>(atom, XH, XL);
    k_zero_bins<<<(40000 + 255) / 256, 256, 0, stream>>>(binCnt, binFill);
    k_hist<<<(1000000 + 255) / 256, 256, 0, stream>>>(memb, binCnt);
    k_scan<<<1, 1024, 0, stream>>>(binCnt, binBase);
    k_scatter<<<(1000000 + 255) / 256, 256, 0, stream>>>(memb, binBase, binFill,
        invperm, sortedMemb);
    k_meta<<<(125000 + 255) / 256, 256, 0, stream>>>(sortedMemb, firstSeg, segCnt);
    k_scan2<<<1, 1024, 0, stream>>>(segCnt, cumSeg);

    // ---- gc1 (MFMA, merged, vectorized gather): XH/XL -> bufA ----
    k_gc1m_all<<<15627, 256, 0, stream>>>(XH, XL, adj1, adj2, adj3, adj4,
        g1Fh, g1Fl, g1b, bn1g, bn1b, bn1m, bn1v, bufA);

    // ---- pool1 (merged): bufA -> bufB (f32; overwrites XH/XL) ----
    k_pool_all<<<125000, 256, 0, stream>>>(bufA, adj1, adj2, adj3, adj4, bufB);

    // ---- gc2 (MFMA, merged): bufB -> bufA ----
    k_gc2m_all<<<15627, 256, 0, stream>>>(bufB, adj1, adj2, adj3, adj4,
        gFh, gFl, g2b, bn1g, bn1b, bn1m, bn1v, bufA);

    // ---- pool2 (merged): bufA -> PH/PL at sorted positions ----
    k_pool_split_all<<<62500, 256, 0, stream>>>(bufA, adj1, adj2, adj3, adj4,
        invperm, PH, PL);

    // ---- copy combine-metadata out of d_out into bufA tail (bufA now dead) ----
    k_copymeta<<<(125000 + 255) / 256, 256, 0, stream>>>(binBase, binCnt,
        firstSeg, cumSeg, cBinBase, cBinCnt, cFirstSeg, cCumSeg);

    // ---- dense (MFMA, sequential staging) -> partials in bufA ----
    k_dense_mfma<<<15625, 256, 0, stream>>>(PH, PL, sortedMemb, cumSeg, dWh, dWl,
        db, bn3g, bn3b, bn3m, bn3v, partials);

    // ---- combine partials -> out (reads metadata from bufA copies) ----
    k_combine<<<10000, 256, 0, stream>>>(partials, cBinBase, cBinCnt,
        cFirstSeg, cCumSeg, out);
}

// Round 16
// 2568.671 us; speedup vs baseline: 1.2592x; 1.0339x over previous
//
#include <hip/hip_runtime.h>
#include <hip/hip_bf16.h>
#include <cstdint>
#include <cstddef>

#define BN_EPS 1e-3f
typedef unsigned short ushort_t;
typedef unsigned int uint_t;
typedef __attribute__((ext_vector_type(8))) short short8v;   // 8 bf16 (4 VGPRs)
typedef __attribute__((ext_vector_type(4))) float f32x4;     // MFMA C/D

// ---------- numeric helpers ----------

__device__ __forceinline__ float fast_tanh(float x) {
    float xc = fminf(fmaxf(x, -12.0f), 12.0f);
    float e = __expf(2.0f * xc);
    return (e - 1.0f) * __builtin_amdgcn_rcpf(e + 1.0f);
}

__device__ __forceinline__ float bf2f(uint_t u) {
    return __uint_as_float(u << 16);
}
__device__ __forceinline__ ushort_t f2bf(float f) {
    union { __hip_bfloat16 h; ushort_t u; } cv;
    cv.h = __float2bfloat16(f);   // RNE
    return cv.u;
}

__device__ __forceinline__ void split8(const float* f, uint4& h, uint4& lo) {
    uint_t hh[8], ll[8];
    #pragma unroll
    for (int j = 0; j < 8; ++j) {
        float x = f[j];
        ushort_t xh = f2bf(x);
        float xr = x - bf2f(xh);
        hh[j] = xh;
        ll[j] = f2bf(xr);
    }
    h  = make_uint4(hh[0] | (hh[1] << 16), hh[2] | (hh[3] << 16),
                    hh[4] | (hh[5] << 16), hh[6] | (hh[7] << 16));
    lo = make_uint4(ll[0] | (ll[1] << 16), ll[2] | (ll[3] << 16),
                    ll[4] | (ll[5] << 16), ll[6] | (ll[7] << 16));
}

// accumulate 8 packed bf16 (one uint4) into f[8]
__device__ __forceinline__ void add8(float* f, uint4 v) {
    f[0] += bf2f(v.x & 0xffffu); f[1] += bf2f(v.x >> 16);
    f[2] += bf2f(v.y & 0xffffu); f[3] += bf2f(v.y >> 16);
    f[4] += bf2f(v.z & 0xffffu); f[5] += bf2f(v.z >> 16);
    f[6] += bf2f(v.w & 0xffffu); f[7] += bf2f(v.w >> 16);
}

// ---------- atom features -> pre-split padded bf16 planes [1M][96] ----------

__global__ void k_prepX(const float* __restrict__ atom,
                        ushort_t* __restrict__ XH, ushort_t* __restrict__ XL) {
    int idx = blockIdx.x * 256 + threadIdx.x;   // [0, 12M)
    if (idx >= 12000000) return;
    int row = idx / 12;
    int c = idx - row * 12;
    int k0 = c * 8;
    const float* r = atom + (size_t)row * 75;
    float f[8];
    #pragma unroll
    for (int j = 0; j < 8; ++j)
        f[j] = (k0 + j < 75) ? r[k0 + j] : 0.0f;
    uint4 h, lo; split8(f, h, lo);
    *(uint4*)(XH + (size_t)row * 96 + k0) = h;
    *(uint4*)(XL + (size_t)row * 96 + k0) = lo;
}

// ---------- counting sort of atoms by membership (ascending) ----------

__global__ void k_zero_bins(int* __restrict__ binCnt, int* __restrict__ binFill) {
    int t = blockIdx.x * 256 + threadIdx.x;
    if (t < 40000) { binCnt[t] = 0; binFill[t] = 0; }
}

__global__ void k_hist(const int* __restrict__ memb, int* __restrict__ binCnt) {
    int t = blockIdx.x * 256 + threadIdx.x;
    if (t < 1000000) atomicAdd(&binCnt[memb[t]], 1);
}

__global__ __launch_bounds__(1024)
void k_scan(const int* __restrict__ binCnt, int* __restrict__ binBase) {
    __shared__ int part[1024];
    const int t = threadIdx.x;
    const int base = t * 40;
    int local[40];
    int s = 0;
    #pragma unroll
    for (int j = 0; j < 40; ++j) {
        int idx = base + j;
        int c = (idx < 40000) ? binCnt[idx] : 0;
        local[j] = s;
        s += c;
    }
    part[t] = s;
    __syncthreads();
    for (int off = 1; off < 1024; off <<= 1) {
        int v = (t >= off) ? part[t - off] : 0;
        __syncthreads();
        part[t] += v;
        __syncthreads();
    }
    int add = (t > 0) ? part[t - 1] : 0;
    #pragma unroll
    for (int j = 0; j < 40; ++j) {
        int idx = base + j;
        if (idx < 40000) binBase[idx] = add + local[j];
    }
}

__global__ void k_scatter(const int* __restrict__ memb, const int* __restrict__ binBase,
                          int* __restrict__ binFill,
                          int* __restrict__ invperm, int* __restrict__ sortedMemb) {
    int t = blockIdx.x * 256 + threadIdx.x;
    if (t < 1000000) {
        int m = memb[t];
        int pos = binBase[m] + atomicAdd(&binFill[m], 1);
        invperm[t] = pos;
        sortedMemb[pos] = m;
    }
}

// ---------- subtile metadata ----------

__global__ void k_meta(const int* __restrict__ sortedMemb,
                       int* __restrict__ firstSeg, int* __restrict__ segCnt) {
    int t = blockIdx.x * 256 + threadIdx.x;
    if (t < 125000) {
        int f = sortedMemb[8 * t];
        int l = sortedMemb[8 * t + 7];
        firstSeg[t] = f;
        segCnt[t] = l - f + 1;
    }
}

__global__ __launch_bounds__(1024)
void k_scan2(const int* __restrict__ segCnt, int* __restrict__ cumSeg) {
    __shared__ int part[1024];
    const int t = threadIdx.x;
    const int base = t * 123;
    int s = 0;
    for (int j = 0; j < 123; ++j) {
        int idx = base + j;
        if (idx < 125000) s += segCnt[idx];
    }
    part[t] = s;
    __syncthreads();
    for (int off = 1; off < 1024; off <<= 1) {
        int v = (t >= off) ? part[t - off] : 0;
        __syncthreads();
        part[t] += v;
        __syncthreads();
    }
    int run = (t > 0) ? part[t - 1] : 0;
    for (int j = 0; j < 123; ++j) {
        int idx = base + j;
        if (idx < 125000) { cumSeg[idx] = run; run += segCnt[idx]; }
    }
}

__global__ void k_copymeta(const int* __restrict__ binBase, const int* __restrict__ binCnt,
                           const int* __restrict__ firstSeg, const int* __restrict__ cumSeg,
                           int* __restrict__ dBinBase, int* __restrict__ dBinCnt,
                           int* __restrict__ dFirstSeg, int* __restrict__ dCumSeg) {
    int t = blockIdx.x * 256 + threadIdx.x;
    if (t < 40000) { dBinBase[t] = binBase[t]; dBinCnt[t] = binCnt[t]; }
    if (t < 125000) { dFirstSeg[t] = firstSeg[t]; dCumSeg[t] = cumSeg[t]; }
}

// ---------- W fragment prep ----------

__global__ void k_prepW(const float* __restrict__ W,
                        ushort_t* __restrict__ Bh, ushort_t* __restrict__ Bl) {
    int idx = blockIdx.x * 256 + threadIdx.x;
    if (idx >= 4096) return;
    int l = idx & 63, g = idx >> 6;
    int tn = g >> 2, ks = g & 3;
    int n = tn * 16 + (l & 15);
    int k0 = ks * 32 + (l >> 4) * 8;
    float f[8];
    #pragma unroll
    for (int j = 0; j < 8; ++j) f[j] = W[(size_t)(k0 + j) * 256 + n];
    uint4 h, lo; split8(f, h, lo);
    *(uint4*)(Bh + (size_t)idx * 8) = h;
    *(uint4*)(Bl + (size_t)idx * 8) = lo;
}

__global__ void k_prepW2(const float* __restrict__ Ws5, const float* __restrict__ Wr4,
                         ushort_t* __restrict__ Fh, ushort_t* __restrict__ Fl) {
    int idx = blockIdx.x * 256 + threadIdx.x;
    if (idx >= 18432) return;
    int mat = idx >> 11;
    int fid = idx & 2047;
    int l = fid & 63, g = fid >> 6;
    int tn = g >> 2, ks = g & 3;
    int n = tn * 16 + (l & 15);
    int k0 = ks * 32 + (l >> 4) * 8;
    const float* W = (mat < 5) ? (Ws5 + (size_t)mat * 16384)
                               : (Wr4 + (size_t)(mat - 5) * 16384);
    float f[8];
    #pragma unroll
    for (int j = 0; j < 8; ++j) f[j] = W[(size_t)(k0 + j) * 128 + n];
    uint4 h, lo; split8(f, h, lo);
    *(uint4*)(Fh + (size_t)idx * 8) = h;
    *(uint4*)(Fl + (size_t)idx * 8) = lo;
}

__global__ void k_prepW1(const float* __restrict__ Ws5, const float* __restrict__ Wr4,
                         ushort_t* __restrict__ Fh, ushort_t* __restrict__ Fl) {
    int idx = blockIdx.x * 256 + threadIdx.x;
    if (idx >= 13824) return;
    int mat = idx / 1536;
    int fid = idx - mat * 1536;
    int l = fid & 63, g = fid >> 6;
    int tn = g / 3, ks = g - tn * 3;
    int n = tn * 16 + (l & 15);
    int k0 = ks * 32 + (l >> 4) * 8;
    const float* W = (mat < 5) ? (Ws5 + (size_t)mat * 9600)
                               : (Wr4 + (size_t)(mat - 5) * 9600);
    float f[8];
    #pragma unroll
    for (int j = 0; j < 8; ++j)
        f[j] = (k0 + j < 75) ? W[(size_t)(k0 + j) * 128 + n] : 0.0f;
    uint4 h, lo; split8(f, h, lo);
    *(uint4*)(Fh + (size_t)idx * 8) = h;
    *(uint4*)(Fl + (size_t)idx * 8) = lo;
}

// ---------- gc1 body: 32-atom tile (MFMA split-bf16, K=96; pre-split planes) ----------

template<int DEG>
__device__ __forceinline__ void gc1m_body(
    int blk, ushort_t* Sh, ushort_t* Sl, ushort_t* Nh, ushort_t* Nl,
    const ushort_t* __restrict__ XH, const ushort_t* __restrict__ XL,
    const int* __restrict__ adj,
    const ushort_t* __restrict__ Wsh, const ushort_t* __restrict__ Wsl,
    const ushort_t* __restrict__ Wrh, const ushort_t* __restrict__ Wrl,
    const float* __restrict__ bias,
    const float* __restrict__ bg, const float* __restrict__ bbeta,
    const float* __restrict__ bm, const float* __restrict__ bv,
    float* __restrict__ Out, int start, int count)
{
    const int tid = threadIdx.x;
    const int tileBase = blk * 32;

    for (int idx = tid; idx < 32 * 12; idx += 256) {
        int a = idx / 12;
        int c = idx - a * 12;
        int ga = tileBase + a;
        uint4 sh = make_uint4(0u, 0u, 0u, 0u);
        uint4 sl = make_uint4(0u, 0u, 0u, 0u);
        float fn[8] = {0, 0, 0, 0, 0, 0, 0, 0};
        if (ga < count) {
            size_t off = (size_t)(start + ga) * 96 + c * 8;
            sh = *(const uint4*)(XH + off);
            sl = *(const uint4*)(XL + off);
            if constexpr (DEG > 0) {
                #pragma unroll
                for (int jj = 0; jj < DEG; ++jj) {
                    int nb = adj[(size_t)ga * DEG + jj];
                    size_t noff = (size_t)nb * 96 + c * 8;
                    add8(fn, *(const uint4*)(XH + noff));
                    add8(fn, *(const uint4*)(XL + noff));
                }
            }
        }
        int cs = c ^ (a & 15);
        *(uint4*)(Sh + a * 128 + cs * 8) = sh;
        *(uint4*)(Sl + a * 128 + cs * 8) = sl;
        if constexpr (DEG > 0) {
            uint4 h, lo;
            split8(fn, h, lo);
            *(uint4*)(Nh + a * 128 + cs * 8) = h;
            *(uint4*)(Nl + a * 128 + cs * 8) = lo;
        }
    }
    __syncthreads();

    const int w = tid >> 6, l = tid & 63;
    const int lm = l & 15, lq = l >> 4;

    f32x4 acc[2][2];
    #pragma unroll
    for (int rt = 0; rt < 2; ++rt)
        #pragma unroll
        for (int ti = 0; ti < 2; ++ti)
            acc[rt][ti] = (f32x4){0.f, 0.f, 0.f, 0.f};

    for (int ks = 0; ks < 3; ++ks) {
        short8v ash[2], asl[2], anh[2], anl[2];
        #pragma unroll
        for (int rt = 0; rt < 2; ++rt) {
            int a = rt * 16 + lm;
            int cs = (ks * 4 + lq) ^ lm;
            ash[rt] = *(const short8v*)(Sh + a * 128 + cs * 8);
            asl[rt] = *(const short8v*)(Sl + a * 128 + cs * 8);
            if constexpr (DEG > 0) {
                anh[rt] = *(const short8v*)(Nh + a * 128 + cs * 8);
                anl[rt] = *(const short8v*)(Nl + a * 128 + cs * 8);
            }
        }
        #pragma unroll
        for (int ti = 0; ti < 2; ++ti) {
            int fid = ((w + ti * 4) * 3 + ks) * 64 + l;
            short8v bh = *(const short8v*)(Wsh + (size_t)fid * 8);
            short8v bl = *(const short8v*)(Wsl + (size_t)fid * 8);
            #pragma unroll
            for (int rt = 0; rt < 2; ++rt) {
                acc[rt][ti] = __builtin_amdgcn_mfma_f32_16x16x32_bf16(ash[rt], bh, acc[rt][ti], 0, 0, 0);
                acc[rt][ti] = __builtin_amdgcn_mfma_f32_16x16x32_bf16(asl[rt], bh, acc[rt][ti], 0, 0, 0);
                acc[rt][ti] = __builtin_amdgcn_mfma_f32_16x16x32_bf16(ash[rt], bl, acc[rt][ti], 0, 0, 0);
            }
            if constexpr (DEG > 0) {
                short8v rh = *(const short8v*)(Wrh + (size_t)fid * 8);
                short8v rl = *(const short8v*)(Wrl + (size_t)fid * 8);
                #pragma unroll
                for (int rt = 0; rt < 2; ++rt) {
                    acc[rt][ti] = __builtin_amdgcn_mfma_f32_16x16x32_bf16(anh[rt], rh, acc[rt][ti], 0, 0, 0);
                    acc[rt][ti] = __builtin_amdgcn_mfma_f32_16x16x32_bf16(anl[rt], rh, acc[rt][ti], 0, 0, 0);
                    acc[rt][ti] = __builtin_amdgcn_mfma_f32_16x16x32_bf16(anh[rt], rl, acc[rt][ti], 0, 0, 0);
                }
            }
        }
    }

    #pragma unroll
    for (int ti = 0; ti < 2; ++ti) {
        int cc = (w + ti * 4) * 16 + lm;
        float bz = bias[cc];
        float s = bg[cc] * rsqrtf(bv[cc] + BN_EPS);
        float sb = bbeta[cc] - bm[cc] * s;
        #pragma unroll
        for (int rt = 0; rt < 2; ++rt) {
            #pragma unroll
            for (int r = 0; r < 4; ++r) {
                int ga = tileBase + rt * 16 + lq * 4 + r;
                if (ga < count)
                    Out[(size_t)(start + ga) * 128 + cc] =
                        fast_tanh(acc[rt][ti][r] + bz) * s + sb;
            }
        }
    }
}

// merged gc1 (32-atom tiles): [0,313) d0 | [313,7813) d1 | [7813,19063) d2 | [19063,26876) d3 | [26876,31251) d4
__global__ __launch_bounds__(256)
void k_gc1m_all(const ushort_t* __restrict__ XH, const ushort_t* __restrict__ XL,
                const int* __restrict__ adj1, const int* __restrict__ adj2,
                const int* __restrict__ adj3, const int* __restrict__ adj4,
                const ushort_t* __restrict__ Fh, const ushort_t* __restrict__ Fl,
                const float* __restrict__ g1b,
                const float* __restrict__ bg, const float* __restrict__ bbeta,
                const float* __restrict__ bm, const float* __restrict__ bv,
                float* __restrict__ Out)
{
    __shared__ __align__(16) ushort_t Sh[32 * 128];
    __shared__ __align__(16) ushort_t Sl[32 * 128];
    __shared__ __align__(16) ushort_t Nh[32 * 128];
    __shared__ __align__(16) ushort_t Nl[32 * 128];
    const size_t MS = (size_t)1536 * 8;
    int b = blockIdx.x;
    if (b < 313)
        gc1m_body<0>(b, Sh, Sl, Nh, Nl, XH, XL, nullptr,
            Fh + 0 * MS, Fl + 0 * MS, nullptr, nullptr,
            g1b + 0 * 128, bg, bbeta, bm, bv, Out, 0, 10000);
    else if (b < 7813)
        gc1m_body<1>(b - 313, Sh, Sl, Nh, Nl, XH, XL, adj1,
            Fh + 1 * MS, Fl + 1 * MS, Fh + 5 * MS, Fl + 5 * MS,
            g1b + 1 * 128, bg, bbeta, bm, bv, Out, 10000, 240000);
    else if (b < 19063)
        gc1m_body<2>(b - 7813, Sh, Sl, Nh, Nl, XH, XL, adj2,
            Fh + 2 * MS, Fl + 2 * MS, Fh + 6 * MS, Fl + 6 * MS,
            g1b + 2 * 128, bg, bbeta, bm, bv, Out, 250000, 360000);
    else if (b < 26876)
        gc1m_body<3>(b - 19063, Sh, Sl, Nh, Nl, XH, XL, adj3,
            Fh + 3 * MS, Fl + 3 * MS, Fh + 7 * MS, Fl + 7 * MS,
            g1b + 3 * 128, bg, bbeta, bm, bv, Out, 610000, 250000);
    else
        gc1m_body<4>(b - 26876, Sh, Sl, Nh, Nl, XH, XL, adj4,
            Fh + 4 * MS, Fl + 4 * MS, Fh + 8 * MS, Fl + 8 * MS,
            g1b + 4 * 128, bg, bbeta, bm, bv, Out, 860000, 140000);
}

// ---------- gc2 body: 32-atom tile (MFMA split-bf16, K=128) ----------

template<int DEG>
__device__ __forceinline__ void gc2m_body(
    int blk, ushort_t* Sh, ushort_t* Sl, ushort_t* Nh, ushort_t* Nl,
    const float* __restrict__ X, const int* __restrict__ adj,
    const ushort_t* __restrict__ Wsh, const ushort_t* __restrict__ Wsl,
    const ushort_t* __restrict__ Wrh, const ushort_t* __restrict__ Wrl,
    const float* __restrict__ bias,
    const float* __restrict__ bg, const float* __restrict__ bbeta,
    const float* __restrict__ bm, const float* __restrict__ bv,
    float* __restrict__ Out, int start, int count)
{
    const int tid = threadIdx.x;
    const int tileBase = blk * 32;

    for (int idx = tid; idx < 512; idx += 256) {
        int a = idx >> 4, c = idx & 15;
        int ga = tileBase + a;
        float fs[8] = {0, 0, 0, 0, 0, 0, 0, 0};
        float fn[8] = {0, 0, 0, 0, 0, 0, 0, 0};
        if (ga < count) {
            const float* row = X + (size_t)(start + ga) * 128 + c * 8;
            *(float4*)(&fs[0]) = *(const float4*)row;
            *(float4*)(&fs[4]) = *(const float4*)(row + 4);
            if constexpr (DEG > 0) {
                #pragma unroll
                for (int j = 0; j < DEG; ++j) {
                    int nb = adj[(size_t)ga * DEG + j];
                    const float* nr = X + (size_t)nb * 128 + c * 8;
                    float4 q0 = *(const float4*)nr;
                    float4 q1 = *(const float4*)(nr + 4);
                    fn[0] += q0.x; fn[1] += q0.y; fn[2] += q0.z; fn[3] += q0.w;
                    fn[4] += q1.x; fn[5] += q1.y; fn[6] += q1.z; fn[7] += q1.w;
                }
            }
        }
        int cs = c ^ (a & 15);
        uint4 h, lo;
        split8(fs, h, lo);
        *(uint4*)(Sh + a * 128 + cs * 8) = h;
        *(uint4*)(Sl + a * 128 + cs * 8) = lo;
        if constexpr (DEG > 0) {
            split8(fn, h, lo);
            *(uint4*)(Nh + a * 128 + cs * 8) = h;
            *(uint4*)(Nl + a * 128 + cs * 8) = lo;
        }
    }
    __syncthreads();

    const int w = tid >> 6, l = tid & 63;
    const int lm = l & 15, lq = l >> 4;

    f32x4 acc[2][2];
    #pragma unroll
    for (int rt = 0; rt < 2; ++rt)
        #pragma unroll
        for (int ti = 0; ti < 2; ++ti)
            acc[rt][ti] = (f32x4){0.f, 0.f, 0.f, 0.f};

    for (int ks = 0; ks < 4; ++ks) {
        short8v ash[2], asl[2], anh[2], anl[2];
        #pragma unroll
        for (int rt = 0; rt < 2; ++rt) {
            int a = rt * 16 + lm;
            int cs = (ks * 4 + lq) ^ lm;
            ash[rt] = *(const short8v*)(Sh + a * 128 + cs * 8);
            asl[rt] = *(const short8v*)(Sl + a * 128 + cs * 8);
            if constexpr (DEG > 0) {
                anh[rt] = *(const short8v*)(Nh + a * 128 + cs * 8);
                anl[rt] = *(const short8v*)(Nl + a * 128 + cs * 8);
            }
        }
        #pragma unroll
        for (int ti = 0; ti < 2; ++ti) {
            int fid = ((w + ti * 4) * 4 + ks) * 64 + l;
            short8v bh = *(const short8v*)(Wsh + (size_t)fid * 8);
            short8v bl = *(const short8v*)(Wsl + (size_t)fid * 8);
            #pragma unroll
            for (int rt = 0; rt < 2; ++rt) {
                acc[rt][ti] = __builtin_amdgcn_mfma_f32_16x16x32_bf16(ash[rt], bh, acc[rt][ti], 0, 0, 0);
                acc[rt][ti] = __builtin_amdgcn_mfma_f32_16x16x32_bf16(asl[rt], bh, acc[rt][ti], 0, 0, 0);
                acc[rt][ti] = __builtin_amdgcn_mfma_f32_16x16x32_bf16(ash[rt], bl, acc[rt][ti], 0, 0, 0);
            }
            if constexpr (DEG > 0) {
                short8v rh = *(const short8v*)(Wrh + (size_t)fid * 8);
                short8v rl = *(const short8v*)(Wrl + (size_t)fid * 8);
                #pragma unroll
                for (int rt = 0; rt < 2; ++rt) {
                    acc[rt][ti] = __builtin_amdgcn_mfma_f32_16x16x32_bf16(anh[rt], rh, acc[rt][ti], 0, 0, 0);
                    acc[rt][ti] = __builtin_amdgcn_mfma_f32_16x16x32_bf16(anl[rt], rh, acc[rt][ti], 0, 0, 0);
                    acc[rt][ti] = __builtin_amdgcn_mfma_f32_16x16x32_bf16(anh[rt], rl, acc[rt][ti], 0, 0, 0);
                }
            }
        }
    }

    #pragma unroll
    for (int ti = 0; ti < 2; ++ti) {
        int cc = (w + ti * 4) * 16 + lm;
        float bz = bias[cc];
        float s = bg[cc] * rsqrtf(bv[cc] + BN_EPS);
        float sb = bbeta[cc] - bm[cc] * s;
        #pragma unroll
        for (int rt = 0; rt < 2; ++rt) {
            #pragma unroll
            for (int r = 0; r < 4; ++r) {
                int ga = tileBase + rt * 16 + lq * 4 + r;
                if (ga < count)
                    Out[(size_t)(start + ga) * 128 + cc] =
                        fast_tanh(acc[rt][ti][r] + bz) * s + sb;
            }
        }
    }
}

// merged gc2 (32-atom tiles): same boundaries as gc1
__global__ __launch_bounds__(256)
void k_gc2m_all(const float* __restrict__ X,
                const int* __restrict__ adj1, const int* __restrict__ adj2,
                const int* __restrict__ adj3, const int* __restrict__ adj4,
                const ushort_t* __restrict__ Fh, const ushort_t* __restrict__ Fl,
                const float* __restrict__ g2b,
                const float* __restrict__ bg, const float* __restrict__ bbeta,
                const float* __restrict__ bm, const float* __restrict__ bv,
                float* __restrict__ Out)
{
    __shared__ __align__(16) ushort_t Sh[32 * 128];
    __shared__ __align__(16) ushort_t Sl[32 * 128];
    __shared__ __align__(16) ushort_t Nh[32 * 128];
    __shared__ __align__(16) ushort_t Nl[32 * 128];
    const size_t MS = (size_t)2048 * 8;
    int b = blockIdx.x;
    if (b < 313)
        gc2m_body<0>(b, Sh, Sl, Nh, Nl, X, nullptr,
            Fh + 0 * MS, Fl + 0 * MS, nullptr, nullptr,
            g2b + 0 * 128, bg, bbeta, bm, bv, Out, 0, 10000);
    else if (b < 7813)
        gc2m_body<1>(b - 313, Sh, Sl, Nh, Nl, X, adj1,
            Fh + 1 * MS, Fl + 1 * MS, Fh + 5 * MS, Fl + 5 * MS,
            g2b + 1 * 128, bg, bbeta, bm, bv, Out, 10000, 240000);
    else if (b < 19063)
        gc2m_body<2>(b - 7813, Sh, Sl, Nh, Nl, X, adj2,
            Fh + 2 * MS, Fl + 2 * MS, Fh + 6 * MS, Fl + 6 * MS,
            g2b + 2 * 128, bg, bbeta, bm, bv, Out, 250000, 360000);
    else if (b < 26876)
        gc2m_body<3>(b - 19063, Sh, Sl, Nh, Nl, X, adj3,
            Fh + 3 * MS, Fl + 3 * MS, Fh + 7 * MS, Fl + 7 * MS,
            g2b + 3 * 128, bg, bbeta, bm, bv, Out, 610000, 250000);
    else
        gc2m_body<4>(b - 26876, Sh, Sl, Nh, Nl, X, adj4,
            Fh + 4 * MS, Fl + 4 * MS, Fh + 8 * MS, Fl + 8 * MS,
            g2b + 4 * 128, bg, bbeta, bm, bv, Out, 860000, 140000);
}

// ---------- pool1 body (f32 -> f32) ----------

template<int DEG>
__device__ __forceinline__ void pool_body(
    int blk, const float* __restrict__ X, const int* __restrict__ adj,
    float* __restrict__ Out, int start, int count)
{
    int t = blk * 256 + threadIdx.x;
    int a = t >> 5;
    if (a >= count) return;
    int c4 = t & 31;
    const float4* X4 = (const float4*)X;
    float4 v = X4[(size_t)(start + a) * 32 + c4];
    #pragma unroll
    for (int j = 0; j < DEG; ++j) {
        int nb = adj[(size_t)a * DEG + j];
        float4 q = X4[(size_t)nb * 32 + c4];
        v.x = fmaxf(v.x, q.x); v.y = fmaxf(v.y, q.y);
        v.z = fmaxf(v.z, q.z); v.w = fmaxf(v.w, q.w);
    }
    ((float4*)Out)[(size_t)(start + a) * 32 + c4] = v;
}

__global__ void k_pool_all(const float* __restrict__ X,
                           const int* __restrict__ adj1, const int* __restrict__ adj2,
                           const int* __restrict__ adj3, const int* __restrict__ adj4,
                           float* __restrict__ Out)
{
    int b = blockIdx.x;
    if (b < 1250)        pool_body<0>(b, X, nullptr, Out, 0, 10000);
    else if (b < 31250)  pool_body<1>(b - 1250, X, adj1, Out, 10000, 240000);
    else if (b < 76250)  pool_body<2>(b - 31250, X, adj2, Out, 250000, 360000);
    else if (b < 107500) pool_body<3>(b - 76250, X, adj3, Out, 610000, 250000);
    else                 pool_body<4>(b - 107500, X, adj4, Out, 860000, 140000);
}

// ---------- pool2 body (f32 -> split bf16 planes, sorted scatter) ----------

template<int DEG>
__device__ __forceinline__ void pool_split_body(
    int blk, const float* __restrict__ X, const int* __restrict__ adj,
    const int* __restrict__ invperm,
    ushort_t* __restrict__ PH, ushort_t* __restrict__ PL,
    int start, int count)
{
    int t = blk * 256 + threadIdx.x;
    int a = t >> 4;
    if (a >= count) return;
    int c8 = (t & 15) * 8;
    const float* row = X + (size_t)(start + a) * 128 + c8;
    float f[8];
    *(float4*)(&f[0]) = *(const float4*)row;
    *(float4*)(&f[4]) = *(const float4*)(row + 4);
    #pragma unroll
    for (int j = 0; j < DEG; ++j) {
        int nb = adj[(size_t)a * DEG + j];
        const float* nr = X + (size_t)nb * 128 + c8;
        float4 q0 = *(const float4*)nr;
        float4 q1 = *(const float4*)(nr + 4);
        f[0] = fmaxf(f[0], q0.x); f[1] = fmaxf(f[1], q0.y);
        f[2] = fmaxf(f[2], q0.z); f[3] = fmaxf(f[3], q0.w);
        f[4] = fmaxf(f[4], q1.x); f[5] = fmaxf(f[5], q1.y);
        f[6] = fmaxf(f[6], q1.z); f[7] = fmaxf(f[7], q1.w);
    }
    uint4 h, lo; split8(f, h, lo);
    int dst = invperm[start + a];
    *(uint4*)(PH + (size_t)dst * 128 + c8) = h;
    *(uint4*)(PL + (size_t)dst * 128 + c8) = lo;
}

__global__ void k_pool_split_all(const float* __restrict__ X,
                                 const int* __restrict__ adj1, const int* __restrict__ adj2,
                                 const int* __restrict__ adj3, const int* __restrict__ adj4,
                                 const int* __restrict__ invperm,
                                 ushort_t* __restrict__ PH, ushort_t* __restrict__ PL)
{
    int b = blockIdx.x;
    if (b < 625)        pool_split_body<0>(b, X, nullptr, invperm, PH, PL, 0, 10000);
    else if (b < 15625) pool_split_body<1>(b - 625, X, adj1, invperm, PH, PL, 10000, 240000);
    else if (b < 38125) pool_split_body<2>(b - 15625, X, adj2, invperm, PH, PL, 250000, 360000);
    else if (b < 53750) pool_split_body<3>(b - 38125, X, adj3, invperm, PH, PL, 610000, 250000);
    else                pool_split_body<4>(b - 53750, X, adj4, invperm, PH, PL, 860000, 140000);
}

// ---------- dense via MFMA split-bf16 (tanh + bn3) + subtile partials ----------

__global__ __launch_bounds__(256)
void k_dense_mfma(const ushort_t* __restrict__ PH,
                  const ushort_t* __restrict__ PL,
                  const int*   __restrict__ sortedMemb,
                  const int*   __restrict__ cumSeg,
                  const ushort_t* __restrict__ Bh,
                  const ushort_t* __restrict__ Bl,
                  const float* __restrict__ bias,
                  const float* __restrict__ bg, const float* __restrict__ bbeta,
                  const float* __restrict__ bm, const float* __restrict__ bv,
                  float* __restrict__ partials)
{
    __shared__ __align__(16) char smem[33792];
    __shared__ int sM[64];
    ushort_t* Ah = (ushort_t*)smem;
    ushort_t* Al = (ushort_t*)(smem + 16384);
    float*    Yt = (float*)smem;

    const int tid = threadIdx.x;
    const int tileBase = blockIdx.x * 64;
    if (tid < 64) sM[tid] = sortedMemb[tileBase + tid];

    for (int idx = tid; idx < 1024; idx += 256) {
        int a = idx >> 4, c = idx & 15;
        size_t off = (size_t)(tileBase + a) * 128 + c * 8;
        uint4 h  = *(const uint4*)(PH + off);
        uint4 lo = *(const uint4*)(PL + off);
        int cs = c ^ (a & 15);
        *(uint4*)(Ah + a * 128 + cs * 8) = h;
        *(uint4*)(Al + a * 128 + cs * 8) = lo;
    }
    __syncthreads();

    const int w = tid >> 6, l = tid & 63;
    const int lm = l & 15, lq = l >> 4;

    f32x4 acc[4][4];
    #pragma unroll
    for (int rt = 0; rt < 4; ++rt)
        #pragma unroll
        for (int ti = 0; ti < 4; ++ti)
            acc[rt][ti] = (f32x4){0.f, 0.f, 0.f, 0.f};

    for (int ks = 0; ks < 4; ++ks) {
        short8v ah[4], al[4];
        #pragma unroll
        for (int rt = 0; rt < 4; ++rt) {
            int a = rt * 16 + lm;
            int cs = (ks * 4 + lq) ^ lm;
            ah[rt] = *(const short8v*)(Ah + a * 128 + cs * 8);
            al[rt] = *(const short8v*)(Al + a * 128 + cs * 8);
        }
        #pragma unroll
        for (int ti = 0; ti < 4; ++ti) {
            int fid = ((w + ti * 4) * 4 + ks) * 64 + l;
            short8v bh = *(const short8v*)(Bh + (size_t)fid * 8);
            short8v bl = *(const short8v*)(Bl + (size_t)fid * 8);
            #pragma unroll
            for (int rt = 0; rt < 4; ++rt) {
                acc[rt][ti] = __builtin_amdgcn_mfma_f32_16x16x32_bf16(ah[rt], bh, acc[rt][ti], 0, 0, 0);
                acc[rt][ti] = __builtin_amdgcn_mfma_f32_16x16x32_bf16(al[rt], bh, acc[rt][ti], 0, 0, 0);
                acc[rt][ti] = __builtin_amdgcn_mfma_f32_16x16x32_bf16(ah[rt], bl, acc[rt][ti], 0, 0, 0);
            }
        }
    }

    float bvz[4], scv[4], shv[4];
    #pragma unroll
    for (int ti = 0; ti < 4; ++ti) {
        int c = (w + ti * 4) * 16 + lm;
        bvz[ti] = bias[c];
        float s = bg[c] * rsqrtf(bv[c] + BN_EPS);
        scv[ti] = s;
        shv[ti] = bbeta[c] - bm[c] * s;
    }

    const int q = tid >> 5, cg = tid & 31;
    const int sub = blockIdx.x * 8 + q;
    const size_t slotBase = (size_t)cumSeg[sub];
    const int fs = sM[q * 8];

    #pragma unroll
    for (int hf = 0; hf < 2; ++hf) {
        __syncthreads();
        #pragma unroll
        for (int tj = 0; tj < 2; ++tj) {
            int ti = 2 * hf + tj;
            int colh = (w + ti * 4) * 16 + lm - hf * 128;
            #pragma unroll
            for (int rt = 0; rt < 4; ++rt)
                #pragma unroll
                for (int r = 0; r < 4; ++r) {
                    int row = rt * 16 + lq * 4 + r;
                    float y = fast_tanh(acc[rt][ti][r] + bvz[ti]) * scv[ti] + shv[ti];
                    Yt[row * 132 + colh] = y;
                }
        }
        __syncthreads();

        float4 ys, ym;
        int cur = sM[q * 8];
        {
            float4 v = *(const float4*)(Yt + (q * 8) * 132 + cg * 4);
            ys = v; ym = v;
        }
        #pragma unroll
        for (int i = 1; i < 8; ++i) {
            float4 v = *(const float4*)(Yt + (q * 8 + i) * 132 + cg * 4);
            int m = sM[q * 8 + i];
            if (m == cur) {
                ys.x += v.x; ys.y += v.y; ys.z += v.z; ys.w += v.w;
                ym.x = fmaxf(ym.x, v.x); ym.y = fmaxf(ym.y, v.y);
                ym.z = fmaxf(ym.z, v.z); ym.w = fmaxf(ym.w, v.w);
            } else {
                float* p = partials + (slotBase + (cur - fs)) * 512 + hf * 128 + cg * 4;
                *(float4*)p         = ys;
                *(float4*)(p + 256) = ym;
                cur = m; ys = v; ym = v;
            }
        }
        float* p = partials + (slotBase + (cur - fs)) * 512 + hf * 128 + cg * 4;
        *(float4*)p         = ys;
        *(float4*)(p + 256) = ym;
    }
}

// ---------- combine partials -> final out (tanh fused) ----------

__global__ __launch_bounds__(256)
void k_combine(const float* __restrict__ partials,
               const int* __restrict__ binBase, const int* __restrict__ binCnt,
               const int* __restrict__ firstSeg, const int* __restrict__ cumSeg,
               float* __restrict__ Out)
{
    int sid = blockIdx.x * 4 + (threadIdx.x >> 6);
    if (sid >= 40000) return;
    int lane = threadIdx.x & 63;
    int b = binBase[sid], n = binCnt[sid];

    float4 s = make_float4(0.f, 0.f, 0.f, 0.f);
    float4 m = make_float4(-INFINITY, -INFINITY, -INFINITY, -INFINITY);
    if (n > 0) {
        int s0 = b >> 3, s1 = (b + n - 1) >> 3;
        for (int t = s0; t <= s1; ++t) {
            size_t slot = (size_t)cumSeg[t] + (sid - firstSeg[t]);
            const float4* P = (const float4*)(partials + slot * 512);
            float4 a = P[lane];
            float4 x = P[64 + lane];
            s.x += a.x; s.y += a.y; s.z += a.z; s.w += a.w;
            m.x = fmaxf(m.x, x.x); m.y = fmaxf(m.y, x.y);
            m.z = fmaxf(m.z, x.z); m.w = fmaxf(m.w, x.w);
        }
    }
    float4 os = make_float4(fast_tanh(s.x), fast_tanh(s.y), fast_tanh(s.z), fast_tanh(s.w));
    float4 om = make_float4(fast_tanh(m.x), fast_tanh(m.y), fast_tanh(m.z), fast_tanh(m.w));
    *(float4*)(Out + (size_t)sid * 512 + lane * 4)       = os;
    *(float4*)(Out + (size_t)sid * 512 + 256 + lane * 4) = om;
}

// ---------- launcher ----------

extern "C" void kernel_launch(void* const* d_in, const int* in_sizes, int n_in,
                              void* d_out, int out_size, void* d_ws, size_t ws_size,
                              hipStream_t stream)
{
    const float* atom = (const float*)d_in[0];
    const int*   memb = (const int*)d_in[1];
    const int*   adj1 = (const int*)d_in[2];
    const int*   adj2 = (const int*)d_in[3];
    const int*   adj3 = (const int*)d_in[4];
    const int*   adj4 = (const int*)d_in[5];
    const float* g1Ws = (const float*)d_in[6];
    const float* g1Wr = (const float*)d_in[7];
    const float* g1b  = (const float*)d_in[8];
    const float* g2Ws = (const float*)d_in[9];
    const float* g2Wr = (const float*)d_in[10];
    const float* g2b  = (const float*)d_in[11];
    const float* bn1g = (const float*)d_in[12];
    const float* bn1b = (const float*)d_in[13];
    const float* bn1m = (const float*)d_in[14];
    const float* bn1v = (const float*)d_in[15];
    const float* bn3g = (const float*)d_in[16];
    const float* bn3b = (const float*)d_in[17];
    const float* bn3m = (const float*)d_in[18];
    const float* bn3v = (const float*)d_in[19];
    const float* dW   = (const float*)d_in[20];
    const float* db   = (const float*)d_in[21];

    char* ws = (char*)d_ws;
    float* bufA = (float*)ws;                    // [1M][128] f32, 512 MB
    float* bufB = (float*)(ws + 512000000);      // [1M][128] f32, 512 MB
    char*  outc = (char*)d_out;                  // [40000][512] f32 = 81.92 MB
    float* out  = (float*)d_out;

    // gc1 pre-split atom planes live in bufB (dead before pool1 writes it):
    ushort_t* XH = (ushort_t*)bufB;              // [1M][96] bf16, 192 MB
    ushort_t* XL = XH + (size_t)1000000 * 96;    // 192 MB

    // pool2 split planes (sorted row order) also live in bufB (after gc2 reads pool1):
    ushort_t* PH = (ushort_t*)bufB;              // 256 MB
    ushort_t* PL = PH + (size_t)1000000 * 128;   // 256 MB

    // temp regions in d_out (all fully overwritten by k_combine at the end):
    ushort_t* gFh   = (ushort_t*)(outc);              // gc2 frags 294,912 B
    ushort_t* gFl   = (ushort_t*)(outc + 294912);
    ushort_t* g1Fh  = (ushort_t*)(outc + 589824);     // gc1 frags 221,184 B
    ushort_t* g1Fl  = (ushort_t*)(outc + 811008);
    ushort_t* dWh   = (ushort_t*)(outc + 1032192);    // dense frags 65,536 B
    ushort_t* dWl   = (ushort_t*)(outc + 1097728);
    int* invperm    = (int*)(outc + 1200000);         // 4,000,000 B
    int* sortedMemb = (int*)(outc + 5200000);         // 4,000,000 B
    int* binCnt     = (int*)(outc + 9200000);         // 160,000 B
    int* binBase    = (int*)(outc + 9360000);
    int* binFill    = (int*)(outc + 9520000);
    int* firstSeg   = (int*)(outc + 9680000);         // 500,000 B
    int* segCnt     = (int*)(outc + 10180000);
    int* cumSeg     = (int*)(outc + 10680000);        // ends ~11.2 MB << 82 MB

    // partials + combine-metadata copies live in bufA (dead after pool_split):
    float* partials = bufA;                           // <=165k slots x 2 KB = 338 MB
    int* cBinBase   = (int*)(ws + 400000000);
    int* cBinCnt    = (int*)(ws + 401000000);
    int* cFirstSeg  = (int*)(ws + 402000000);
    int* cCumSeg    = (int*)(ws + 403000000);

    // ---- W fragment prep + atom pre-split + counting sort (input-only deps) ----
    k_prepW2<<<72, 256, 0, stream>>>(g2Ws, g2Wr, gFh, gFl);
    k_prepW1<<<54, 256, 0, stream>>>(g1Ws, g1Wr, g1Fh, g1Fl);
    k_prepW<<<16, 256, 0, stream>>>(dW, dWh, dWl);
    k_prepX<<<46875, 256, 0, stream>>>(atom, XH, XL);
    k_zero_bins<<<(40000 + 255) / 256, 256, 0, stream>>>(binCnt, binFill);
    k_hist<<<(1000000 + 255) / 256, 256, 0, stream>>>(memb, binCnt);
    k_scan<<<1, 1024, 0, stream>>>(binCnt, binBase);
    k_scatter<<<(1000000 + 255) / 256, 256, 0, stream>>>(memb, binBase, binFill,
        invperm, sortedMemb);
    k_meta<<<(125000 + 255) / 256, 256, 0, stream>>>(sortedMemb, firstSeg, segCnt);
    k_scan2<<<1, 1024, 0, stream>>>(segCnt, cumSeg);

    // ---- gc1 (MFMA, merged, 32-atom tiles): XH/XL -> bufA ----
    k_gc1m_all<<<31251, 256, 0, stream>>>(XH, XL, adj1, adj2, adj3, adj4,
        g1Fh, g1Fl, g1b, bn1g, bn1b, bn1m, bn1v, bufA);

    // ---- pool1 (merged): bufA -> bufB (f32; overwrites XH/XL) ----
    k_pool_all<<<125000, 256, 0, stream>>>(bufA, adj1, adj2, adj3, adj4, bufB);

    // ---- gc2 (MFMA, merged, 32-atom tiles): bufB -> bufA ----
    k_gc2m_all<<<31251, 256, 0, stream>>>(bufB, adj1, adj2, adj3, adj4,
        gFh, gFl, g2b, bn1g, bn1b, bn1m, bn1v, bufA);

    // ---- pool2 (merged): bufA -> PH/PL at sorted positions ----
    k_pool_split_all<<<62500, 256, 0, stream>>>(bufA, adj1, adj2, adj3, adj4,
        invperm, PH, PL);

    // ---- copy combine-metadata out of d_out into bufA tail (bufA now dead) ----
    k_copymeta<<<(125000 + 255) / 256, 256, 0, stream>>>(binBase, binCnt,
        firstSeg, cumSeg, cBinBase, cBinCnt, cFirstSeg, cCumSeg);

    // ---- dense (MFMA, sequential staging) -> partials in bufA ----
    k_dense_mfma<<<15625, 256, 0, stream>>>(PH, PL, sortedMemb, cumSeg, dWh, dWl,
        db, bn3g, bn3b, bn3m, bn3v, partials);

    // ---- combine partials -> out (reads metadata from bufA copies) ----
    k_combine<<<10000, 256, 0, stream>>>(partials, cBinBase, cBinCnt,
        cFirstSeg, cCumSeg, out);
}